// Round 1
// baseline (2445.438 us; speedup 1.0000x reference)
//
#include <hip/hip_runtime.h>
#include <cstddef>

// ---------------- constants ----------------
#define H_ 256
#define NPT_ 1024
#define E_ 8192
#define K_ 48
#define L_ 3

// ws layout in floats
#define WS_X      0u
#define WS_Y      1048576u
#define WS_INT    2097152u       // int region starts here (as float offset)
#define WS_CNTS   0u             // int offsets relative to WS_INT
#define WS_OFFS   49152u
#define WS_CUR    98352u
#define WS_ELIST  147504u
#define WS_QKV    2637872u
#define WS_PACC   5783600u
#define WS_PML    7880752u
#define WS_LOG    8011824u
#define WS_STATS  8015920u
#define WS_PART   8015936u

// ---------------- proj: x = x_nodes @ proj_W + proj_b ----------------
__global__ __launch_bounds__(256) void k_proj(const float* __restrict__ xn,
    const float* __restrict__ pW, const float* __restrict__ pb,
    float* __restrict__ x)
{
  const int t = blockIdx.x >> 10, n = blockIdx.x & 1023;
  const int tid = threadIdx.x;
  __shared__ float xr[32];
  if (tid < 21) xr[tid] = xn[(size_t)(t*1024 + n)*21 + tid];
  __syncthreads();
  float acc = pb[t*256 + tid];
  #pragma unroll
  for (int i = 0; i < 21; ++i) acc += xr[i] * pW[(size_t)(t*21 + i)*256 + tid];
  x[(size_t)(t*1024 + n)*256 + tid] = acc;
}

// ---------------- CSR build ----------------
__global__ __launch_bounds__(256) void k_hist(const int* __restrict__ ei, int* __restrict__ cnts)
{
  const int gid = blockIdx.x*256 + threadIdx.x;       // 48*8192
  const int k = gid >> 13, e = gid & 8191;
  const int dst = ei[(size_t)k*2*E_ + E_ + e];
  atomicAdd(&cnts[k*1024 + dst], 1);
}

__global__ __launch_bounds__(1024) void k_scan(const int* __restrict__ cnts,
    int* __restrict__ offs, int* __restrict__ cur)
{
  const int k = blockIdx.x, tid = threadIdx.x;
  __shared__ int s[1024];
  const int v = cnts[k*1024 + tid];
  s[tid] = v; __syncthreads();
  for (int off = 1; off < 1024; off <<= 1) {
    int add = 0;
    if (tid >= off) add = s[tid - off];
    __syncthreads();
    s[tid] += add;
    __syncthreads();
  }
  const int ex = s[tid] - v;
  offs[k*1025 + tid] = ex;
  cur[k*1024 + tid] = ex;
  if (tid == 1023) offs[k*1025 + 1024] = s[1023];
}

__global__ __launch_bounds__(256) void k_scatter(const int* __restrict__ ei,
    int* __restrict__ cur, int* __restrict__ elist)
{
  const int gid = blockIdx.x*256 + threadIdx.x;
  const int k = gid >> 13, e = gid & 8191;
  const int src = ei[(size_t)k*2*E_ + e];
  const int dst = ei[(size_t)k*2*E_ + E_ + e];
  const int p = atomicAdd(&cur[k*1024 + dst], 1);
  elist[k*E_ + p] = src;
}

// ---------------- conv layer: y[t] = sum_j mean_rows(k_j) @ W[l][k_j] ----------------
// grid (2, 32, 4), block 256.  tile: 32 d-rows x 128 g-cols, K = 12*256
__global__ __launch_bounds__(256) void k_conv(const float* __restrict__ x,
    const float* __restrict__ convW, const int* __restrict__ offs,
    const int* __restrict__ elist, float* __restrict__ y, int l)
{
  const int gt = blockIdx.x, dblk = blockIdx.y, t = blockIdx.z;
  const int tid = threadIdx.x;
  const int wave = tid >> 6, lane = tid & 63;
  const int dg = tid >> 5, gg = tid & 31;
  __shared__ float At[256][32];     // [h][d_local] transposed means
  __shared__ float Wl[64][128];
  float acc[16];
  #pragma unroll
  for (int i = 0; i < 16; ++i) acc[i] = 0.f;

  for (int j = 0; j < 12; ++j) {
    const int a = j / 3, c = j - a*3;
    const int k = a*12 + t*3 + c;
    __syncthreads();   // previous iteration done with At/Wl
    // stage transposed means: wave handles 8 d-rows
    for (int i = 0; i < 8; ++i) {
      const int dl = wave*8 + i;
      const int d = dblk*32 + dl;
      const int o0 = offs[k*1025 + d];
      const int o1 = offs[k*1025 + d + 1];
      float4 s4 = make_float4(0.f, 0.f, 0.f, 0.f);
      const float* xb = x + (size_t)a*1024*256;
      for (int p = o0; p < o1; ++p) {
        const int src = elist[k*E_ + p];
        const float4 v = *reinterpret_cast<const float4*>(xb + (size_t)src*256 + lane*4);
        s4.x += v.x; s4.y += v.y; s4.z += v.z; s4.w += v.w;
      }
      const float inv = 1.f / fmaxf((float)(o1 - o0), 1.f);
      const int h0 = lane*4;
      At[h0+0][dl] = s4.x*inv; At[h0+1][dl] = s4.y*inv;
      At[h0+2][dl] = s4.z*inv; At[h0+3][dl] = s4.w*inv;
    }
    const float* Wk = convW + ((size_t)(l*K_ + k)) * 65536;
    for (int hc = 0; hc < 4; ++hc) {
      __syncthreads();   // At ready / previous compute done
      for (int i = tid; i < 8192; i += 256) {
        const int hh = i >> 7, g2 = i & 127;
        Wl[hh][g2] = Wk[(size_t)(hc*64 + hh)*256 + gt*128 + g2];
      }
      __syncthreads();
      #pragma unroll 8
      for (int hh = 0; hh < 64; ++hh) {
        const int h = hc*64 + hh;
        const float4 a4 = *reinterpret_cast<const float4*>(&At[h][dg*4]);
        const float4 w4 = *reinterpret_cast<const float4*>(&Wl[hh][gg*4]);
        acc[0]  += a4.x*w4.x; acc[1]  += a4.x*w4.y; acc[2]  += a4.x*w4.z; acc[3]  += a4.x*w4.w;
        acc[4]  += a4.y*w4.x; acc[5]  += a4.y*w4.y; acc[6]  += a4.y*w4.z; acc[7]  += a4.y*w4.w;
        acc[8]  += a4.z*w4.x; acc[9]  += a4.z*w4.y; acc[10] += a4.z*w4.z; acc[11] += a4.z*w4.w;
        acc[12] += a4.w*w4.x; acc[13] += a4.w*w4.y; acc[14] += a4.w*w4.z; acc[15] += a4.w*w4.w;
      }
    }
  }
  const int gcol = gt*128 + gg*4;
  #pragma unroll
  for (int di = 0; di < 4; ++di) {
    const int d = dblk*32 + dg*4 + di;
    float4 o = make_float4(acc[di*4+0], acc[di*4+1], acc[di*4+2], acc[di*4+3]);
    *reinterpret_cast<float4*>(y + (size_t)(t*1024 + d)*256 + gcol) = o;
  }
}

// ---------------- bias-gate + residual + LN + relu ----------------
__global__ __launch_bounds__(256) void k_ln(float* __restrict__ x,
    const float* __restrict__ y, const int* __restrict__ cnts,
    const float* __restrict__ convB, const float* __restrict__ ng,
    const float* __restrict__ nb, int l)
{
  const int r = blockIdx.x;               // t*1024 + d
  const int t = r >> 10, d = r & 1023;
  const int tid = threadIdx.x;
  __shared__ float flag[12];
  __shared__ float rbuf[256];
  if (tid < 12) {
    const int a = tid / 3, c = tid - a*3;
    const int kj = a*12 + t*3 + c;
    flag[tid] = (cnts[kj*1024 + d] > 0) ? 1.f : 0.f;
  }
  __syncthreads();
  float v = y[(size_t)r*256 + tid] + x[(size_t)r*256 + tid];
  #pragma unroll
  for (int j = 0; j < 12; ++j) {
    const int a = j / 3, c = j - a*3;
    const int kj = a*12 + t*3 + c;
    v += flag[j] * convB[(size_t)(l*K_ + kj)*256 + tid];
  }
  rbuf[tid] = v; __syncthreads();
  for (int s = 128; s > 0; s >>= 1) { if (tid < s) rbuf[tid] += rbuf[tid+s]; __syncthreads(); }
  const float mean = rbuf[0] * (1.f/256.f); __syncthreads();
  const float diff = v - mean;
  rbuf[tid] = diff*diff; __syncthreads();
  for (int s = 128; s > 0; s >>= 1) { if (tid < s) rbuf[tid] += rbuf[tid+s]; __syncthreads(); }
  const float var = rbuf[0] * (1.f/256.f); __syncthreads();
  const float xn = diff * rsqrtf(var + 1e-5f) * ng[(size_t)(l*4 + t)*256 + tid]
                 + nb[(size_t)(l*4 + t)*256 + tid];
  x[(size_t)r*256 + tid] = fmaxf(xn, 0.f);
}

// ---------------- generic 4096x256 @ 256x256 + bias ----------------
// grid (2, 256, batch), block 256
__global__ __launch_bounds__(256) void k_mm16(const float* __restrict__ A,
    const float* __restrict__ B, const float* __restrict__ bias,
    float* __restrict__ C, int wStride, int biasStride, int cStride)
{
  const int gt = blockIdx.x, rb = blockIdx.y, bz = blockIdx.z;
  const float* Bp = B + (size_t)bz*wStride;
  const float* bp = bias + (size_t)bz*biasStride;
  float* Cp = C + (size_t)bz*cStride;
  const int tid = threadIdx.x;
  __shared__ float At[256][16];
  __shared__ float Wl[64][128];
  for (int i = tid; i < 4096; i += 256) {
    const int rl = i >> 8, hh = i & 255;
    At[hh][rl] = A[(size_t)(rb*16 + rl)*256 + hh];
  }
  float acc[8];
  #pragma unroll
  for (int i = 0; i < 8; ++i) acc[i] = 0.f;
  const int dg = tid >> 5, gg = tid & 31;
  for (int hc = 0; hc < 4; ++hc) {
    __syncthreads();
    for (int i = tid; i < 8192; i += 256) {
      const int hh = i >> 7, g2 = i & 127;
      Wl[hh][g2] = Bp[(size_t)(hc*64 + hh)*256 + gt*128 + g2];
    }
    __syncthreads();
    #pragma unroll 8
    for (int hh = 0; hh < 64; ++hh) {
      const int h = hc*64 + hh;
      const float2 a2 = *reinterpret_cast<const float2*>(&At[h][dg*2]);
      const float4 w4 = *reinterpret_cast<const float4*>(&Wl[hh][gg*4]);
      acc[0]+=a2.x*w4.x; acc[1]+=a2.x*w4.y; acc[2]+=a2.x*w4.z; acc[3]+=a2.x*w4.w;
      acc[4]+=a2.y*w4.x; acc[5]+=a2.y*w4.y; acc[6]+=a2.y*w4.z; acc[7]+=a2.y*w4.w;
    }
  }
  const int gcol = gt*128 + gg*4;
  const float4 b4 = *reinterpret_cast<const float4*>(bp + gcol);
  #pragma unroll
  for (int ri = 0; ri < 2; ++ri) {
    const int row = rb*16 + dg*2 + ri;
    float4 o = make_float4(acc[ri*4+0]+b4.x, acc[ri*4+1]+b4.y, acc[ri*4+2]+b4.z, acc[ri*4+3]+b4.w);
    *reinterpret_cast<float4*>(Cp + (size_t)row*256 + gcol) = o;
  }
}

// ---------------- flash attention, 2-way key split ----------------
// grid (16, 8, 2), block 256: thread = one query row
__global__ __launch_bounds__(256) void k_attn(const float* __restrict__ qkv,
    float* __restrict__ pacc, float* __restrict__ pml)
{
  const int tid = threadIdx.x;
  const int r = blockIdx.x*256 + tid;
  const int h = blockIdx.y;
  const int sp = blockIdx.z;
  const float* qb = qkv;
  const float* kb = qkv + 1048576;
  const float* vb = qkv + 2097152;
  __shared__ float Kt[128][32];
  __shared__ float Vt[128][32];
  float q[32];
  #pragma unroll
  for (int d0 = 0; d0 < 8; ++d0) {
    const float4 qv = *reinterpret_cast<const float4*>(qb + (size_t)r*256 + h*32 + d0*4);
    q[d0*4+0]=qv.x; q[d0*4+1]=qv.y; q[d0*4+2]=qv.z; q[d0*4+3]=qv.w;
  }
  float m = -1e30f, lsum = 0.f;
  float acc[32];
  #pragma unroll
  for (int d = 0; d < 32; ++d) acc[d] = 0.f;
  for (int tile = 0; tile < 16; ++tile) {
    const int m0 = sp*2048 + tile*128;
    __syncthreads();
    for (int i = tid; i < 4096; i += 256) {
      const int mm = i >> 5, d = i & 31;
      Kt[mm][d] = kb[(size_t)(m0+mm)*256 + h*32 + d];
      Vt[mm][d] = vb[(size_t)(m0+mm)*256 + h*32 + d];
    }
    __syncthreads();
    for (int mm = 0; mm < 128; ++mm) {
      float s = 0.f;
      #pragma unroll
      for (int d = 0; d < 32; ++d) s += q[d]*Kt[mm][d];
      s *= 0.17677669529663687f;
      const float mnew = fmaxf(m, s);
      const float corr = __expf(m - mnew);
      const float p = __expf(s - mnew);
      lsum = lsum*corr + p;
      #pragma unroll
      for (int d = 0; d < 32; ++d) acc[d] = acc[d]*corr + p*Vt[mm][d];
      m = mnew;
    }
  }
  const size_t base = (size_t)(r*8 + h)*2 + sp;
  #pragma unroll
  for (int d = 0; d < 32; ++d) pacc[base*32 + d] = acc[d];
  pml[base*2 + 0] = m;
  pml[base*2 + 1] = lsum;
}

__global__ __launch_bounds__(256) void k_attn_merge(const float* __restrict__ pacc,
    const float* __restrict__ pml, float* __restrict__ attno)
{
  const int gid = blockIdx.x*256 + threadIdx.x;      // 4096*8*32
  const int rh = gid >> 5, d = gid & 31;
  const int r = rh >> 3, h = rh & 7;
  const float m0 = pml[rh*4+0], l0 = pml[rh*4+1];
  const float m1 = pml[rh*4+2], l1 = pml[rh*4+3];
  const float mx = fmaxf(m0, m1);
  const float e0 = __expf(m0 - mx), e1 = __expf(m1 - mx);
  const float den = l0*e0 + l1*e1;
  const float o = (pacc[(size_t)(rh*2)*32 + d]*e0 + pacc[(size_t)(rh*2+1)*32 + d]*e1) / den;
  attno[(size_t)r*256 + h*32 + d] = o;
}

// ---------------- pooling ----------------
__global__ __launch_bounds__(256) void k_pool_logits(const float* __restrict__ z,
    const float* __restrict__ pW, const float* __restrict__ pb, float* __restrict__ logits)
{
  const int tid = threadIdx.x;
  const int wave = tid >> 6, lane = tid & 63;
  const int r = blockIdx.x*4 + wave;
  const float4 zv = reinterpret_cast<const float4*>(z + (size_t)r*256)[lane];
  const float4 wv = reinterpret_cast<const float4*>(pW)[lane];
  float dv = zv.x*wv.x + zv.y*wv.y + zv.z*wv.z + zv.w*wv.w;
  for (int off = 32; off; off >>= 1) dv += __shfl_down(dv, off);
  if (lane == 0) logits[r] = dv + pb[0];
}

__global__ __launch_bounds__(256) void k_pool_stats(const float* __restrict__ logits,
    float* __restrict__ stats)
{
  const int tid = threadIdx.x;
  __shared__ float rbuf[256];
  float mx = -1e30f;
  for (int i = tid; i < 4096; i += 256) mx = fmaxf(mx, logits[i]);
  rbuf[tid] = mx; __syncthreads();
  for (int s = 128; s > 0; s >>= 1) { if (tid < s) rbuf[tid] = fmaxf(rbuf[tid], rbuf[tid+s]); __syncthreads(); }
  mx = rbuf[0]; __syncthreads();
  float se = 0.f;
  for (int i = tid; i < 4096; i += 256) se += __expf(logits[i] - mx);
  rbuf[tid] = se; __syncthreads();
  for (int s = 128; s > 0; s >>= 1) { if (tid < s) rbuf[tid] += rbuf[tid+s]; __syncthreads(); }
  if (tid == 0) { stats[0] = mx; stats[1] = rbuf[0]; }
}

__global__ __launch_bounds__(256) void k_pool_partial(const float* __restrict__ z,
    const float* __restrict__ logits, const float* __restrict__ stats,
    float* __restrict__ partial)
{
  const int pb = blockIdx.x, tid = threadIdx.x;
  const float mx = stats[0], se = stats[1];
  __shared__ float wl[256];
  wl[tid] = __expf(logits[pb*256 + tid] - mx) / se;
  __syncthreads();
  float acc = 0.f;
  for (int n = 0; n < 256; ++n) acc += wl[n] * z[(size_t)(pb*256 + n)*256 + tid];
  partial[pb*256 + tid] = acc;
}

// ---------------- heads (single block) ----------------
__global__ __launch_bounds__(256) void k_heads(
    const float* __restrict__ partial,
    const float* __restrict__ cx, const float* __restrict__ cW, const float* __restrict__ cb,
    const float* __restrict__ taW1, const float* __restrict__ tab1,
    const float* __restrict__ tag, const float* __restrict__ tabeta,
    const float* __restrict__ taW2, const float* __restrict__ tab2,
    const float* __restrict__ shW1, const float* __restrict__ shb1,
    const float* __restrict__ shW2, const float* __restrict__ shb2,
    const float* __restrict__ fprWa, const float* __restrict__ fprba,
    const float* __restrict__ fprg, const float* __restrict__ fprbeta,
    const float* __restrict__ fprW1, const float* __restrict__ fprb1,
    const float* __restrict__ fprW2, const float* __restrict__ fprb2,
    const float* __restrict__ secW1, const float* __restrict__ secb1,
    const float* __restrict__ secW2, const float* __restrict__ secb2,
    float* __restrict__ out)
{
  const int tid = threadIdx.x;
  __shared__ float semb[256], esec[256], efpr[256], hb[256], hb2[128], rbuf[256];

  float v = cb[tid];
  for (int pb = 0; pb < 16; ++pb) v += partial[pb*256 + tid];
  for (int i = 0; i < 32; ++i) v += cx[i] * cW[i*256 + tid];
  semb[tid] = v;
  __syncthreads();

  // tool_att 0 (sec), 1 (fpr)
  for (int i = 0; i < 2; ++i) {
    float u = tab1[i*256 + tid];
    for (int h = 0; h < 256; ++h) u += semb[h] * taW1[(size_t)(i*256 + h)*256 + tid];
    rbuf[tid] = u; __syncthreads();
    for (int s = 128; s > 0; s >>= 1) { if (tid < s) rbuf[tid] += rbuf[tid+s]; __syncthreads(); }
    const float mean = rbuf[0] * (1.f/256.f); __syncthreads();
    const float diff = u - mean;
    rbuf[tid] = diff*diff; __syncthreads();
    for (int s = 128; s > 0; s >>= 1) { if (tid < s) rbuf[tid] += rbuf[tid+s]; __syncthreads(); }
    const float var = rbuf[0] * (1.f/256.f); __syncthreads();
    hb[tid] = fmaxf(diff * rsqrtf(var + 1e-5f) * tag[i*256 + tid] + tabeta[i*256 + tid], 0.f);
    __syncthreads();
    float s2 = tab2[i*256 + tid];
    for (int h = 0; h < 256; ++h) s2 += hb[h] * taW2[(size_t)(i*256 + h)*256 + tid];
    const float att = semb[tid] * (1.f/(1.f + __expf(-s2)));
    if (i == 0) esec[tid] = att; else efpr[tid] = att;
    __syncthreads();
  }

  // simple heads -> out rows {0,2,3,4}
  #pragma unroll
  for (int i = 0; i < 4; ++i) {
    const int rowm = (i == 0) ? 0 : (i + 1);
    float h1 = 0.f;
    if (tid < 128) {
      h1 = shb1[i*128 + tid];
      for (int h = 0; h < 256; ++h) h1 += semb[h] * shW1[(size_t)(i*256 + h)*128 + tid];
      h1 = fmaxf(h1, 0.f);
    }
    hb[tid] = h1;
    __syncthreads();
    if (tid < 5) {
      float o = shb2[i*5 + tid];
      for (int h = 0; h < 128; ++h) o += hb[h] * shW2[(i*128 + h)*5 + tid];
      out[rowm*5 + tid] = 1.f/(1.f + __expf(-o));
    }
    __syncthreads();
  }

  // fpr chain -> out row 1
  {
    float u = fprba[tid];
    for (int h = 0; h < 256; ++h) u += efpr[h] * fprWa[(size_t)h*256 + tid];
    rbuf[tid] = u; __syncthreads();
    for (int s = 128; s > 0; s >>= 1) { if (tid < s) rbuf[tid] += rbuf[tid+s]; __syncthreads(); }
    const float mean = rbuf[0] * (1.f/256.f); __syncthreads();
    const float diff = u - mean;
    rbuf[tid] = diff*diff; __syncthreads();
    for (int s = 128; s > 0; s >>= 1) { if (tid < s) rbuf[tid] += rbuf[tid+s]; __syncthreads(); }
    const float var = rbuf[0] * (1.f/256.f); __syncthreads();
    hb[tid] = fmaxf(diff * rsqrtf(var + 1e-5f) * fprg[tid] + fprbeta[tid], 0.f);
    __syncthreads();
    float h1 = 0.f;
    if (tid < 128) {
      h1 = fprb1[tid];
      for (int h = 0; h < 256; ++h) h1 += hb[h] * fprW1[h*128 + tid];
      h1 = fmaxf(h1, 0.f);
      hb2[tid] = h1;
    }
    __syncthreads();
    if (tid < 5) {
      float o = fprb2[tid];
      for (int h = 0; h < 128; ++h) o += hb2[h] * fprW2[h*5 + tid];
      out[1*5 + tid] = 1.f/(1.f + __expf(-o));
    }
    __syncthreads();
  }

  // sec heads -> override positions {1,6,11,16,21}
  #pragma unroll
  for (int i = 0; i < 5; ++i) {
    if (tid < 128) {
      float h1 = secb1[i*128 + tid];
      for (int h = 0; h < 256; ++h) h1 += esec[h] * secW1[(size_t)(i*256 + h)*128 + tid];
      hb2[tid] = fmaxf(h1, 0.f);
    }
    __syncthreads();
    if (tid == 0) {
      float o = secb2[i];
      for (int h = 0; h < 128; ++h) o += hb2[h] * secW2[i*128 + h];
      out[i*5 + 1] = 1.f/(1.f + __expf(-o));
    }
    __syncthreads();
  }
}

// ---------------- launcher ----------------
extern "C" void kernel_launch(void* const* d_in, const int* in_sizes, int n_in,
                              void* d_out, int out_size, void* d_ws, size_t ws_size,
                              hipStream_t stream)
{
  const float* x_nodes    = (const float*)d_in[0];
  const float* contract_x = (const float*)d_in[1];
  const float* proj_W     = (const float*)d_in[2];
  const float* proj_b     = (const float*)d_in[3];
  const float* conv_W     = (const float*)d_in[4];
  const float* conv_b     = (const float*)d_in[5];
  const float* norm_g     = (const float*)d_in[6];
  const float* norm_b     = (const float*)d_in[7];
  const float* attn_W     = (const float*)d_in[8];
  const float* attn_b     = (const float*)d_in[9];
  const float* pool_W     = (const float*)d_in[10];
  const float* pool_b     = (const float*)d_in[11];
  const float* contract_W = (const float*)d_in[12];
  const float* contract_b = (const float*)d_in[13];
  const float* ta_W1      = (const float*)d_in[14];
  const float* ta_b1      = (const float*)d_in[15];
  const float* ta_g       = (const float*)d_in[16];
  const float* ta_beta    = (const float*)d_in[17];
  const float* ta_W2      = (const float*)d_in[18];
  const float* ta_b2      = (const float*)d_in[19];
  const float* sh_W1      = (const float*)d_in[20];
  const float* sh_b1      = (const float*)d_in[21];
  const float* sh_W2      = (const float*)d_in[22];
  const float* sh_b2      = (const float*)d_in[23];
  const float* fpr_Wa     = (const float*)d_in[24];
  const float* fpr_ba     = (const float*)d_in[25];
  const float* fpr_g      = (const float*)d_in[26];
  const float* fpr_beta   = (const float*)d_in[27];
  const float* fpr_W1     = (const float*)d_in[28];
  const float* fpr_b1     = (const float*)d_in[29];
  const float* fpr_W2     = (const float*)d_in[30];
  const float* fpr_b2     = (const float*)d_in[31];
  const float* sec_W1     = (const float*)d_in[32];
  const float* sec_b1     = (const float*)d_in[33];
  const float* sec_W2     = (const float*)d_in[34];
  const float* sec_b2     = (const float*)d_in[35];
  const int*   edge_index = (const int*)d_in[36];

  float* ws = (float*)d_ws;
  float* X     = ws + WS_X;
  float* Y     = ws + WS_Y;
  int*   ints  = (int*)(ws + WS_INT);
  int*   CNTS  = ints + WS_CNTS;
  int*   OFFS  = ints + WS_OFFS;
  int*   CUR   = ints + WS_CUR;
  int*   ELIST = ints + WS_ELIST;
  float* QKV   = ws + WS_QKV;
  float* PACC  = ws + WS_PACC;
  float* PML   = ws + WS_PML;
  float* LOG   = ws + WS_LOG;
  float* STATS = ws + WS_STATS;
  float* PART  = ws + WS_PART;

  hipMemsetAsync(CNTS, 0, (size_t)K_*NPT_*sizeof(int), stream);

  k_proj<<<dim3(4096), 256, 0, stream>>>(x_nodes, proj_W, proj_b, X);
  k_hist<<<dim3(1536), 256, 0, stream>>>(edge_index, CNTS);
  k_scan<<<dim3(48), 1024, 0, stream>>>(CNTS, OFFS, CUR);
  k_scatter<<<dim3(1536), 256, 0, stream>>>(edge_index, CUR, ELIST);

  for (int l = 0; l < L_; ++l) {
    k_conv<<<dim3(2, 32, 4), 256, 0, stream>>>(X, conv_W, OFFS, ELIST, Y, l);
    k_ln<<<dim3(4096), 256, 0, stream>>>(X, Y, CNTS, conv_b, norm_g, norm_b, l);
  }

  // qkv
  k_mm16<<<dim3(2, 256, 3), 256, 0, stream>>>(X, attn_W, attn_b, QKV, 65536, 256, 1048576);
  // attention
  k_attn<<<dim3(16, 8, 2), 256, 0, stream>>>(QKV, PACC, PML);
  k_attn_merge<<<dim3(4096), 256, 0, stream>>>(PACC, PML, Y);   // Y = attn out (pre-proj)
  // out projection -> z2 stored in QKV (q region free now)
  k_mm16<<<dim3(2, 256, 1), 256, 0, stream>>>(Y, attn_W + 3*65536, attn_b + 3*256, QKV, 0, 0, 0);
  // pooling
  k_pool_logits<<<dim3(1024), 256, 0, stream>>>(QKV, pool_W, pool_b, LOG);
  k_pool_stats<<<dim3(1), 256, 0, stream>>>(LOG, STATS);
  k_pool_partial<<<dim3(16), 256, 0, stream>>>(QKV, LOG, STATS, PART);
  // heads
  k_heads<<<dim3(1), 256, 0, stream>>>(PART,
      contract_x, contract_W, contract_b,
      ta_W1, ta_b1, ta_g, ta_beta, ta_W2, ta_b2,
      sh_W1, sh_b1, sh_W2, sh_b2,
      fpr_Wa, fpr_ba, fpr_g, fpr_beta, fpr_W1, fpr_b1, fpr_W2, fpr_b2,
      sec_W1, sec_b1, sec_W2, sec_b2,
      (float*)d_out);
}

// Round 2
// 1451.277 us; speedup vs baseline: 1.6850x; 1.6850x over previous
//
#include <hip/hip_runtime.h>
#include <cstddef>

typedef unsigned short ushort_t;
typedef __attribute__((ext_vector_type(8))) short bf16x8;
typedef __attribute__((ext_vector_type(4))) float f32x4;

// ---------------- constants ----------------
#define H_ 256
#define NPT_ 1024
#define E_ 8192
#define K_ 48
#define L_ 3

// ws layout in floats
#define WS_X      0u
#define WS_Y      1048576u
#define WS_INT    2097152u       // int region starts here (as float offset)
#define WS_CNTS   0u             // int offsets relative to WS_INT
#define WS_OFFS   49152u
#define WS_CUR    98352u
#define WS_ELIST  147504u
#define WS_QKV    2637872u
#define WS_BF     5783600u       // bf16 Q/K/Vt region (old PACC)
#define WS_PART   7880752u       // old PML region: pool partials (64*256)
#define WS_LOG    8011824u
#define WS_STATS  8015920u

__device__ __forceinline__ ushort_t f2bf(float x) {
  unsigned u = __float_as_uint(x);
  unsigned r = (u + 0x7FFFu + ((u >> 16) & 1u)) >> 16;
  return (ushort_t)r;
}

// ---------------- proj: x = x_nodes @ proj_W + proj_b ----------------
__global__ __launch_bounds__(256) void k_proj(const float* __restrict__ xn,
    const float* __restrict__ pW, const float* __restrict__ pb,
    float* __restrict__ x)
{
  const int t = blockIdx.x >> 10, n = blockIdx.x & 1023;
  const int tid = threadIdx.x;
  __shared__ float xr[32];
  if (tid < 21) xr[tid] = xn[(size_t)(t*1024 + n)*21 + tid];
  __syncthreads();
  float acc = pb[t*256 + tid];
  #pragma unroll
  for (int i = 0; i < 21; ++i) acc += xr[i] * pW[(size_t)(t*21 + i)*256 + tid];
  x[(size_t)(t*1024 + n)*256 + tid] = acc;
}

// ---------------- CSR build ----------------
__global__ __launch_bounds__(256) void k_hist(const int* __restrict__ ei, int* __restrict__ cnts)
{
  const int gid = blockIdx.x*256 + threadIdx.x;       // 48*8192
  const int k = gid >> 13, e = gid & 8191;
  const int dst = ei[(size_t)k*2*E_ + E_ + e];
  atomicAdd(&cnts[k*1024 + dst], 1);
}

__global__ __launch_bounds__(1024) void k_scan(const int* __restrict__ cnts,
    int* __restrict__ offs, int* __restrict__ cur)
{
  const int k = blockIdx.x, tid = threadIdx.x;
  __shared__ int s[1024];
  const int v = cnts[k*1024 + tid];
  s[tid] = v; __syncthreads();
  for (int off = 1; off < 1024; off <<= 1) {
    int add = 0;
    if (tid >= off) add = s[tid - off];
    __syncthreads();
    s[tid] += add;
    __syncthreads();
  }
  const int ex = s[tid] - v;
  offs[k*1025 + tid] = ex;
  cur[k*1024 + tid] = ex;
  if (tid == 1023) offs[k*1025 + 1024] = s[1023];
}

__global__ __launch_bounds__(256) void k_scatter(const int* __restrict__ ei,
    int* __restrict__ cur, int* __restrict__ elist)
{
  const int gid = blockIdx.x*256 + threadIdx.x;
  const int k = gid >> 13, e = gid & 8191;
  const int src = ei[(size_t)k*2*E_ + e];
  const int dst = ei[(size_t)k*2*E_ + E_ + e];
  const int p = atomicAdd(&cur[k*1024 + dst], 1);
  elist[k*E_ + p] = src;
}

// ---------------- conv layer (unchanged this round) ----------------
__global__ __launch_bounds__(256) void k_conv(const float* __restrict__ x,
    const float* __restrict__ convW, const int* __restrict__ offs,
    const int* __restrict__ elist, float* __restrict__ y, int l)
{
  const int gt = blockIdx.x, dblk = blockIdx.y, t = blockIdx.z;
  const int tid = threadIdx.x;
  const int wave = tid >> 6, lane = tid & 63;
  const int dg = tid >> 5, gg = tid & 31;
  __shared__ float At[256][32];     // [h][d_local] transposed means
  __shared__ float Wl[64][128];
  float acc[16];
  #pragma unroll
  for (int i = 0; i < 16; ++i) acc[i] = 0.f;

  for (int j = 0; j < 12; ++j) {
    const int a = j / 3, c = j - a*3;
    const int k = a*12 + t*3 + c;
    __syncthreads();
    for (int i = 0; i < 8; ++i) {
      const int dl = wave*8 + i;
      const int d = dblk*32 + dl;
      const int o0 = offs[k*1025 + d];
      const int o1 = offs[k*1025 + d + 1];
      float4 s4 = make_float4(0.f, 0.f, 0.f, 0.f);
      const float* xb = x + (size_t)a*1024*256;
      for (int p = o0; p < o1; ++p) {
        const int src = elist[k*E_ + p];
        const float4 v = *reinterpret_cast<const float4*>(xb + (size_t)src*256 + lane*4);
        s4.x += v.x; s4.y += v.y; s4.z += v.z; s4.w += v.w;
      }
      const float inv = 1.f / fmaxf((float)(o1 - o0), 1.f);
      const int h0 = lane*4;
      At[h0+0][dl] = s4.x*inv; At[h0+1][dl] = s4.y*inv;
      At[h0+2][dl] = s4.z*inv; At[h0+3][dl] = s4.w*inv;
    }
    const float* Wk = convW + ((size_t)(l*K_ + k)) * 65536;
    for (int hc = 0; hc < 4; ++hc) {
      __syncthreads();
      for (int i = tid; i < 8192; i += 256) {
        const int hh = i >> 7, g2 = i & 127;
        Wl[hh][g2] = Wk[(size_t)(hc*64 + hh)*256 + gt*128 + g2];
      }
      __syncthreads();
      #pragma unroll 8
      for (int hh = 0; hh < 64; ++hh) {
        const int h = hc*64 + hh;
        const float4 a4 = *reinterpret_cast<const float4*>(&At[h][dg*4]);
        const float4 w4 = *reinterpret_cast<const float4*>(&Wl[hh][gg*4]);
        acc[0]  += a4.x*w4.x; acc[1]  += a4.x*w4.y; acc[2]  += a4.x*w4.z; acc[3]  += a4.x*w4.w;
        acc[4]  += a4.y*w4.x; acc[5]  += a4.y*w4.y; acc[6]  += a4.y*w4.z; acc[7]  += a4.y*w4.w;
        acc[8]  += a4.z*w4.x; acc[9]  += a4.z*w4.y; acc[10] += a4.z*w4.z; acc[11] += a4.z*w4.w;
        acc[12] += a4.w*w4.x; acc[13] += a4.w*w4.y; acc[14] += a4.w*w4.z; acc[15] += a4.w*w4.w;
      }
    }
  }
  const int gcol = gt*128 + gg*4;
  #pragma unroll
  for (int di = 0; di < 4; ++di) {
    const int d = dblk*32 + dg*4 + di;
    float4 o = make_float4(acc[di*4+0], acc[di*4+1], acc[di*4+2], acc[di*4+3]);
    *reinterpret_cast<float4*>(y + (size_t)(t*1024 + d)*256 + gcol) = o;
  }
}

// ---------------- bias-gate + residual + LN + relu ----------------
__global__ __launch_bounds__(256) void k_ln(float* __restrict__ x,
    const float* __restrict__ y, const int* __restrict__ cnts,
    const float* __restrict__ convB, const float* __restrict__ ng,
    const float* __restrict__ nb, int l)
{
  const int r = blockIdx.x;               // t*1024 + d
  const int t = r >> 10, d = r & 1023;
  const int tid = threadIdx.x;
  __shared__ float flag[12];
  __shared__ float rbuf[256];
  if (tid < 12) {
    const int a = tid / 3, c = tid - a*3;
    const int kj = a*12 + t*3 + c;
    flag[tid] = (cnts[kj*1024 + d] > 0) ? 1.f : 0.f;
  }
  __syncthreads();
  float v = y[(size_t)r*256 + tid] + x[(size_t)r*256 + tid];
  #pragma unroll
  for (int j = 0; j < 12; ++j) {
    const int a = j / 3, c = j - a*3;
    const int kj = a*12 + t*3 + c;
    v += flag[j] * convB[(size_t)(l*K_ + kj)*256 + tid];
  }
  rbuf[tid] = v; __syncthreads();
  for (int s = 128; s > 0; s >>= 1) { if (tid < s) rbuf[tid] += rbuf[tid+s]; __syncthreads(); }
  const float mean = rbuf[0] * (1.f/256.f); __syncthreads();
  const float diff = v - mean;
  rbuf[tid] = diff*diff; __syncthreads();
  for (int s = 128; s > 0; s >>= 1) { if (tid < s) rbuf[tid] += rbuf[tid+s]; __syncthreads(); }
  const float var = rbuf[0] * (1.f/256.f); __syncthreads();
  const float xn = diff * rsqrtf(var + 1e-5f) * ng[(size_t)(l*4 + t)*256 + tid]
                 + nb[(size_t)(l*4 + t)*256 + tid];
  x[(size_t)r*256 + tid] = fmaxf(xn, 0.f);
}

// ---------------- generic 4096x256 @ 256x256 + bias ----------------
__global__ __launch_bounds__(256) void k_mm16(const float* __restrict__ A,
    const float* __restrict__ B, const float* __restrict__ bias,
    float* __restrict__ C, int wStride, int biasStride, int cStride)
{
  const int gt = blockIdx.x, rb = blockIdx.y, bz = blockIdx.z;
  const float* Bp = B + (size_t)bz*wStride;
  const float* bp = bias + (size_t)bz*biasStride;
  float* Cp = C + (size_t)bz*cStride;
  const int tid = threadIdx.x;
  __shared__ float At[256][16];
  __shared__ float Wl[64][128];
  for (int i = tid; i < 4096; i += 256) {
    const int rl = i >> 8, hh = i & 255;
    At[hh][rl] = A[(size_t)(rb*16 + rl)*256 + hh];
  }
  float acc[8];
  #pragma unroll
  for (int i = 0; i < 8; ++i) acc[i] = 0.f;
  const int dg = tid >> 5, gg = tid & 31;
  for (int hc = 0; hc < 4; ++hc) {
    __syncthreads();
    for (int i = tid; i < 8192; i += 256) {
      const int hh = i >> 7, g2 = i & 127;
      Wl[hh][g2] = Bp[(size_t)(hc*64 + hh)*256 + gt*128 + g2];
    }
    __syncthreads();
    #pragma unroll 8
    for (int hh = 0; hh < 64; ++hh) {
      const int h = hc*64 + hh;
      const float2 a2 = *reinterpret_cast<const float2*>(&At[h][dg*2]);
      const float4 w4 = *reinterpret_cast<const float4*>(&Wl[hh][gg*4]);
      acc[0]+=a2.x*w4.x; acc[1]+=a2.x*w4.y; acc[2]+=a2.x*w4.z; acc[3]+=a2.x*w4.w;
      acc[4]+=a2.y*w4.x; acc[5]+=a2.y*w4.y; acc[6]+=a2.y*w4.z; acc[7]+=a2.y*w4.w;
    }
  }
  const int gcol = gt*128 + gg*4;
  const float4 b4 = *reinterpret_cast<const float4*>(bp + gcol);
  #pragma unroll
  for (int ri = 0; ri < 2; ++ri) {
    const int row = rb*16 + dg*2 + ri;
    float4 o = make_float4(acc[ri*4+0]+b4.x, acc[ri*4+1]+b4.y, acc[ri*4+2]+b4.z, acc[ri*4+3]+b4.w);
    *reinterpret_cast<float4*>(Cp + (size_t)row*256 + gcol) = o;
  }
}

// ---------------- cast QKV fp32 -> bf16 (Q scaled, V transposed) ----------------
// grid (64 rblk, 8 h), block 256
__global__ __launch_bounds__(256) void k_cast(const float* __restrict__ qkv,
    ushort_t* __restrict__ Qh, ushort_t* __restrict__ Kh, ushort_t* __restrict__ Vt)
{
  const int rb = blockIdx.x, h = blockIdx.y;
  const int tid = threadIdx.x;
  const int r = tid >> 2, c8 = (tid & 3) * 8;
  const int row = rb*64 + r;
  __shared__ ushort_t vt[32][72];
  {
    const float* src = qkv + (size_t)row*256 + h*32 + c8;
    ushort_t tmp[8];
    #pragma unroll
    for (int j = 0; j < 8; ++j) tmp[j] = f2bf(src[j] * 0.17677669529663687f);
    *reinterpret_cast<uint4*>(Qh + ((size_t)(h*4096 + row))*32 + c8) = *reinterpret_cast<uint4*>(tmp);
  }
  {
    const float* src = qkv + 1048576 + (size_t)row*256 + h*32 + c8;
    ushort_t tmp[8];
    #pragma unroll
    for (int j = 0; j < 8; ++j) tmp[j] = f2bf(src[j]);
    *reinterpret_cast<uint4*>(Kh + ((size_t)(h*4096 + row))*32 + c8) = *reinterpret_cast<uint4*>(tmp);
  }
  {
    const float* src = qkv + 2097152 + (size_t)row*256 + h*32 + c8;
    #pragma unroll
    for (int j = 0; j < 8; ++j) vt[c8 + j][r] = f2bf(src[j]);
  }
  __syncthreads();
  const int d2 = tid >> 3, r0 = (tid & 7) * 8;
  *reinterpret_cast<uint4*>(Vt + ((size_t)(h*32 + d2))*4096 + rb*64 + r0)
      = *reinterpret_cast<const uint4*>(&vt[d2][r0]);
}

// ---------------- MFMA flash attention ----------------
// grid (64 qblk, 8 h), block 256 (4 waves x 16 q-rows)
__global__ __launch_bounds__(256) void k_attn2(const ushort_t* __restrict__ Qh,
    const ushort_t* __restrict__ Kh, const ushort_t* __restrict__ Vt,
    float* __restrict__ Yo)
{
  const int tid = threadIdx.x;
  const int wave = tid >> 6, lane = tid & 63;
  const int lrow = lane & 15, lgrp = lane >> 4;
  const int h = blockIdx.y;
  const int q0 = blockIdx.x * 64 + wave * 16;
  __shared__ ushort_t P[4][16][72];

  const bf16x8 qf = *reinterpret_cast<const bf16x8*>(
      Qh + ((size_t)(h*4096 + q0 + lrow))*32 + lgrp*8);

  float m[4], l[4];
  f32x4 o0 = {0.f,0.f,0.f,0.f}, o1 = {0.f,0.f,0.f,0.f};
  #pragma unroll
  for (int r = 0; r < 4; ++r) { m[r] = -1e30f; l[r] = 0.f; }

  const ushort_t* Kbase = Kh + (size_t)(h*4096)*32;
  const ushort_t* Vbase = Vt + (size_t)(h*32)*4096;

  for (int kt = 0; kt < 64; ++kt) {
    const int kb = kt*64;
    f32x4 s[4];
    #pragma unroll
    for (int ks = 0; ks < 4; ++ks) {
      const bf16x8 kf = *reinterpret_cast<const bf16x8*>(
          Kbase + (size_t)(kb + ks*16 + lrow)*32 + lgrp*8);
      f32x4 z = {0.f,0.f,0.f,0.f};
      s[ks] = __builtin_amdgcn_mfma_f32_16x16x32_bf16(qf, kf, z, 0, 0, 0);
    }
    #pragma unroll
    for (int r = 0; r < 4; ++r) {
      float mx = fmaxf(fmaxf(s[0][r], s[1][r]), fmaxf(s[2][r], s[3][r]));
      mx = fmaxf(mx, __shfl_xor(mx, 1));
      mx = fmaxf(mx, __shfl_xor(mx, 2));
      mx = fmaxf(mx, __shfl_xor(mx, 4));
      mx = fmaxf(mx, __shfl_xor(mx, 8));
      const float mnew = fmaxf(m[r], mx);
      const float corr = __expf(m[r] - mnew);
      m[r] = mnew;
      float ps = 0.f;
      #pragma unroll
      for (int ks = 0; ks < 4; ++ks) {
        const float p = __expf(s[ks][r] - mnew);
        s[ks][r] = p; ps += p;
      }
      ps += __shfl_xor(ps, 1); ps += __shfl_xor(ps, 2);
      ps += __shfl_xor(ps, 4); ps += __shfl_xor(ps, 8);
      l[r] = l[r]*corr + ps;
      o0[r] *= corr; o1[r] *= corr;
    }
    #pragma unroll
    for (int ks = 0; ks < 4; ++ks)
      #pragma unroll
      for (int r = 0; r < 4; ++r)
        P[wave][lgrp*4 + r][ks*16 + lrow] = f2bf(s[ks][r]);
    #pragma unroll
    for (int ks2 = 0; ks2 < 2; ++ks2) {
      const bf16x8 pa = *reinterpret_cast<const bf16x8*>(&P[wave][lrow][ks2*32 + lgrp*8]);
      const bf16x8 v0 = *reinterpret_cast<const bf16x8*>(
          Vbase + (size_t)lrow*4096 + kb + ks2*32 + lgrp*8);
      const bf16x8 v1 = *reinterpret_cast<const bf16x8*>(
          Vbase + (size_t)(16 + lrow)*4096 + kb + ks2*32 + lgrp*8);
      o0 = __builtin_amdgcn_mfma_f32_16x16x32_bf16(pa, v0, o0, 0, 0, 0);
      o1 = __builtin_amdgcn_mfma_f32_16x16x32_bf16(pa, v1, o1, 0, 0, 0);
    }
  }
  #pragma unroll
  for (int r = 0; r < 4; ++r) {
    const float inv = 1.f / l[r];
    const int row = q0 + lgrp*4 + r;
    Yo[(size_t)row*256 + h*32 + lrow]      = o0[r]*inv;
    Yo[(size_t)row*256 + h*32 + 16 + lrow] = o1[r]*inv;
  }
}

// ---------------- pooling ----------------
__global__ __launch_bounds__(256) void k_pool_logits(const float* __restrict__ z,
    const float* __restrict__ pW, const float* __restrict__ pb, float* __restrict__ logits)
{
  const int tid = threadIdx.x;
  const int wave = tid >> 6, lane = tid & 63;
  const int r = blockIdx.x*4 + wave;
  const float4 zv = reinterpret_cast<const float4*>(z + (size_t)r*256)[lane];
  const float4 wv = reinterpret_cast<const float4*>(pW)[lane];
  float dv = zv.x*wv.x + zv.y*wv.y + zv.z*wv.z + zv.w*wv.w;
  for (int off = 32; off; off >>= 1) dv += __shfl_down(dv, off);
  if (lane == 0) logits[r] = dv + pb[0];
}

__global__ __launch_bounds__(256) void k_pool_stats(const float* __restrict__ logits,
    float* __restrict__ stats)
{
  const int tid = threadIdx.x;
  __shared__ float rbuf[256];
  float mx = -1e30f;
  for (int i = tid; i < 4096; i += 256) mx = fmaxf(mx, logits[i]);
  rbuf[tid] = mx; __syncthreads();
  for (int s = 128; s > 0; s >>= 1) { if (tid < s) rbuf[tid] = fmaxf(rbuf[tid], rbuf[tid+s]); __syncthreads(); }
  mx = rbuf[0]; __syncthreads();
  float se = 0.f;
  for (int i = tid; i < 4096; i += 256) se += __expf(logits[i] - mx);
  rbuf[tid] = se; __syncthreads();
  for (int s = 128; s > 0; s >>= 1) { if (tid < s) rbuf[tid] += rbuf[tid+s]; __syncthreads(); }
  if (tid == 0) { stats[0] = mx; stats[1] = rbuf[0]; }
}

// grid 64 blocks: rows pb*64..+63
__global__ __launch_bounds__(256) void k_pool_partial(const float* __restrict__ z,
    const float* __restrict__ logits, const float* __restrict__ stats,
    float* __restrict__ partial)
{
  const int pb = blockIdx.x, tid = threadIdx.x;
  const float mx = stats[0], se = stats[1];
  __shared__ float wl[64];
  if (tid < 64) wl[tid] = __expf(logits[pb*64 + tid] - mx) / se;
  __syncthreads();
  float acc = 0.f;
  for (int n = 0; n < 64; ++n) acc += wl[n] * z[(size_t)(pb*64 + n)*256 + tid];
  partial[pb*256 + tid] = acc;
}

// ---------------- heads (single block) ----------------
__global__ __launch_bounds__(256) void k_heads(
    const float* __restrict__ partial,
    const float* __restrict__ cx, const float* __restrict__ cW, const float* __restrict__ cb,
    const float* __restrict__ taW1, const float* __restrict__ tab1,
    const float* __restrict__ tag, const float* __restrict__ tabeta,
    const float* __restrict__ taW2, const float* __restrict__ tab2,
    const float* __restrict__ shW1, const float* __restrict__ shb1,
    const float* __restrict__ shW2, const float* __restrict__ shb2,
    const float* __restrict__ fprWa, const float* __restrict__ fprba,
    const float* __restrict__ fprg, const float* __restrict__ fprbeta,
    const float* __restrict__ fprW1, const float* __restrict__ fprb1,
    const float* __restrict__ fprW2, const float* __restrict__ fprb2,
    const float* __restrict__ secW1, const float* __restrict__ secb1,
    const float* __restrict__ secW2, const float* __restrict__ secb2,
    float* __restrict__ out)
{
  const int tid = threadIdx.x;
  __shared__ float semb[256], esec[256], efpr[256], hb[256], hb2[128], rbuf[256];

  float v = cb[tid];
  for (int pb = 0; pb < 64; ++pb) v += partial[pb*256 + tid];
  for (int i = 0; i < 32; ++i) v += cx[i] * cW[i*256 + tid];
  semb[tid] = v;
  __syncthreads();

  for (int i = 0; i < 2; ++i) {
    float u = tab1[i*256 + tid];
    for (int h = 0; h < 256; ++h) u += semb[h] * taW1[(size_t)(i*256 + h)*256 + tid];
    rbuf[tid] = u; __syncthreads();
    for (int s = 128; s > 0; s >>= 1) { if (tid < s) rbuf[tid] += rbuf[tid+s]; __syncthreads(); }
    const float mean = rbuf[0] * (1.f/256.f); __syncthreads();
    const float diff = u - mean;
    rbuf[tid] = diff*diff; __syncthreads();
    for (int s = 128; s > 0; s >>= 1) { if (tid < s) rbuf[tid] += rbuf[tid+s]; __syncthreads(); }
    const float var = rbuf[0] * (1.f/256.f); __syncthreads();
    hb[tid] = fmaxf(diff * rsqrtf(var + 1e-5f) * tag[i*256 + tid] + tabeta[i*256 + tid], 0.f);
    __syncthreads();
    float s2 = tab2[i*256 + tid];
    for (int h = 0; h < 256; ++h) s2 += hb[h] * taW2[(size_t)(i*256 + h)*256 + tid];
    const float att = semb[tid] * (1.f/(1.f + __expf(-s2)));
    if (i == 0) esec[tid] = att; else efpr[tid] = att;
    __syncthreads();
  }

  #pragma unroll
  for (int i = 0; i < 4; ++i) {
    const int rowm = (i == 0) ? 0 : (i + 1);
    float h1 = 0.f;
    if (tid < 128) {
      h1 = shb1[i*128 + tid];
      for (int h = 0; h < 256; ++h) h1 += semb[h] * shW1[(size_t)(i*256 + h)*128 + tid];
      h1 = fmaxf(h1, 0.f);
    }
    hb[tid] = h1;
    __syncthreads();
    if (tid < 5) {
      float o = shb2[i*5 + tid];
      for (int h = 0; h < 128; ++h) o += hb[h] * shW2[(i*128 + h)*5 + tid];
      out[rowm*5 + tid] = 1.f/(1.f + __expf(-o));
    }
    __syncthreads();
  }

  {
    float u = fprba[tid];
    for (int h = 0; h < 256; ++h) u += efpr[h] * fprWa[(size_t)h*256 + tid];
    rbuf[tid] = u; __syncthreads();
    for (int s = 128; s > 0; s >>= 1) { if (tid < s) rbuf[tid] += rbuf[tid+s]; __syncthreads(); }
    const float mean = rbuf[0] * (1.f/256.f); __syncthreads();
    const float diff = u - mean;
    rbuf[tid] = diff*diff; __syncthreads();
    for (int s = 128; s > 0; s >>= 1) { if (tid < s) rbuf[tid] += rbuf[tid+s]; __syncthreads(); }
    const float var = rbuf[0] * (1.f/256.f); __syncthreads();
    hb[tid] = fmaxf(diff * rsqrtf(var + 1e-5f) * fprg[tid] + fprbeta[tid], 0.f);
    __syncthreads();
    float h1 = 0.f;
    if (tid < 128) {
      h1 = fprb1[tid];
      for (int h = 0; h < 256; ++h) h1 += hb[h] * fprW1[h*128 + tid];
      h1 = fmaxf(h1, 0.f);
      hb2[tid] = h1;
    }
    __syncthreads();
    if (tid < 5) {
      float o = fprb2[tid];
      for (int h = 0; h < 128; ++h) o += hb2[h] * fprW2[h*5 + tid];
      out[1*5 + tid] = 1.f/(1.f + __expf(-o));
    }
    __syncthreads();
  }

  #pragma unroll
  for (int i = 0; i < 5; ++i) {
    if (tid < 128) {
      float h1 = secb1[i*128 + tid];
      for (int h = 0; h < 256; ++h) h1 += esec[h] * secW1[(size_t)(i*256 + h)*128 + tid];
      hb2[tid] = fmaxf(h1, 0.f);
    }
    __syncthreads();
    if (tid == 0) {
      float o = secb2[i];
      for (int h = 0; h < 128; ++h) o += hb2[h] * secW2[i*128 + h];
      out[i*5 + 1] = 1.f/(1.f + __expf(-o));
    }
    __syncthreads();
  }
}

// ---------------- launcher ----------------
extern "C" void kernel_launch(void* const* d_in, const int* in_sizes, int n_in,
                              void* d_out, int out_size, void* d_ws, size_t ws_size,
                              hipStream_t stream)
{
  const float* x_nodes    = (const float*)d_in[0];
  const float* contract_x = (const float*)d_in[1];
  const float* proj_W     = (const float*)d_in[2];
  const float* proj_b     = (const float*)d_in[3];
  const float* conv_W     = (const float*)d_in[4];
  const float* conv_b     = (const float*)d_in[5];
  const float* norm_g     = (const float*)d_in[6];
  const float* norm_b     = (const float*)d_in[7];
  const float* attn_W     = (const float*)d_in[8];
  const float* attn_b     = (const float*)d_in[9];
  const float* pool_W     = (const float*)d_in[10];
  const float* pool_b     = (const float*)d_in[11];
  const float* contract_W = (const float*)d_in[12];
  const float* contract_b = (const float*)d_in[13];
  const float* ta_W1      = (const float*)d_in[14];
  const float* ta_b1      = (const float*)d_in[15];
  const float* ta_g       = (const float*)d_in[16];
  const float* ta_beta    = (const float*)d_in[17];
  const float* ta_W2      = (const float*)d_in[18];
  const float* ta_b2      = (const float*)d_in[19];
  const float* sh_W1      = (const float*)d_in[20];
  const float* sh_b1      = (const float*)d_in[21];
  const float* sh_W2      = (const float*)d_in[22];
  const float* sh_b2      = (const float*)d_in[23];
  const float* fpr_Wa     = (const float*)d_in[24];
  const float* fpr_ba     = (const float*)d_in[25];
  const float* fpr_g      = (const float*)d_in[26];
  const float* fpr_beta   = (const float*)d_in[27];
  const float* fpr_W1     = (const float*)d_in[28];
  const float* fpr_b1     = (const float*)d_in[29];
  const float* fpr_W2     = (const float*)d_in[30];
  const float* fpr_b2     = (const float*)d_in[31];
  const float* sec_W1     = (const float*)d_in[32];
  const float* sec_b1     = (const float*)d_in[33];
  const float* sec_W2     = (const float*)d_in[34];
  const float* sec_b2     = (const float*)d_in[35];
  const int*   edge_index = (const int*)d_in[36];

  float* ws = (float*)d_ws;
  float* X     = ws + WS_X;
  float* Y     = ws + WS_Y;
  int*   ints  = (int*)(ws + WS_INT);
  int*   CNTS  = ints + WS_CNTS;
  int*   OFFS  = ints + WS_OFFS;
  int*   CUR   = ints + WS_CUR;
  int*   ELIST = ints + WS_ELIST;
  float* QKV   = ws + WS_QKV;
  ushort_t* QH = (ushort_t*)(ws + WS_BF);
  ushort_t* KH = (ushort_t*)(ws + WS_BF + 524288);
  ushort_t* VT = (ushort_t*)(ws + WS_BF + 1048576);
  float* PART  = ws + WS_PART;
  float* LOG   = ws + WS_LOG;
  float* STATS = ws + WS_STATS;

  hipMemsetAsync(CNTS, 0, (size_t)K_*NPT_*sizeof(int), stream);

  k_proj<<<dim3(4096), 256, 0, stream>>>(x_nodes, proj_W, proj_b, X);
  k_hist<<<dim3(1536), 256, 0, stream>>>(edge_index, CNTS);
  k_scan<<<dim3(48), 1024, 0, stream>>>(CNTS, OFFS, CUR);
  k_scatter<<<dim3(1536), 256, 0, stream>>>(edge_index, CUR, ELIST);

  for (int l = 0; l < L_; ++l) {
    k_conv<<<dim3(2, 32, 4), 256, 0, stream>>>(X, conv_W, OFFS, ELIST, Y, l);
    k_ln<<<dim3(4096), 256, 0, stream>>>(X, Y, CNTS, conv_b, norm_g, norm_b, l);
  }

  // qkv (fp32), then cast to bf16 fragments
  k_mm16<<<dim3(2, 256, 3), 256, 0, stream>>>(X, attn_W, attn_b, QKV, 65536, 256, 1048576);
  k_cast<<<dim3(64, 8), 256, 0, stream>>>(QKV, QH, KH, VT);
  // MFMA flash attention -> Y
  k_attn2<<<dim3(64, 8), 256, 0, stream>>>(QH, KH, VT, Y);
  // out projection -> z2 stored in QKV
  k_mm16<<<dim3(2, 256, 1), 256, 0, stream>>>(Y, attn_W + 3*65536, attn_b + 3*256, QKV, 0, 0, 0);
  // pooling
  k_pool_logits<<<dim3(1024), 256, 0, stream>>>(QKV, pool_W, pool_b, LOG);
  k_pool_stats<<<dim3(1), 256, 0, stream>>>(LOG, STATS);
  k_pool_partial<<<dim3(64), 256, 0, stream>>>(QKV, LOG, STATS, PART);
  // heads
  k_heads<<<dim3(1), 256, 0, stream>>>(PART,
      contract_x, contract_W, contract_b,
      ta_W1, ta_b1, ta_g, ta_beta, ta_W2, ta_b2,
      sh_W1, sh_b1, sh_W2, sh_b2,
      fpr_Wa, fpr_ba, fpr_g, fpr_beta, fpr_W1, fpr_b1, fpr_W2, fpr_b2,
      sec_W1, sec_b1, sec_W2, sec_b2,
      (float*)d_out);
}

// Round 4
// 910.298 us; speedup vs baseline: 2.6864x; 1.5943x over previous
//
#include <hip/hip_runtime.h>
#include <cstddef>

typedef unsigned short ushort_t;
typedef __attribute__((ext_vector_type(8))) short bf16x8;
typedef __attribute__((ext_vector_type(4))) float f32x4;

// ---------------- constants ----------------
#define H_ 256
#define NPT_ 1024
#define E_ 8192
#define K_ 48
#define L_ 3

// ws layout in floats (~29.5 MB)
#define WS_X      0u          // X fp32 [4][1024][256]
#define WS_Y      1048576u    // Ypart during convs / attn-out after
#define WS_INT    2097152u    // int region (as float offset)
#define WS_CNTS   0u          // ints, relative to WS_INT
#define WS_OFFS   49152u
#define WS_CUR    98352u
#define WS_ELIST  147504u     // end 540720 ints
#define WS_WXF    2637872u    // Wx fp32 quarter [12][1024][256] = 3145728 floats
#define WS_QKV    2637872u    // QKV fp32 (reuses WXF after convs, same size)
#define WS_BF     5783600u    // bf16 Q/K/Vt (1572864 floats)
#define WS_PART   7356464u
#define WS_LOG    7372848u
#define WS_STATS  7376944u

__device__ __forceinline__ ushort_t f2bf(float x) {
  unsigned u = __float_as_uint(x);
  unsigned r = (u + 0x7FFFu + ((u >> 16) & 1u)) >> 16;
  return (ushort_t)r;
}
__device__ __forceinline__ float bf2f(ushort_t x) {
  return __uint_as_float(((unsigned)x) << 16);
}

// ---------------- proj: x = x_nodes @ proj_W + proj_b ----------------
__global__ __launch_bounds__(256) void k_proj(const float* __restrict__ xn,
    const float* __restrict__ pW, const float* __restrict__ pb,
    float* __restrict__ x)
{
  const int t = blockIdx.x >> 10, n = blockIdx.x & 1023;
  const int tid = threadIdx.x;
  __shared__ float xr[32];
  if (tid < 21) xr[tid] = xn[(size_t)(t*1024 + n)*21 + tid];
  __syncthreads();
  float acc = pb[t*256 + tid];
  #pragma unroll
  for (int i = 0; i < 21; ++i) acc += xr[i] * pW[(size_t)(t*21 + i)*256 + tid];
  x[(size_t)(t*1024 + n)*256 + tid] = acc;
}

// ---------------- CSR build ----------------
__global__ __launch_bounds__(256) void k_hist(const int* __restrict__ ei, int* __restrict__ cnts)
{
  const int gid = blockIdx.x*256 + threadIdx.x;       // 48*8192
  const int k = gid >> 13, e = gid & 8191;
  const int dst = ei[(size_t)k*2*E_ + E_ + e];
  atomicAdd(&cnts[k*1024 + dst], 1);
}

__global__ __launch_bounds__(1024) void k_scan(const int* __restrict__ cnts,
    int* __restrict__ offs, int* __restrict__ cur)
{
  const int k = blockIdx.x, tid = threadIdx.x;
  __shared__ int s[1024];
  const int v = cnts[k*1024 + tid];
  s[tid] = v; __syncthreads();
  for (int off = 1; off < 1024; off <<= 1) {
    int add = 0;
    if (tid >= off) add = s[tid - off];
    __syncthreads();
    s[tid] += add;
    __syncthreads();
  }
  const int ex = s[tid] - v;
  offs[k*1025 + tid] = ex;
  cur[k*1024 + tid] = ex;
  if (tid == 1023) offs[k*1025 + 1024] = s[1023];
}

__global__ __launch_bounds__(256) void k_scatter(const int* __restrict__ ei,
    int* __restrict__ cur, int* __restrict__ elist)
{
  const int gid = blockIdx.x*256 + threadIdx.x;
  const int k = gid >> 13, e = gid & 8191;
  const int src = ei[(size_t)k*2*E_ + e];
  const int dst = ei[(size_t)k*2*E_ + E_ + e];
  const int p = atomicAdd(&cur[k*1024 + dst], 1);
  elist[k*E_ + p] = src;
}

// ---------------- Wx[kk] = X[a] @ W[l][a*12+kk]  (bf16 hi/lo 3-pass MFMA, fp32 out) ----------------
// grid (cb=2, rb=8, kk=12), block 256 (4 waves of 64x64). Effectively-fp32 precision.
__global__ __launch_bounds__(256) void k_wx(const float* __restrict__ Xa,
    const float* __restrict__ Wsrc, float* __restrict__ Wxf)
{
  const int cb = blockIdx.x, rb = blockIdx.y, kk = blockIdx.z;
  const int tid = threadIdx.x, wave = tid >> 6, lane = tid & 63;
  const int lrow = lane & 15, lgrp = lane >> 4;
  const int wr = wave >> 1, wc = wave & 1;
  __shared__ __align__(16) ushort_t AswH[128*64];
  __shared__ __align__(16) ushort_t AswL[128*64];
  __shared__ __align__(16) ushort_t BswH[128*64];
  __shared__ __align__(16) ushort_t BswL[128*64];
  const float* Ab = Xa + (size_t)rb*128*256;
  const float* Wk = Wsrc + (size_t)kk*65536;        // [h=256][g=256]
  f32x4 acc[4][4];
  #pragma unroll
  for (int i = 0; i < 4; ++i)
    #pragma unroll
    for (int j = 0; j < 4; ++j) acc[i][j] = (f32x4){0.f,0.f,0.f,0.f};

  for (int ks = 0; ks < 4; ++ks) {
    __syncthreads();
    // stage A: fp32 -> hi/lo bf16, swizzled
    #pragma unroll
    for (int it = 0; it < 8; ++it) {
      const int idx = tid + it*256;          // 0..2047: 128 rows x 16 col4
      const int row = idx >> 4, c4 = idx & 15;
      const float4 v = *reinterpret_cast<const float4*>(Ab + (size_t)row*256 + ks*64 + c4*4);
      const float f[4] = {v.x, v.y, v.z, v.w};
      ushort_t hi[4], lo[4];
      #pragma unroll
      for (int e = 0; e < 4; ++e) {
        hi[e] = f2bf(f[e]);
        lo[e] = f2bf(f[e] - bf2f(hi[e]));
      }
      const int c8 = c4 >> 1, sub = (c4 & 1) * 4;
      const int off = row*64 + ((c8 ^ (row & 7)) << 3) + sub;
      *reinterpret_cast<uint2*>(&AswH[off]) = *reinterpret_cast<const uint2*>(hi);
      *reinterpret_cast<uint2*>(&AswL[off]) = *reinterpret_cast<const uint2*>(lo);
    }
    // stage B: fp32 -> hi/lo bf16 + transpose (h-pairs packed for b32 writes)
    #pragma unroll
    for (int it = 0; it < 4; ++it) {
      const int idx = tid + it*256;          // 0..1023: 32 hp x 32 g4
      const int hp = idx >> 5, g4 = idx & 31;
      const int h = ks*64 + hp*2;
      const float4 v0 = *reinterpret_cast<const float4*>(Wk + (size_t)h*256 + cb*128 + g4*4);
      const float4 v1 = *reinterpret_cast<const float4*>(Wk + (size_t)(h+1)*256 + cb*128 + g4*4);
      const float f0[4] = {v0.x, v0.y, v0.z, v0.w};
      const float f1[4] = {v1.x, v1.y, v1.z, v1.w};
      const int hl = hp*2;
      #pragma unroll
      for (int e = 0; e < 4; ++e) {
        const int g = g4*4 + e;
        const ushort_t h0 = f2bf(f0[e]), h1 = f2bf(f1[e]);
        const ushort_t l0 = f2bf(f0[e] - bf2f(h0)), l1 = f2bf(f1[e] - bf2f(h1));
        const int off = g*64 + (((hl >> 3) ^ (g & 7)) << 3) + (hl & 7);
        *reinterpret_cast<unsigned*>(&BswH[off]) = (unsigned)h0 | ((unsigned)h1 << 16);
        *reinterpret_cast<unsigned*>(&BswL[off]) = (unsigned)l0 | ((unsigned)l1 << 16);
      }
    }
    __syncthreads();
    #pragma unroll
    for (int ksub = 0; ksub < 2; ++ksub) {
      bf16x8 ah[4], al[4], bh[4], bl[4];
      const int c8 = ksub*4 + lgrp;
      #pragma unroll
      for (int mf = 0; mf < 4; ++mf) {
        const int row = wr*64 + mf*16 + lrow;
        const int off = row*64 + ((c8 ^ (row & 7)) << 3);
        ah[mf] = *reinterpret_cast<const bf16x8*>(&AswH[off]);
        al[mf] = *reinterpret_cast<const bf16x8*>(&AswL[off]);
      }
      #pragma unroll
      for (int nf = 0; nf < 4; ++nf) {
        const int row = wc*64 + nf*16 + lrow;
        const int off = row*64 + ((c8 ^ (row & 7)) << 3);
        bh[nf] = *reinterpret_cast<const bf16x8*>(&BswH[off]);
        bl[nf] = *reinterpret_cast<const bf16x8*>(&BswL[off]);
      }
      #pragma unroll
      for (int mf = 0; mf < 4; ++mf)
        #pragma unroll
        for (int nf = 0; nf < 4; ++nf) {
          acc[mf][nf] = __builtin_amdgcn_mfma_f32_16x16x32_bf16(ah[mf], bh[nf], acc[mf][nf], 0, 0, 0);
          acc[mf][nf] = __builtin_amdgcn_mfma_f32_16x16x32_bf16(ah[mf], bl[nf], acc[mf][nf], 0, 0, 0);
          acc[mf][nf] = __builtin_amdgcn_mfma_f32_16x16x32_bf16(al[mf], bh[nf], acc[mf][nf], 0, 0, 0);
        }
    }
  }
  float* Cb = Wxf + ((size_t)(kk*1024 + rb*128))*256 + cb*128;
  #pragma unroll
  for (int mf = 0; mf < 4; ++mf)
    #pragma unroll
    for (int nf = 0; nf < 4; ++nf)
      #pragma unroll
      for (int r = 0; r < 4; ++r) {
        const int row = wr*64 + mf*16 + lgrp*4 + r;
        const int col = wc*64 + nf*16 + lrow;
        Cb[(size_t)row*256 + col] = acc[mf][nf][r];
      }
}

// ---------------- gather means over fp32 Wx quarter; a==3 finalizes ----------------
// grid (d=1024, t=4), block 256 (waves 0..2 handle c=0..2)
__global__ __launch_bounds__(256) void k_gather(const float* __restrict__ Wxf,
    const int* __restrict__ offs, const int* __restrict__ elist,
    const int* __restrict__ cnts, const float* __restrict__ convB,
    const float* __restrict__ ng, const float* __restrict__ nb,
    const float* __restrict__ xin, float* __restrict__ ypart,
    float* __restrict__ xout, int a, int l)
{
  const int d = blockIdx.x, t = blockIdx.y;
  const int tid = threadIdx.x, wave = tid >> 6, lane = tid & 63;
  __shared__ float red[4][260];
  __shared__ float rbuf[256];
  __shared__ float flag[12];

  float4 acc = {0.f, 0.f, 0.f, 0.f};
  if (wave < 3) {
    const int c = wave;
    const int lk = t*3 + c;                 // index into Wxf quarter
    const int kg = a*12 + t*3 + c;          // global k
    const int o0 = offs[kg*1025 + d];
    const int o1 = offs[kg*1025 + d + 1];
    const float* wb = Wxf + (size_t)lk*1024*256;
    float4 s = {0.f, 0.f, 0.f, 0.f};
    int p = o0;
    while (p < o1) {
      int nb8 = o1 - p; if (nb8 > 8) nb8 = 8;
      int srcs[8];
      #pragma unroll
      for (int q = 0; q < 8; ++q) srcs[q] = (q < nb8) ? elist[(size_t)kg*E_ + p + q] : -1;
      #pragma unroll
      for (int q = 0; q < 8; ++q) {
        if (srcs[q] >= 0) {
          const float4 v = *reinterpret_cast<const float4*>(wb + (size_t)srcs[q]*256 + lane*4);
          s.x += v.x; s.y += v.y; s.z += v.z; s.w += v.w;
        }
      }
      p += nb8;
    }
    const float inv = 1.f / fmaxf((float)(o1 - o0), 1.f);
    acc.x = s.x*inv; acc.y = s.y*inv; acc.z = s.z*inv; acc.w = s.w*inv;
  }
  *reinterpret_cast<float4*>(&red[wave][lane*4]) = acc;
  if (a == 3 && tid < 12) {
    const int aa = tid / 3, c = tid - aa*3;
    const int kj = aa*12 + t*3 + c;
    flag[tid] = (cnts[kj*1024 + d] > 0) ? 1.f : 0.f;
  }
  __syncthreads();
  const int r = t*1024 + d;
  float v = red[0][tid] + red[1][tid] + red[2][tid];
  if (a == 0) { ypart[(size_t)r*256 + tid] = v; return; }
  if (a < 3)  { ypart[(size_t)r*256 + tid] += v; return; }
  v += ypart[(size_t)r*256 + tid] + xin[(size_t)r*256 + tid];
  #pragma unroll
  for (int j = 0; j < 12; ++j) {
    const int aa = j / 3, c = j - aa*3;
    const int kj = aa*12 + t*3 + c;
    v += flag[j] * convB[(size_t)(l*K_ + kj)*256 + tid];
  }
  rbuf[tid] = v; __syncthreads();
  for (int s = 128; s > 0; s >>= 1) { if (tid < s) rbuf[tid] += rbuf[tid+s]; __syncthreads(); }
  const float mean = rbuf[0] * (1.f/256.f); __syncthreads();
  const float diff = v - mean;
  rbuf[tid] = diff*diff; __syncthreads();
  for (int s = 128; s > 0; s >>= 1) { if (tid < s) rbuf[tid] += rbuf[tid+s]; __syncthreads(); }
  const float var = rbuf[0] * (1.f/256.f); __syncthreads();
  const float xn = diff * rsqrtf(var + 1e-5f) * ng[(size_t)(l*4 + t)*256 + tid]
                 + nb[(size_t)(l*4 + t)*256 + tid];
  xout[(size_t)r*256 + tid] = fmaxf(xn, 0.f);
}

// ---------------- generic 4096x256 @ 256x256 + bias (fp32) ----------------
__global__ __launch_bounds__(256) void k_mm16(const float* __restrict__ A,
    const float* __restrict__ B, const float* __restrict__ bias,
    float* __restrict__ C, int wStride, int biasStride, int cStride)
{
  const int gt = blockIdx.x, rb = blockIdx.y, bz = blockIdx.z;
  const float* Bp = B + (size_t)bz*wStride;
  const float* bp = bias + (size_t)bz*biasStride;
  float* Cp = C + (size_t)bz*cStride;
  const int tid = threadIdx.x;
  __shared__ float At[256][16];
  __shared__ float Wl[64][128];
  for (int i = tid; i < 4096; i += 256) {
    const int rl = i >> 8, hh = i & 255;
    At[hh][rl] = A[(size_t)(rb*16 + rl)*256 + hh];
  }
  float acc[8];
  #pragma unroll
  for (int i = 0; i < 8; ++i) acc[i] = 0.f;
  const int dg = tid >> 5, gg = tid & 31;
  for (int hc = 0; hc < 4; ++hc) {
    __syncthreads();
    for (int i = tid; i < 8192; i += 256) {
      const int hh = i >> 7, g2 = i & 127;
      Wl[hh][g2] = Bp[(size_t)(hc*64 + hh)*256 + gt*128 + g2];
    }
    __syncthreads();
    #pragma unroll 8
    for (int hh = 0; hh < 64; ++hh) {
      const int h = hc*64 + hh;
      const float2 a2 = *reinterpret_cast<const float2*>(&At[h][dg*2]);
      const float4 w4 = *reinterpret_cast<const float4*>(&Wl[hh][gg*4]);
      acc[0]+=a2.x*w4.x; acc[1]+=a2.x*w4.y; acc[2]+=a2.x*w4.z; acc[3]+=a2.x*w4.w;
      acc[4]+=a2.y*w4.x; acc[5]+=a2.y*w4.y; acc[6]+=a2.y*w4.z; acc[7]+=a2.y*w4.w;
    }
  }
  const int gcol = gt*128 + gg*4;
  const float4 b4 = *reinterpret_cast<const float4*>(bp + gcol);
  #pragma unroll
  for (int ri = 0; ri < 2; ++ri) {
    const int row = rb*16 + dg*2 + ri;
    float4 o = make_float4(acc[ri*4+0]+b4.x, acc[ri*4+1]+b4.y, acc[ri*4+2]+b4.z, acc[ri*4+3]+b4.w);
    *reinterpret_cast<float4*>(Cp + (size_t)row*256 + gcol) = o;
  }
}

// ---------------- cast QKV fp32 -> bf16 (Q scaled, V transposed) ----------------
__global__ __launch_bounds__(256) void k_cast(const float* __restrict__ qkv,
    ushort_t* __restrict__ Qh, ushort_t* __restrict__ Kh, ushort_t* __restrict__ Vt)
{
  const int rb = blockIdx.x, h = blockIdx.y;
  const int tid = threadIdx.x;
  const int r = tid >> 2, c8 = (tid & 3) * 8;
  const int row = rb*64 + r;
  __shared__ ushort_t vt[32][72];
  {
    const float* src = qkv + (size_t)row*256 + h*32 + c8;
    ushort_t tmp[8];
    #pragma unroll
    for (int j = 0; j < 8; ++j) tmp[j] = f2bf(src[j] * 0.17677669529663687f);
    *reinterpret_cast<uint4*>(Qh + ((size_t)(h*4096 + row))*32 + c8) = *reinterpret_cast<uint4*>(tmp);
  }
  {
    const float* src = qkv + 1048576 + (size_t)row*256 + h*32 + c8;
    ushort_t tmp[8];
    #pragma unroll
    for (int j = 0; j < 8; ++j) tmp[j] = f2bf(src[j]);
    *reinterpret_cast<uint4*>(Kh + ((size_t)(h*4096 + row))*32 + c8) = *reinterpret_cast<uint4*>(tmp);
  }
  {
    const float* src = qkv + 2097152 + (size_t)row*256 + h*32 + c8;
    #pragma unroll
    for (int j = 0; j < 8; ++j) vt[c8 + j][r] = f2bf(src[j]);
  }
  __syncthreads();
  const int d2 = tid >> 3, r0 = (tid & 7) * 8;
  *reinterpret_cast<uint4*>(Vt + ((size_t)(h*32 + d2))*4096 + rb*64 + r0)
      = *reinterpret_cast<const uint4*>(&vt[d2][r0]);
}

// ---------------- MFMA flash attention ----------------
__global__ __launch_bounds__(256) void k_attn2(const ushort_t* __restrict__ Qh,
    const ushort_t* __restrict__ Kh, const ushort_t* __restrict__ Vt,
    float* __restrict__ Yo)
{
  const int tid = threadIdx.x;
  const int wave = tid >> 6, lane = tid & 63;
  const int lrow = lane & 15, lgrp = lane >> 4;
  const int h = blockIdx.y;
  const int q0 = blockIdx.x * 64 + wave * 16;
  __shared__ ushort_t P[4][16][72];

  const bf16x8 qf = *reinterpret_cast<const bf16x8*>(
      Qh + ((size_t)(h*4096 + q0 + lrow))*32 + lgrp*8);

  float m[4], l[4];
  f32x4 o0 = {0.f,0.f,0.f,0.f}, o1 = {0.f,0.f,0.f,0.f};
  #pragma unroll
  for (int r = 0; r < 4; ++r) { m[r] = -1e30f; l[r] = 0.f; }

  const ushort_t* Kbase = Kh + (size_t)(h*4096)*32;
  const ushort_t* Vbase = Vt + (size_t)(h*32)*4096;

  for (int kt = 0; kt < 64; ++kt) {
    const int kb = kt*64;
    f32x4 s[4];
    #pragma unroll
    for (int ks = 0; ks < 4; ++ks) {
      const bf16x8 kf = *reinterpret_cast<const bf16x8*>(
          Kbase + (size_t)(kb + ks*16 + lrow)*32 + lgrp*8);
      f32x4 z = {0.f,0.f,0.f,0.f};
      s[ks] = __builtin_amdgcn_mfma_f32_16x16x32_bf16(qf, kf, z, 0, 0, 0);
    }
    #pragma unroll
    for (int r = 0; r < 4; ++r) {
      float mx = fmaxf(fmaxf(s[0][r], s[1][r]), fmaxf(s[2][r], s[3][r]));
      mx = fmaxf(mx, __shfl_xor(mx, 1));
      mx = fmaxf(mx, __shfl_xor(mx, 2));
      mx = fmaxf(mx, __shfl_xor(mx, 4));
      mx = fmaxf(mx, __shfl_xor(mx, 8));
      const float mnew = fmaxf(m[r], mx);
      const float corr = __expf(m[r] - mnew);
      m[r] = mnew;
      float ps = 0.f;
      #pragma unroll
      for (int ks = 0; ks < 4; ++ks) {
        const float p = __expf(s[ks][r] - mnew);
        s[ks][r] = p; ps += p;
      }
      ps += __shfl_xor(ps, 1); ps += __shfl_xor(ps, 2);
      ps += __shfl_xor(ps, 4); ps += __shfl_xor(ps, 8);
      l[r] = l[r]*corr + ps;
      o0[r] *= corr; o1[r] *= corr;
    }
    #pragma unroll
    for (int ks = 0; ks < 4; ++ks)
      #pragma unroll
      for (int r = 0; r < 4; ++r)
        P[wave][lgrp*4 + r][ks*16 + lrow] = f2bf(s[ks][r]);
    #pragma unroll
    for (int ks2 = 0; ks2 < 2; ++ks2) {
      const bf16x8 pa = *reinterpret_cast<const bf16x8*>(&P[wave][lrow][ks2*32 + lgrp*8]);
      const bf16x8 v0 = *reinterpret_cast<const bf16x8*>(
          Vbase + (size_t)lrow*4096 + kb + ks2*32 + lgrp*8);
      const bf16x8 v1 = *reinterpret_cast<const bf16x8*>(
          Vbase + (size_t)(16 + lrow)*4096 + kb + ks2*32 + lgrp*8);
      o0 = __builtin_amdgcn_mfma_f32_16x16x32_bf16(pa, v0, o0, 0, 0, 0);
      o1 = __builtin_amdgcn_mfma_f32_16x16x32_bf16(pa, v1, o1, 0, 0, 0);
    }
  }
  #pragma unroll
  for (int r = 0; r < 4; ++r) {
    const float inv = 1.f / l[r];
    const int row = q0 + lgrp*4 + r;
    Yo[(size_t)row*256 + h*32 + lrow]      = o0[r]*inv;
    Yo[(size_t)row*256 + h*32 + 16 + lrow] = o1[r]*inv;
  }
}

// ---------------- pooling ----------------
__global__ __launch_bounds__(256) void k_pool_logits(const float* __restrict__ z,
    const float* __restrict__ pW, const float* __restrict__ pb, float* __restrict__ logits)
{
  const int tid = threadIdx.x;
  const int wave = tid >> 6, lane = tid & 63;
  const int r = blockIdx.x*4 + wave;
  const float4 zv = reinterpret_cast<const float4*>(z + (size_t)r*256)[lane];
  const float4 wv = reinterpret_cast<const float4*>(pW)[lane];
  float dv = zv.x*wv.x + zv.y*wv.y + zv.z*wv.z + zv.w*wv.w;
  for (int off = 32; off; off >>= 1) dv += __shfl_down(dv, off);
  if (lane == 0) logits[r] = dv + pb[0];
}

__global__ __launch_bounds__(256) void k_pool_stats(const float* __restrict__ logits,
    float* __restrict__ stats)
{
  const int tid = threadIdx.x;
  __shared__ float rbuf[256];
  float mx = -1e30f;
  for (int i = tid; i < 4096; i += 256) mx = fmaxf(mx, logits[i]);
  rbuf[tid] = mx; __syncthreads();
  for (int s = 128; s > 0; s >>= 1) { if (tid < s) rbuf[tid] = fmaxf(rbuf[tid], rbuf[tid+s]); __syncthreads(); }
  mx = rbuf[0]; __syncthreads();
  float se = 0.f;
  for (int i = tid; i < 4096; i += 256) se += __expf(logits[i] - mx);
  rbuf[tid] = se; __syncthreads();
  for (int s = 128; s > 0; s >>= 1) { if (tid < s) rbuf[tid] += rbuf[tid+s]; __syncthreads(); }
  if (tid == 0) { stats[0] = mx; stats[1] = rbuf[0]; }
}

__global__ __launch_bounds__(256) void k_pool_partial(const float* __restrict__ z,
    const float* __restrict__ logits, const float* __restrict__ stats,
    float* __restrict__ partial)
{
  const int pb = blockIdx.x, tid = threadIdx.x;
  const float mx = stats[0], se = stats[1];
  __shared__ float wl[64];
  if (tid < 64) wl[tid] = __expf(logits[pb*64 + tid] - mx) / se;
  __syncthreads();
  float acc = 0.f;
  for (int n = 0; n < 64; ++n) acc += wl[n] * z[(size_t)(pb*64 + n)*256 + tid];
  partial[pb*256 + tid] = acc;
}

// ---------------- heads (single block) ----------------
__global__ __launch_bounds__(256) void k_heads(
    const float* __restrict__ partial,
    const float* __restrict__ cx, const float* __restrict__ cW, const float* __restrict__ cb,
    const float* __restrict__ taW1, const float* __restrict__ tab1,
    const float* __restrict__ tag, const float* __restrict__ tabeta,
    const float* __restrict__ taW2, const float* __restrict__ tab2,
    const float* __restrict__ shW1, const float* __restrict__ shb1,
    const float* __restrict__ shW2, const float* __restrict__ shb2,
    const float* __restrict__ fprWa, const float* __restrict__ fprba,
    const float* __restrict__ fprg, const float* __restrict__ fprbeta,
    const float* __restrict__ fprW1, const float* __restrict__ fprb1,
    const float* __restrict__ fprW2, const float* __restrict__ fprb2,
    const float* __restrict__ secW1, const float* __restrict__ secb1,
    const float* __restrict__ secW2, const float* __restrict__ secb2,
    float* __restrict__ out)
{
  const int tid = threadIdx.x;
  __shared__ float semb[256], esec[256], efpr[256], hb[256], hb2[128], rbuf[256];

  float v = cb[tid];
  for (int pb = 0; pb < 64; ++pb) v += partial[pb*256 + tid];
  for (int i = 0; i < 32; ++i) v += cx[i] * cW[i*256 + tid];
  semb[tid] = v;
  __syncthreads();

  for (int i = 0; i < 2; ++i) {
    float u = tab1[i*256 + tid];
    for (int h = 0; h < 256; ++h) u += semb[h] * taW1[(size_t)(i*256 + h)*256 + tid];
    rbuf[tid] = u; __syncthreads();
    for (int s = 128; s > 0; s >>= 1) { if (tid < s) rbuf[tid] += rbuf[tid+s]; __syncthreads(); }
    const float mean = rbuf[0] * (1.f/256.f); __syncthreads();
    const float diff = u - mean;
    rbuf[tid] = diff*diff; __syncthreads();
    for (int s = 128; s > 0; s >>= 1) { if (tid < s) rbuf[tid] += rbuf[tid+s]; __syncthreads(); }
    const float var = rbuf[0] * (1.f/256.f); __syncthreads();
    hb[tid] = fmaxf(diff * rsqrtf(var + 1e-5f) * tag[i*256 + tid] + tabeta[i*256 + tid], 0.f);
    __syncthreads();
    float s2 = tab2[i*256 + tid];
    for (int h = 0; h < 256; ++h) s2 += hb[h] * taW2[(size_t)(i*256 + h)*256 + tid];
    const float att = semb[tid] * (1.f/(1.f + __expf(-s2)));
    if (i == 0) esec[tid] = att; else efpr[tid] = att;
    __syncthreads();
  }

  #pragma unroll
  for (int i = 0; i < 4; ++i) {
    const int rowm = (i == 0) ? 0 : (i + 1);
    float h1 = 0.f;
    if (tid < 128) {
      h1 = shb1[i*128 + tid];
      for (int h = 0; h < 256; ++h) h1 += semb[h] * shW1[(size_t)(i*256 + h)*128 + tid];
      h1 = fmaxf(h1, 0.f);
    }
    hb[tid] = h1;
    __syncthreads();
    if (tid < 5) {
      float o = shb2[i*5 + tid];
      for (int h = 0; h < 128; ++h) o += hb[h] * shW2[(i*128 + h)*5 + tid];
      out[rowm*5 + tid] = 1.f/(1.f + __expf(-o));
    }
    __syncthreads();
  }

  {
    float u = fprba[tid];
    for (int h = 0; h < 256; ++h) u += efpr[h] * fprWa[(size_t)h*256 + tid];
    rbuf[tid] = u; __syncthreads();
    for (int s = 128; s > 0; s >>= 1) { if (tid < s) rbuf[tid] += rbuf[tid+s]; __syncthreads(); }
    const float mean = rbuf[0] * (1.f/256.f); __syncthreads();
    const float diff = u - mean;
    rbuf[tid] = diff*diff; __syncthreads();
    for (int s = 128; s > 0; s >>= 1) { if (tid < s) rbuf[tid] += rbuf[tid+s]; __syncthreads(); }
    const float var = rbuf[0] * (1.f/256.f); __syncthreads();
    hb[tid] = fmaxf(diff * rsqrtf(var + 1e-5f) * fprg[tid] + fprbeta[tid], 0.f);
    __syncthreads();
    float h1 = 0.f;
    if (tid < 128) {
      h1 = fprb1[tid];
      for (int h = 0; h < 256; ++h) h1 += hb[h] * fprW1[h*128 + tid];
      h1 = fmaxf(h1, 0.f);
      hb2[tid] = h1;
    }
    __syncthreads();
    if (tid < 5) {
      float o = fprb2[tid];
      for (int h = 0; h < 128; ++h) o += hb2[h] * fprW2[h*5 + tid];
      out[1*5 + tid] = 1.f/(1.f + __expf(-o));
    }
    __syncthreads();
  }

  #pragma unroll
  for (int i = 0; i < 5; ++i) {
    if (tid < 128) {
      float h1 = secb1[i*128 + tid];
      for (int h = 0; h < 256; ++h) h1 += esec[h] * secW1[(size_t)(i*256 + h)*128 + tid];
      hb2[tid] = fmaxf(h1, 0.f);
    }
    __syncthreads();
    if (tid == 0) {
      float o = secb2[i];
      for (int h = 0; h < 128; ++h) o += hb2[h] * secW2[i*128 + h];
      out[i*5 + 1] = 1.f/(1.f + __expf(-o));
    }
    __syncthreads();
  }
}

// ---------------- launcher ----------------
extern "C" void kernel_launch(void* const* d_in, const int* in_sizes, int n_in,
                              void* d_out, int out_size, void* d_ws, size_t ws_size,
                              hipStream_t stream)
{
  const float* x_nodes    = (const float*)d_in[0];
  const float* contract_x = (const float*)d_in[1];
  const float* proj_W     = (const float*)d_in[2];
  const float* proj_b     = (const float*)d_in[3];
  const float* conv_W     = (const float*)d_in[4];
  const float* conv_b     = (const float*)d_in[5];
  const float* norm_g     = (const float*)d_in[6];
  const float* norm_b     = (const float*)d_in[7];
  const float* attn_W     = (const float*)d_in[8];
  const float* attn_b     = (const float*)d_in[9];
  const float* pool_W     = (const float*)d_in[10];
  const float* pool_b     = (const float*)d_in[11];
  const float* contract_W = (const float*)d_in[12];
  const float* contract_b = (const float*)d_in[13];
  const float* ta_W1      = (const float*)d_in[14];
  const float* ta_b1      = (const float*)d_in[15];
  const float* ta_g       = (const float*)d_in[16];
  const float* ta_beta    = (const float*)d_in[17];
  const float* ta_W2      = (const float*)d_in[18];
  const float* ta_b2      = (const float*)d_in[19];
  const float* sh_W1      = (const float*)d_in[20];
  const float* sh_b1      = (const float*)d_in[21];
  const float* sh_W2      = (const float*)d_in[22];
  const float* sh_b2      = (const float*)d_in[23];
  const float* fpr_Wa     = (const float*)d_in[24];
  const float* fpr_ba     = (const float*)d_in[25];
  const float* fpr_g      = (const float*)d_in[26];
  const float* fpr_beta   = (const float*)d_in[27];
  const float* fpr_W1     = (const float*)d_in[28];
  const float* fpr_b1     = (const float*)d_in[29];
  const float* fpr_W2     = (const float*)d_in[30];
  const float* fpr_b2     = (const float*)d_in[31];
  const float* sec_W1     = (const float*)d_in[32];
  const float* sec_b1     = (const float*)d_in[33];
  const float* sec_W2     = (const float*)d_in[34];
  const float* sec_b2     = (const float*)d_in[35];
  const int*   edge_index = (const int*)d_in[36];

  float* ws = (float*)d_ws;
  float* X     = ws + WS_X;
  float* Y     = ws + WS_Y;       // Ypart during convs, attn-out after
  int*   ints  = (int*)(ws + WS_INT);
  int*   CNTS  = ints + WS_CNTS;
  int*   OFFS  = ints + WS_OFFS;
  int*   CUR   = ints + WS_CUR;
  int*   ELIST = ints + WS_ELIST;
  float* WXF   = ws + WS_WXF;
  float* QKV   = ws + WS_QKV;
  ushort_t* QH = (ushort_t*)(ws + WS_BF);
  ushort_t* KH = (ushort_t*)(ws + WS_BF + 524288);
  ushort_t* VT = (ushort_t*)(ws + WS_BF + 1048576);
  float* PART  = ws + WS_PART;
  float* LOG   = ws + WS_LOG;
  float* STATS = ws + WS_STATS;

  hipMemsetAsync(CNTS, 0, (size_t)K_*NPT_*sizeof(int), stream);

  k_proj<<<dim3(4096), 256, 0, stream>>>(x_nodes, proj_W, proj_b, X);
  k_hist<<<dim3(1536), 256, 0, stream>>>(edge_index, CNTS);
  k_scan<<<dim3(48), 1024, 0, stream>>>(CNTS, OFFS, CUR);
  k_scatter<<<dim3(1536), 256, 0, stream>>>(edge_index, CUR, ELIST);

  for (int l = 0; l < L_; ++l) {
    for (int a = 0; a < 4; ++a) {
      k_wx<<<dim3(2, 8, 12), 256, 0, stream>>>(
          X + (size_t)a*1024*256,
          conv_W + ((size_t)(l*K_ + a*12))*65536, WXF);
      k_gather<<<dim3(1024, 4), 256, 0, stream>>>(WXF, OFFS, ELIST, CNTS, conv_b,
          norm_g, norm_b, X, Y, X, a, l);
    }
  }

  // qkv (fp32), then cast to bf16 fragments
  k_mm16<<<dim3(2, 256, 3), 256, 0, stream>>>(X, attn_W, attn_b, QKV, 65536, 256, 1048576);
  k_cast<<<dim3(64, 8), 256, 0, stream>>>(QKV, QH, KH, VT);
  // MFMA flash attention -> Y
  k_attn2<<<dim3(64, 8), 256, 0, stream>>>(QH, KH, VT, Y);
  // out projection -> z2 stored in QKV
  k_mm16<<<dim3(2, 256, 1), 256, 0, stream>>>(Y, attn_W + 3*65536, attn_b + 3*256, QKV, 0, 0, 0);
  // pooling
  k_pool_logits<<<dim3(1024), 256, 0, stream>>>(QKV, pool_W, pool_b, LOG);
  k_pool_stats<<<dim3(1), 256, 0, stream>>>(LOG, STATS);
  k_pool_partial<<<dim3(64), 256, 0, stream>>>(QKV, LOG, STATS, PART);
  // heads
  k_heads<<<dim3(1), 256, 0, stream>>>(PART,
      contract_x, contract_W, contract_b,
      ta_W1, ta_b1, ta_g, ta_beta, ta_W2, ta_b2,
      sh_W1, sh_b1, sh_W2, sh_b2,
      fpr_Wa, fpr_ba, fpr_g, fpr_beta, fpr_W1, fpr_b1, fpr_W2, fpr_b2,
      sec_W1, sec_b1, sec_W2, sec_b2,
      (float*)d_out);
}

// Round 5
// 768.700 us; speedup vs baseline: 3.1813x; 1.1842x over previous
//
#include <hip/hip_runtime.h>
#include <cstddef>

typedef unsigned short ushort_t;
typedef __attribute__((ext_vector_type(8))) short bf16x8;
typedef __attribute__((ext_vector_type(4))) float f32x4;

// ---------------- constants ----------------
#define H_ 256
#define NPT_ 1024
#define E_ 8192
#define K_ 48
#define L_ 3

// ws layout in floats (~29.8 MB)
#define WS_X      0u          // X fp32 [4][1024][256]
#define WS_Y      1048576u    // conv GEMM accum / attn-out after
#define WS_INT    2097152u    // int region (600000 floats reserved)
#define WS_CNTS   0u          // ints, relative to WS_INT
#define WS_OFFS   49152u
#define WS_CUR    98352u
#define WS_ELIST  147504u     // end 540720 ints
#define WS_M      2700288u    // Mhi/Mlo bf16 [2][12][1024][256] = 3145728 floats
#define WS_QKV    2700288u    // QKV fp32 (reuses M after convs, 3145728 floats)
#define WS_WQ     5846016u    // Wqhi/Wqlo bf16 [2][12][256][256] = 1572864 floats
#define WS_BF     5846016u    // bf16 Q/K/Vt (reuses WQ after convs, 1572864 floats)
#define WS_PART   7418880u
#define WS_LOG    7435264u
#define WS_STATS  7439360u

__device__ __forceinline__ ushort_t f2bf(float x) {
  unsigned u = __float_as_uint(x);
  unsigned r = (u + 0x7FFFu + ((u >> 16) & 1u)) >> 16;
  return (ushort_t)r;
}
__device__ __forceinline__ float bf2f(ushort_t x) {
  return __uint_as_float(((unsigned)x) << 16);
}

// ---------------- proj ----------------
__global__ __launch_bounds__(256) void k_proj(const float* __restrict__ xn,
    const float* __restrict__ pW, const float* __restrict__ pb,
    float* __restrict__ x)
{
  const int t = blockIdx.x >> 10, n = blockIdx.x & 1023;
  const int tid = threadIdx.x;
  __shared__ float xr[32];
  if (tid < 21) xr[tid] = xn[(size_t)(t*1024 + n)*21 + tid];
  __syncthreads();
  float acc = pb[t*256 + tid];
  #pragma unroll
  for (int i = 0; i < 21; ++i) acc += xr[i] * pW[(size_t)(t*21 + i)*256 + tid];
  x[(size_t)(t*1024 + n)*256 + tid] = acc;
}

// ---------------- CSR build ----------------
__global__ __launch_bounds__(256) void k_hist(const int* __restrict__ ei, int* __restrict__ cnts)
{
  const int gid = blockIdx.x*256 + threadIdx.x;
  const int k = gid >> 13, e = gid & 8191;
  const int dst = ei[(size_t)k*2*E_ + E_ + e];
  atomicAdd(&cnts[k*1024 + dst], 1);
}

__global__ __launch_bounds__(1024) void k_scan(const int* __restrict__ cnts,
    int* __restrict__ offs, int* __restrict__ cur)
{
  const int k = blockIdx.x, tid = threadIdx.x;
  __shared__ int s[1024];
  const int v = cnts[k*1024 + tid];
  s[tid] = v; __syncthreads();
  for (int off = 1; off < 1024; off <<= 1) {
    int add = 0;
    if (tid >= off) add = s[tid - off];
    __syncthreads();
    s[tid] += add;
    __syncthreads();
  }
  const int ex = s[tid] - v;
  offs[k*1025 + tid] = ex;
  cur[k*1024 + tid] = ex;
  if (tid == 1023) offs[k*1025 + 1024] = s[1023];
}

__global__ __launch_bounds__(256) void k_scatter(const int* __restrict__ ei,
    int* __restrict__ cur, int* __restrict__ elist)
{
  const int gid = blockIdx.x*256 + threadIdx.x;
  const int k = gid >> 13, e = gid & 8191;
  const int src = ei[(size_t)k*2*E_ + e];
  const int dst = ei[(size_t)k*2*E_ + E_ + e];
  const int p = atomicAdd(&cur[k*1024 + dst], 1);
  elist[k*E_ + p] = src;
}

// ---------------- means: M[kl][d] = mean of X[a] rows (hi/lo bf16 out) ----------------
// grid 3072 blocks x 256 (4 waves); wave handles one (kl,d)
__global__ __launch_bounds__(256) void k_means(const float* __restrict__ X,
    const int* __restrict__ offs, const int* __restrict__ elist,
    ushort_t* __restrict__ Mhi, ushort_t* __restrict__ Mlo, int a)
{
  const int pid = blockIdx.x*4 + (threadIdx.x >> 6);
  const int kl = pid >> 10, d = pid & 1023;
  const int lane = threadIdx.x & 63;
  const int kg = a*12 + kl;
  const int o0 = offs[kg*1025 + d];
  const int o1 = offs[kg*1025 + d + 1];
  const float* xb = X + (size_t)a*1024*256;
  float4 s = {0.f, 0.f, 0.f, 0.f};
  int p = o0;
  while (p + 4 <= o1) {
    const int s0 = elist[(size_t)kg*E_ + p + 0];
    const int s1 = elist[(size_t)kg*E_ + p + 1];
    const int s2 = elist[(size_t)kg*E_ + p + 2];
    const int s3 = elist[(size_t)kg*E_ + p + 3];
    const float4 v0 = *reinterpret_cast<const float4*>(xb + (size_t)s0*256 + lane*4);
    const float4 v1 = *reinterpret_cast<const float4*>(xb + (size_t)s1*256 + lane*4);
    const float4 v2 = *reinterpret_cast<const float4*>(xb + (size_t)s2*256 + lane*4);
    const float4 v3 = *reinterpret_cast<const float4*>(xb + (size_t)s3*256 + lane*4);
    s.x += v0.x + v1.x + v2.x + v3.x;
    s.y += v0.y + v1.y + v2.y + v3.y;
    s.z += v0.z + v1.z + v2.z + v3.z;
    s.w += v0.w + v1.w + v2.w + v3.w;
    p += 4;
  }
  while (p < o1) {
    const int sp = elist[(size_t)kg*E_ + p];
    const float4 v = *reinterpret_cast<const float4*>(xb + (size_t)sp*256 + lane*4);
    s.x += v.x; s.y += v.y; s.z += v.z; s.w += v.w;
    ++p;
  }
  const float inv = 1.f / fmaxf((float)(o1 - o0), 1.f);
  const float mv[4] = {s.x*inv, s.y*inv, s.z*inv, s.w*inv};
  ushort_t hi[4], lo[4];
  #pragma unroll
  for (int e = 0; e < 4; ++e) {
    hi[e] = f2bf(mv[e]);
    lo[e] = f2bf(mv[e] - bf2f(hi[e]));
  }
  const size_t base = ((size_t)kl*1024 + d)*256 + lane*4;
  *reinterpret_cast<ushort4*>(Mhi + base) = *reinterpret_cast<const ushort4*>(hi);
  *reinterpret_cast<ushort4*>(Mlo + base) = *reinterpret_cast<const ushort4*>(lo);
}

// ---------------- W prep: transpose + hi/lo split for one quarter ----------------
// grid (12, 8, 8), block 256
__global__ __launch_bounds__(256) void k_wprep(const float* __restrict__ Wsrc,
    ushort_t* __restrict__ Whi, ushort_t* __restrict__ Wlo)
{
  const int kl = blockIdx.x, hb = blockIdx.y, gb = blockIdx.z;
  const int tid = threadIdx.x;
  __shared__ float tile[32][33];
  const float* W = Wsrc + (size_t)kl*65536;
  const int r0 = tid >> 5, c = tid & 31;
  #pragma unroll
  for (int it = 0; it < 4; ++it) {
    const int r = it*8 + r0;
    tile[r][c] = W[(size_t)(hb*32 + r)*256 + gb*32 + c];
  }
  __syncthreads();
  #pragma unroll
  for (int it = 0; it < 4; ++it) {
    const int g = it*8 + r0, h = c;
    const float v = tile[h][g];
    const ushort_t hi = f2bf(v);
    const ushort_t lo = f2bf(v - bf2f(hi));
    const size_t off = (size_t)kl*65536 + (size_t)(gb*32 + g)*256 + hb*32 + h;
    Whi[off] = hi;
    Wlo[off] = lo;
  }
}

// ---------------- conv GEMM: Y[t] (+)= sum_c M[t*3+c] @ Wq[t*3+c] (hi/lo 3-pass) ----------------
// grid (cb=2, rb=8, t=4), block 256 (4 waves of 64x64)
__global__ __launch_bounds__(256) void k_wxm(const ushort_t* __restrict__ Mhi,
    const ushort_t* __restrict__ Mlo, const ushort_t* __restrict__ Wqhi,
    const ushort_t* __restrict__ Wqlo, float* __restrict__ Y, int a)
{
  const int cb = blockIdx.x, rb = blockIdx.y, t = blockIdx.z;
  const int tid = threadIdx.x, wave = tid >> 6, lane = tid & 63;
  const int lrow = lane & 15, lgrp = lane >> 4;
  const int wr = wave >> 1, wc = wave & 1;
  __shared__ __align__(16) ushort_t AswH[128*64];
  __shared__ __align__(16) ushort_t AswL[128*64];
  __shared__ __align__(16) ushort_t BswH[128*64];
  __shared__ __align__(16) ushort_t BswL[128*64];
  f32x4 acc[4][4];
  #pragma unroll
  for (int i = 0; i < 4; ++i)
    #pragma unroll
    for (int j = 0; j < 4; ++j) acc[i][j] = (f32x4){0.f,0.f,0.f,0.f};

  for (int c = 0; c < 3; ++c) {
    const int kl = t*3 + c;
    const ushort_t* Ah = Mhi + ((size_t)kl*1024 + rb*128)*256;
    const ushort_t* Al = Mlo + ((size_t)kl*1024 + rb*128)*256;
    const ushort_t* Bh = Wqhi + (size_t)kl*65536 + (size_t)cb*128*256;
    const ushort_t* Bl = Wqlo + (size_t)kl*65536 + (size_t)cb*128*256;
    for (int ks = 0; ks < 4; ++ks) {
      __syncthreads();
      #pragma unroll
      for (int it = 0; it < 4; ++it) {
        const int idx = tid + it*256;      // 0..1023: 128 rows x 8 c8
        const int row = idx >> 3, c8 = idx & 7;
        const int off = row*64 + ((c8 ^ (row & 7)) << 3);
        const size_t gsrc = (size_t)row*256 + ks*64 + c8*8;
        *reinterpret_cast<bf16x8*>(&AswH[off]) = *reinterpret_cast<const bf16x8*>(Ah + gsrc);
        *reinterpret_cast<bf16x8*>(&AswL[off]) = *reinterpret_cast<const bf16x8*>(Al + gsrc);
        *reinterpret_cast<bf16x8*>(&BswH[off]) = *reinterpret_cast<const bf16x8*>(Bh + gsrc);
        *reinterpret_cast<bf16x8*>(&BswL[off]) = *reinterpret_cast<const bf16x8*>(Bl + gsrc);
      }
      __syncthreads();
      #pragma unroll
      for (int ksub = 0; ksub < 2; ++ksub) {
        bf16x8 ah[4], al[4], bh[4], bl[4];
        const int c8 = ksub*4 + lgrp;
        #pragma unroll
        for (int mf = 0; mf < 4; ++mf) {
          const int row = wr*64 + mf*16 + lrow;
          const int off = row*64 + ((c8 ^ (row & 7)) << 3);
          ah[mf] = *reinterpret_cast<const bf16x8*>(&AswH[off]);
          al[mf] = *reinterpret_cast<const bf16x8*>(&AswL[off]);
        }
        #pragma unroll
        for (int nf = 0; nf < 4; ++nf) {
          const int row = wc*64 + nf*16 + lrow;
          const int off = row*64 + ((c8 ^ (row & 7)) << 3);
          bh[nf] = *reinterpret_cast<const bf16x8*>(&BswH[off]);
          bl[nf] = *reinterpret_cast<const bf16x8*>(&BswL[off]);
        }
        #pragma unroll
        for (int mf = 0; mf < 4; ++mf)
          #pragma unroll
          for (int nf = 0; nf < 4; ++nf) {
            acc[mf][nf] = __builtin_amdgcn_mfma_f32_16x16x32_bf16(ah[mf], bh[nf], acc[mf][nf], 0, 0, 0);
            acc[mf][nf] = __builtin_amdgcn_mfma_f32_16x16x32_bf16(ah[mf], bl[nf], acc[mf][nf], 0, 0, 0);
            acc[mf][nf] = __builtin_amdgcn_mfma_f32_16x16x32_bf16(al[mf], bh[nf], acc[mf][nf], 0, 0, 0);
          }
      }
    }
  }
  float* Cb = Y + ((size_t)(t*1024 + rb*128))*256 + cb*128;
  if (a == 0) {
    #pragma unroll
    for (int mf = 0; mf < 4; ++mf)
      #pragma unroll
      for (int nf = 0; nf < 4; ++nf)
        #pragma unroll
        for (int r = 0; r < 4; ++r) {
          const int row = wr*64 + mf*16 + lgrp*4 + r;
          const int col = wc*64 + nf*16 + lrow;
          Cb[(size_t)row*256 + col] = acc[mf][nf][r];
        }
  } else {
    #pragma unroll
    for (int mf = 0; mf < 4; ++mf)
      #pragma unroll
      for (int nf = 0; nf < 4; ++nf)
        #pragma unroll
        for (int r = 0; r < 4; ++r) {
          const int row = wr*64 + mf*16 + lgrp*4 + r;
          const int col = wc*64 + nf*16 + lrow;
          Cb[(size_t)row*256 + col] += acc[mf][nf][r];
        }
  }
}

// ---------------- bias-gate + residual + LN + relu ----------------
__global__ __launch_bounds__(256) void k_ln(float* __restrict__ x,
    const float* __restrict__ y, const int* __restrict__ cnts,
    const float* __restrict__ convB, const float* __restrict__ ng,
    const float* __restrict__ nb, int l)
{
  const int r = blockIdx.x;               // t*1024 + d
  const int t = r >> 10, d = r & 1023;
  const int tid = threadIdx.x;
  __shared__ float flag[12];
  __shared__ float rbuf[256];
  if (tid < 12) {
    const int a = tid / 3, c = tid - a*3;
    const int kj = a*12 + t*3 + c;
    flag[tid] = (cnts[kj*1024 + d] > 0) ? 1.f : 0.f;
  }
  __syncthreads();
  float v = y[(size_t)r*256 + tid] + x[(size_t)r*256 + tid];
  #pragma unroll
  for (int j = 0; j < 12; ++j) {
    const int a = j / 3, c = j - a*3;
    const int kj = a*12 + t*3 + c;
    v += flag[j] * convB[(size_t)(l*K_ + kj)*256 + tid];
  }
  rbuf[tid] = v; __syncthreads();
  for (int s = 128; s > 0; s >>= 1) { if (tid < s) rbuf[tid] += rbuf[tid+s]; __syncthreads(); }
  const float mean = rbuf[0] * (1.f/256.f); __syncthreads();
  const float diff = v - mean;
  rbuf[tid] = diff*diff; __syncthreads();
  for (int s = 128; s > 0; s >>= 1) { if (tid < s) rbuf[tid] += rbuf[tid+s]; __syncthreads(); }
  const float var = rbuf[0] * (1.f/256.f); __syncthreads();
  const float xn = diff * rsqrtf(var + 1e-5f) * ng[(size_t)(l*4 + t)*256 + tid]
                 + nb[(size_t)(l*4 + t)*256 + tid];
  x[(size_t)r*256 + tid] = fmaxf(xn, 0.f);
}

// ---------------- generic 4096x256 @ 256x256 + bias (fp32) ----------------
__global__ __launch_bounds__(256) void k_mm16(const float* __restrict__ A,
    const float* __restrict__ B, const float* __restrict__ bias,
    float* __restrict__ C, int wStride, int biasStride, int cStride)
{
  const int gt = blockIdx.x, rb = blockIdx.y, bz = blockIdx.z;
  const float* Bp = B + (size_t)bz*wStride;
  const float* bp = bias + (size_t)bz*biasStride;
  float* Cp = C + (size_t)bz*cStride;
  const int tid = threadIdx.x;
  __shared__ float At[256][16];
  __shared__ float Wl[64][128];
  for (int i = tid; i < 4096; i += 256) {
    const int rl = i >> 8, hh = i & 255;
    At[hh][rl] = A[(size_t)(rb*16 + rl)*256 + hh];
  }
  float acc[8];
  #pragma unroll
  for (int i = 0; i < 8; ++i) acc[i] = 0.f;
  const int dg = tid >> 5, gg = tid & 31;
  for (int hc = 0; hc < 4; ++hc) {
    __syncthreads();
    for (int i = tid; i < 8192; i += 256) {
      const int hh = i >> 7, g2 = i & 127;
      Wl[hh][g2] = Bp[(size_t)(hc*64 + hh)*256 + gt*128 + g2];
    }
    __syncthreads();
    #pragma unroll 8
    for (int hh = 0; hh < 64; ++hh) {
      const int h = hc*64 + hh;
      const float2 a2 = *reinterpret_cast<const float2*>(&At[h][dg*2]);
      const float4 w4 = *reinterpret_cast<const float4*>(&Wl[hh][gg*4]);
      acc[0]+=a2.x*w4.x; acc[1]+=a2.x*w4.y; acc[2]+=a2.x*w4.z; acc[3]+=a2.x*w4.w;
      acc[4]+=a2.y*w4.x; acc[5]+=a2.y*w4.y; acc[6]+=a2.y*w4.z; acc[7]+=a2.y*w4.w;
    }
  }
  const int gcol = gt*128 + gg*4;
  const float4 b4 = *reinterpret_cast<const float4*>(bp + gcol);
  #pragma unroll
  for (int ri = 0; ri < 2; ++ri) {
    const int row = rb*16 + dg*2 + ri;
    float4 o = make_float4(acc[ri*4+0]+b4.x, acc[ri*4+1]+b4.y, acc[ri*4+2]+b4.z, acc[ri*4+3]+b4.w);
    *reinterpret_cast<float4*>(Cp + (size_t)row*256 + gcol) = o;
  }
}

// ---------------- cast QKV fp32 -> bf16 (Q scaled, V transposed) ----------------
__global__ __launch_bounds__(256) void k_cast(const float* __restrict__ qkv,
    ushort_t* __restrict__ Qh, ushort_t* __restrict__ Kh, ushort_t* __restrict__ Vt)
{
  const int rb = blockIdx.x, h = blockIdx.y;
  const int tid = threadIdx.x;
  const int r = tid >> 2, c8 = (tid & 3) * 8;
  const int row = rb*64 + r;
  __shared__ ushort_t vt[32][72];
  {
    const float* src = qkv + (size_t)row*256 + h*32 + c8;
    ushort_t tmp[8];
    #pragma unroll
    for (int j = 0; j < 8; ++j) tmp[j] = f2bf(src[j] * 0.17677669529663687f);
    *reinterpret_cast<uint4*>(Qh + ((size_t)(h*4096 + row))*32 + c8) = *reinterpret_cast<uint4*>(tmp);
  }
  {
    const float* src = qkv + 1048576 + (size_t)row*256 + h*32 + c8;
    ushort_t tmp[8];
    #pragma unroll
    for (int j = 0; j < 8; ++j) tmp[j] = f2bf(src[j]);
    *reinterpret_cast<uint4*>(Kh + ((size_t)(h*4096 + row))*32 + c8) = *reinterpret_cast<uint4*>(tmp);
  }
  {
    const float* src = qkv + 2097152 + (size_t)row*256 + h*32 + c8;
    #pragma unroll
    for (int j = 0; j < 8; ++j) vt[c8 + j][r] = f2bf(src[j]);
  }
  __syncthreads();
  const int d2 = tid >> 3, r0 = (tid & 7) * 8;
  *reinterpret_cast<uint4*>(Vt + ((size_t)(h*32 + d2))*4096 + rb*64 + r0)
      = *reinterpret_cast<const uint4*>(&vt[d2][r0]);
}

// ---------------- MFMA flash attention ----------------
__global__ __launch_bounds__(256) void k_attn2(const ushort_t* __restrict__ Qh,
    const ushort_t* __restrict__ Kh, const ushort_t* __restrict__ Vt,
    float* __restrict__ Yo)
{
  const int tid = threadIdx.x;
  const int wave = tid >> 6, lane = tid & 63;
  const int lrow = lane & 15, lgrp = lane >> 4;
  const int h = blockIdx.y;
  const int q0 = blockIdx.x * 64 + wave * 16;
  __shared__ ushort_t P[4][16][72];

  const bf16x8 qf = *reinterpret_cast<const bf16x8*>(
      Qh + ((size_t)(h*4096 + q0 + lrow))*32 + lgrp*8);

  float m[4], l[4];
  f32x4 o0 = {0.f,0.f,0.f,0.f}, o1 = {0.f,0.f,0.f,0.f};
  #pragma unroll
  for (int r = 0; r < 4; ++r) { m[r] = -1e30f; l[r] = 0.f; }

  const ushort_t* Kbase = Kh + (size_t)(h*4096)*32;
  const ushort_t* Vbase = Vt + (size_t)(h*32)*4096;

  for (int kt = 0; kt < 64; ++kt) {
    const int kb = kt*64;
    f32x4 s[4];
    #pragma unroll
    for (int ks = 0; ks < 4; ++ks) {
      const bf16x8 kf = *reinterpret_cast<const bf16x8*>(
          Kbase + (size_t)(kb + ks*16 + lrow)*32 + lgrp*8);
      f32x4 z = {0.f,0.f,0.f,0.f};
      s[ks] = __builtin_amdgcn_mfma_f32_16x16x32_bf16(qf, kf, z, 0, 0, 0);
    }
    #pragma unroll
    for (int r = 0; r < 4; ++r) {
      float mx = fmaxf(fmaxf(s[0][r], s[1][r]), fmaxf(s[2][r], s[3][r]));
      mx = fmaxf(mx, __shfl_xor(mx, 1));
      mx = fmaxf(mx, __shfl_xor(mx, 2));
      mx = fmaxf(mx, __shfl_xor(mx, 4));
      mx = fmaxf(mx, __shfl_xor(mx, 8));
      const float mnew = fmaxf(m[r], mx);
      const float corr = __expf(m[r] - mnew);
      m[r] = mnew;
      float ps = 0.f;
      #pragma unroll
      for (int ks = 0; ks < 4; ++ks) {
        const float p = __expf(s[ks][r] - mnew);
        s[ks][r] = p; ps += p;
      }
      ps += __shfl_xor(ps, 1); ps += __shfl_xor(ps, 2);
      ps += __shfl_xor(ps, 4); ps += __shfl_xor(ps, 8);
      l[r] = l[r]*corr + ps;
      o0[r] *= corr; o1[r] *= corr;
    }
    #pragma unroll
    for (int ks = 0; ks < 4; ++ks)
      #pragma unroll
      for (int r = 0; r < 4; ++r)
        P[wave][lgrp*4 + r][ks*16 + lrow] = f2bf(s[ks][r]);
    #pragma unroll
    for (int ks2 = 0; ks2 < 2; ++ks2) {
      const bf16x8 pa = *reinterpret_cast<const bf16x8*>(&P[wave][lrow][ks2*32 + lgrp*8]);
      const bf16x8 v0 = *reinterpret_cast<const bf16x8*>(
          Vbase + (size_t)lrow*4096 + kb + ks2*32 + lgrp*8);
      const bf16x8 v1 = *reinterpret_cast<const bf16x8*>(
          Vbase + (size_t)(16 + lrow)*4096 + kb + ks2*32 + lgrp*8);
      o0 = __builtin_amdgcn_mfma_f32_16x16x32_bf16(pa, v0, o0, 0, 0, 0);
      o1 = __builtin_amdgcn_mfma_f32_16x16x32_bf16(pa, v1, o1, 0, 0, 0);
    }
  }
  #pragma unroll
  for (int r = 0; r < 4; ++r) {
    const float inv = 1.f / l[r];
    const int row = q0 + lgrp*4 + r;
    Yo[(size_t)row*256 + h*32 + lrow]      = o0[r]*inv;
    Yo[(size_t)row*256 + h*32 + 16 + lrow] = o1[r]*inv;
  }
}

// ---------------- pooling ----------------
__global__ __launch_bounds__(256) void k_pool_logits(const float* __restrict__ z,
    const float* __restrict__ pW, const float* __restrict__ pb, float* __restrict__ logits)
{
  const int tid = threadIdx.x;
  const int wave = tid >> 6, lane = tid & 63;
  const int r = blockIdx.x*4 + wave;
  const float4 zv = reinterpret_cast<const float4*>(z + (size_t)r*256)[lane];
  const float4 wv = reinterpret_cast<const float4*>(pW)[lane];
  float dv = zv.x*wv.x + zv.y*wv.y + zv.z*wv.z + zv.w*wv.w;
  for (int off = 32; off; off >>= 1) dv += __shfl_down(dv, off);
  if (lane == 0) logits[r] = dv + pb[0];
}

__global__ __launch_bounds__(256) void k_pool_stats(const float* __restrict__ logits,
    float* __restrict__ stats)
{
  const int tid = threadIdx.x;
  __shared__ float rbuf[256];
  float mx = -1e30f;
  for (int i = tid; i < 4096; i += 256) mx = fmaxf(mx, logits[i]);
  rbuf[tid] = mx; __syncthreads();
  for (int s = 128; s > 0; s >>= 1) { if (tid < s) rbuf[tid] = fmaxf(rbuf[tid], rbuf[tid+s]); __syncthreads(); }
  mx = rbuf[0]; __syncthreads();
  float se = 0.f;
  for (int i = tid; i < 4096; i += 256) se += __expf(logits[i] - mx);
  rbuf[tid] = se; __syncthreads();
  for (int s = 128; s > 0; s >>= 1) { if (tid < s) rbuf[tid] += rbuf[tid+s]; __syncthreads(); }
  if (tid == 0) { stats[0] = mx; stats[1] = rbuf[0]; }
}

__global__ __launch_bounds__(256) void k_pool_partial(const float* __restrict__ z,
    const float* __restrict__ logits, const float* __restrict__ stats,
    float* __restrict__ partial)
{
  const int pb = blockIdx.x, tid = threadIdx.x;
  const float mx = stats[0], se = stats[1];
  __shared__ float wl[64];
  if (tid < 64) wl[tid] = __expf(logits[pb*64 + tid] - mx) / se;
  __syncthreads();
  float acc = 0.f;
  for (int n = 0; n < 64; ++n) acc += wl[n] * z[(size_t)(pb*64 + n)*256 + tid];
  partial[pb*256 + tid] = acc;
}

// ---------------- heads helpers ----------------
__device__ __forceinline__ void mv256(const float* __restrict__ W,
    const float* __restrict__ sIn, float (*red)[256], int o, int hq)
{
  float a0 = 0.f, a1 = 0.f, a2 = 0.f, a3 = 0.f;
  const float* Wp = W + (size_t)(hq*64)*256 + o;
  const float* ip = sIn + hq*64;
  #pragma unroll
  for (int j = 0; j < 16; ++j) {
    a0 += ip[j*4+0] * Wp[(size_t)(j*4+0)*256];
    a1 += ip[j*4+1] * Wp[(size_t)(j*4+1)*256];
    a2 += ip[j*4+2] * Wp[(size_t)(j*4+2)*256];
    a3 += ip[j*4+3] * Wp[(size_t)(j*4+3)*256];
  }
  red[hq][o] = (a0 + a1) + (a2 + a3);
}

// ---------------- heads (single block, 1024 threads) ----------------
__global__ __launch_bounds__(1024) void k_heads(
    const float* __restrict__ partial,
    const float* __restrict__ cx, const float* __restrict__ cW, const float* __restrict__ cb,
    const float* __restrict__ taW1, const float* __restrict__ tab1,
    const float* __restrict__ tag, const float* __restrict__ tabeta,
    const float* __restrict__ taW2, const float* __restrict__ tab2,
    const float* __restrict__ shW1, const float* __restrict__ shb1,
    const float* __restrict__ shW2, const float* __restrict__ shb2,
    const float* __restrict__ fprWa, const float* __restrict__ fprba,
    const float* __restrict__ fprg, const float* __restrict__ fprbeta,
    const float* __restrict__ fprW1, const float* __restrict__ fprb1,
    const float* __restrict__ fprW2, const float* __restrict__ fprb2,
    const float* __restrict__ secW1, const float* __restrict__ secb1,
    const float* __restrict__ secW2, const float* __restrict__ secb2,
    float* __restrict__ out)
{
  const int tid = threadIdx.x;
  const int o = tid & 255, hq = tid >> 8;
  __shared__ float semb[256], esec[256], efpr[256], vbuf[256];
  __shared__ float red[4][256];
  __shared__ float rbuf[256];
  __shared__ float h1s[640];
  float* redf = &red[0][0];

  // ---- semb ----
  {
    float acc = 0.f;
    #pragma unroll
    for (int pb = 0; pb < 16; ++pb) acc += partial[(hq*16 + pb)*256 + o];
    #pragma unroll
    for (int i = 0; i < 8; ++i) acc += cx[hq*8 + i] * cW[(hq*8 + i)*256 + o];
    red[hq][o] = acc;
  }
  __syncthreads();
  if (tid < 256) semb[tid] = red[0][tid] + red[1][tid] + red[2][tid] + red[3][tid] + cb[tid];
  __syncthreads();

  // ---- tool_att i=0 (sec), i=1 (fpr) ----
  for (int i = 0; i < 2; ++i) {
    mv256(taW1 + (size_t)i*65536, semb, red, o, hq);
    __syncthreads();
    float u = 0.f;
    if (tid < 256) u = red[0][tid] + red[1][tid] + red[2][tid] + red[3][tid] + tab1[i*256 + tid];
    if (tid < 256) rbuf[tid] = u;
    __syncthreads();
    for (int s = 128; s > 0; s >>= 1) { if (tid < s) rbuf[tid] += rbuf[tid+s]; __syncthreads(); }
    const float mean = rbuf[0] * (1.f/256.f);
    __syncthreads();
    const float diff = u - mean;
    if (tid < 256) rbuf[tid] = diff*diff;
    __syncthreads();
    for (int s = 128; s > 0; s >>= 1) { if (tid < s) rbuf[tid] += rbuf[tid+s]; __syncthreads(); }
    const float var = rbuf[0] * (1.f/256.f);
    __syncthreads();
    if (tid < 256)
      vbuf[tid] = fmaxf(diff * rsqrtf(var + 1e-5f) * tag[i*256 + tid] + tabeta[i*256 + tid], 0.f);
    __syncthreads();
    mv256(taW2 + (size_t)i*65536, vbuf, red, o, hq);
    __syncthreads();
    if (tid < 256) {
      const float s2v = red[0][tid] + red[1][tid] + red[2][tid] + red[3][tid] + tab2[i*256 + tid];
      const float att = semb[tid] * (1.f/(1.f + __expf(-s2v)));
      if (i == 0) esec[tid] = att; else efpr[tid] = att;
    }
    __syncthreads();
  }

  // ---- simple heads (4 x 128, K=256 split 2) ----
  {
    const int oo = tid & 511, ii = oo >> 7, col = oo & 127, hh = tid >> 9;
    float a0 = 0.f, a1 = 0.f, a2 = 0.f, a3 = 0.f;
    const float* Wp = shW1 + (size_t)ii*32768 + (size_t)(hh*128)*128 + col;
    const float* ip = semb + hh*128;
    #pragma unroll
    for (int j = 0; j < 32; ++j) {
      a0 += ip[j*4+0] * Wp[(size_t)(j*4+0)*128];
      a1 += ip[j*4+1] * Wp[(size_t)(j*4+1)*128];
      a2 += ip[j*4+2] * Wp[(size_t)(j*4+2)*128];
      a3 += ip[j*4+3] * Wp[(size_t)(j*4+3)*128];
    }
    redf[hh*512 + oo] = (a0 + a1) + (a2 + a3);
  }
  __syncthreads();
  if (tid < 512) {
    const int ii = tid >> 7, col = tid & 127;
    h1s[tid] = fmaxf(redf[tid] + redf[512 + tid] + shb1[ii*128 + col], 0.f);
  }
  __syncthreads();
  if (tid < 20) {
    const int ii = tid / 5, c = tid % 5;
    const int rowm = (ii == 0) ? 0 : (ii + 1);
    float ov = shb2[ii*5 + c];
    for (int hh = 0; hh < 128; ++hh) ov += h1s[ii*128 + hh] * shW2[ii*640 + hh*5 + c];
    out[rowm*5 + c] = 1.f/(1.f + __expf(-ov));
  }

  // ---- fpr chain -> row 1 ----
  mv256(fprWa, efpr, red, o, hq);
  __syncthreads();
  {
    float u = 0.f;
    if (tid < 256) u = red[0][tid] + red[1][tid] + red[2][tid] + red[3][tid] + fprba[tid];
    if (tid < 256) rbuf[tid] = u;
    __syncthreads();
    for (int s = 128; s > 0; s >>= 1) { if (tid < s) rbuf[tid] += rbuf[tid+s]; __syncthreads(); }
    const float mean = rbuf[0] * (1.f/256.f);
    __syncthreads();
    const float diff = u - mean;
    if (tid < 256) rbuf[tid] = diff*diff;
    __syncthreads();
    for (int s = 128; s > 0; s >>= 1) { if (tid < s) rbuf[tid] += rbuf[tid+s]; __syncthreads(); }
    const float var = rbuf[0] * (1.f/256.f);
    __syncthreads();
    if (tid < 256)
      vbuf[tid] = fmaxf(diff * rsqrtf(var + 1e-5f) * fprg[tid] + fprbeta[tid], 0.f);
    __syncthreads();
  }
  {
    // fprW1: 128 outs, K=256 split 8
    const int col = tid & 127, hs = tid >> 7;
    float a0 = 0.f, a1 = 0.f;
    const float* Wp = fprW1 + (size_t)(hs*32)*128 + col;
    const float* ip = vbuf + hs*32;
    #pragma unroll
    for (int j = 0; j < 16; ++j) {
      a0 += ip[j*2+0] * Wp[(size_t)(j*2+0)*128];
      a1 += ip[j*2+1] * Wp[(size_t)(j*2+1)*128];
    }
    redf[hs*128 + col] = a0 + a1;
  }
  __syncthreads();
  if (tid < 128) {
    float hv = fprb1[tid];
    #pragma unroll
    for (int s = 0; s < 8; ++s) hv += redf[s*128 + tid];
    h1s[tid] = fmaxf(hv, 0.f);
  }
  __syncthreads();
  if (tid < 5) {
    float ov = fprb2[tid];
    for (int hh = 0; hh < 128; ++hh) ov += h1s[hh] * fprW2[hh*5 + tid];
    out[5 + tid] = 1.f/(1.f + __expf(-ov));
  }
  __syncthreads();

  // ---- sec heads -> col 1 of rows 0..4 ----
  if (tid < 640) {
    const int ii = tid >> 7, col = tid & 127;
    float a0 = 0.f, a1 = 0.f, a2 = 0.f, a3 = 0.f;
    const float* Wp = secW1 + (size_t)ii*32768 + col;
    #pragma unroll
    for (int j = 0; j < 64; ++j) {
      a0 += esec[j*4+0] * Wp[(size_t)(j*4+0)*128];
      a1 += esec[j*4+1] * Wp[(size_t)(j*4+1)*128];
      a2 += esec[j*4+2] * Wp[(size_t)(j*4+2)*128];
      a3 += esec[j*4+3] * Wp[(size_t)(j*4+3)*128];
    }
    h1s[tid] = fmaxf((a0 + a1) + (a2 + a3) + secb1[ii*128 + col], 0.f);
  }
  __syncthreads();
  if (tid < 5) {
    float ov = secb2[tid];
    for (int hh = 0; hh < 128; ++hh) ov += h1s[tid*128 + hh] * secW2[tid*128 + hh];
    out[tid*5 + 1] = 1.f/(1.f + __expf(-ov));
  }
}

// ---------------- launcher ----------------
extern "C" void kernel_launch(void* const* d_in, const int* in_sizes, int n_in,
                              void* d_out, int out_size, void* d_ws, size_t ws_size,
                              hipStream_t stream)
{
  const float* x_nodes    = (const float*)d_in[0];
  const float* contract_x = (const float*)d_in[1];
  const float* proj_W     = (const float*)d_in[2];
  const float* proj_b     = (const float*)d_in[3];
  const float* conv_W     = (const float*)d_in[4];
  const float* conv_b     = (const float*)d_in[5];
  const float* norm_g     = (const float*)d_in[6];
  const float* norm_b     = (const float*)d_in[7];
  const float* attn_W     = (const float*)d_in[8];
  const float* attn_b     = (const float*)d_in[9];
  const float* pool_W     = (const float*)d_in[10];
  const float* pool_b     = (const float*)d_in[11];
  const float* contract_W = (const float*)d_in[12];
  const float* contract_b = (const float*)d_in[13];
  const float* ta_W1      = (const float*)d_in[14];
  const float* ta_b1      = (const float*)d_in[15];
  const float* ta_g       = (const float*)d_in[16];
  const float* ta_beta    = (const float*)d_in[17];
  const float* ta_W2      = (const float*)d_in[18];
  const float* ta_b2      = (const float*)d_in[19];
  const float* sh_W1      = (const float*)d_in[20];
  const float* sh_b1      = (const float*)d_in[21];
  const float* sh_W2      = (const float*)d_in[22];
  const float* sh_b2      = (const float*)d_in[23];
  const float* fpr_Wa     = (const float*)d_in[24];
  const float* fpr_ba     = (const float*)d_in[25];
  const float* fpr_g      = (const float*)d_in[26];
  const float* fpr_beta   = (const float*)d_in[27];
  const float* fpr_W1     = (const float*)d_in[28];
  const float* fpr_b1     = (const float*)d_in[29];
  const float* fpr_W2     = (const float*)d_in[30];
  const float* fpr_b2     = (const float*)d_in[31];
  const float* sec_W1     = (const float*)d_in[32];
  const float* sec_b1     = (const float*)d_in[33];
  const float* sec_W2     = (const float*)d_in[34];
  const float* sec_b2     = (const float*)d_in[35];
  const int*   edge_index = (const int*)d_in[36];

  float* ws = (float*)d_ws;
  float* X     = ws + WS_X;
  float* Y     = ws + WS_Y;
  int*   ints  = (int*)(ws + WS_INT);
  int*   CNTS  = ints + WS_CNTS;
  int*   OFFS  = ints + WS_OFFS;
  int*   CUR   = ints + WS_CUR;
  int*   ELIST = ints + WS_ELIST;
  ushort_t* MHI  = (ushort_t*)(ws + WS_M);
  ushort_t* MLO  = MHI + (size_t)12*1024*256;
  ushort_t* WQHI = (ushort_t*)(ws + WS_WQ);
  ushort_t* WQLO = WQHI + (size_t)12*65536;
  float* QKV   = ws + WS_QKV;
  ushort_t* QH = (ushort_t*)(ws + WS_BF);
  ushort_t* KH = (ushort_t*)(ws + WS_BF + 524288);
  ushort_t* VT = (ushort_t*)(ws + WS_BF + 1048576);
  float* PART  = ws + WS_PART;
  float* LOG   = ws + WS_LOG;
  float* STATS = ws + WS_STATS;

  hipMemsetAsync(CNTS, 0, (size_t)K_*NPT_*sizeof(int), stream);

  k_proj<<<dim3(4096), 256, 0, stream>>>(x_nodes, proj_W, proj_b, X);
  k_hist<<<dim3(1536), 256, 0, stream>>>(edge_index, CNTS);
  k_scan<<<dim3(48), 1024, 0, stream>>>(CNTS, OFFS, CUR);
  k_scatter<<<dim3(1536), 256, 0, stream>>>(edge_index, CUR, ELIST);

  for (int l = 0; l < L_; ++l) {
    for (int a = 0; a < 4; ++a) {
      k_means<<<dim3(3072), 256, 0, stream>>>(X, OFFS, ELIST, MHI, MLO, a);
      k_wprep<<<dim3(12, 8, 8), 256, 0, stream>>>(
          conv_W + ((size_t)(l*K_ + a*12))*65536, WQHI, WQLO);
      k_wxm<<<dim3(2, 8, 4), 256, 0, stream>>>(MHI, MLO, WQHI, WQLO, Y, a);
    }
    k_ln<<<dim3(4096), 256, 0, stream>>>(X, Y, CNTS, conv_b, norm_g, norm_b, l);
  }

  // qkv (fp32), then cast to bf16 fragments
  k_mm16<<<dim3(2, 256, 3), 256, 0, stream>>>(X, attn_W, attn_b, QKV, 65536, 256, 1048576);
  k_cast<<<dim3(64, 8), 256, 0, stream>>>(QKV, QH, KH, VT);
  // MFMA flash attention -> Y
  k_attn2<<<dim3(64, 8), 256, 0, stream>>>(QH, KH, VT, Y);
  // out projection -> z2 stored in QKV
  k_mm16<<<dim3(2, 256, 1), 256, 0, stream>>>(Y, attn_W + 3*65536, attn_b + 3*256, QKV, 0, 0, 0);
  // pooling
  k_pool_logits<<<dim3(1024), 256, 0, stream>>>(QKV, pool_W, pool_b, LOG);
  k_pool_stats<<<dim3(1), 256, 0, stream>>>(LOG, STATS);
  k_pool_partial<<<dim3(64), 256, 0, stream>>>(QKV, LOG, STATS, PART);
  // heads
  k_heads<<<dim3(1), 1024, 0, stream>>>(PART,
      contract_x, contract_W, contract_b,
      ta_W1, ta_b1, ta_g, ta_beta, ta_W2, ta_b2,
      sh_W1, sh_b1, sh_W2, sh_b2,
      fpr_Wa, fpr_ba, fpr_g, fpr_beta, fpr_W1, fpr_b1, fpr_W2, fpr_b2,
      sec_W1, sec_b1, sec_W2, sec_b2,
      (float*)d_out);
}

// Round 6
// 649.715 us; speedup vs baseline: 3.7639x; 1.1831x over previous
//
#include <hip/hip_runtime.h>
#include <cstddef>

typedef unsigned short ushort_t;
typedef __attribute__((ext_vector_type(8))) short bf16x8;
typedef __attribute__((ext_vector_type(4))) float f32x4;

// ---------------- constants ----------------
#define H_ 256
#define NPT_ 1024
#define E_ 8192
#define K_ 48
#define L_ 3

// ws layout in floats (~30.8 MB peak)
#define WS_X      0u          // X fp32 [4][1024][256]
#define WS_Y      1048576u    // conv GEMM accum / attn-merge out
#define WS_INT    2097152u    // int region
#define WS_CNTS   0u
#define WS_OFFS   49152u
#define WS_CUR    98352u
#define WS_ELIST  147504u
#define WS_M      2700288u    // Mhi/Mlo bf16 quarter (3145728 floats)
#define WS_QKV    2700288u    // QKV fp32 / PACC+PML during attention
#define WS_WQ     5846016u    // conv W quarter hi/lo (786432 floats)
#define WS_BF     5846016u    // bf16 Q/K/Vt post-conv (1572864 floats)
#define WS_PART   7418880u
#define WS_LOG    7435264u
#define WS_STATS  7439360u
#define WS_AW     7440000u    // attn_W hi/lo (262144 floats) -> end 7702144

__device__ __forceinline__ ushort_t f2bf(float x) {
  unsigned u = __float_as_uint(x);
  unsigned r = (u + 0x7FFFu + ((u >> 16) & 1u)) >> 16;
  return (ushort_t)r;
}
__device__ __forceinline__ float bf2f(ushort_t x) {
  return __uint_as_float(((unsigned)x) << 16);
}

// ---------------- proj ----------------
__global__ __launch_bounds__(256) void k_proj(const float* __restrict__ xn,
    const float* __restrict__ pW, const float* __restrict__ pb,
    float* __restrict__ x)
{
  const int t = blockIdx.x >> 10, n = blockIdx.x & 1023;
  const int tid = threadIdx.x;
  __shared__ float xr[32];
  if (tid < 21) xr[tid] = xn[(size_t)(t*1024 + n)*21 + tid];
  __syncthreads();
  float acc = pb[t*256 + tid];
  #pragma unroll
  for (int i = 0; i < 21; ++i) acc += xr[i] * pW[(size_t)(t*21 + i)*256 + tid];
  x[(size_t)(t*1024 + n)*256 + tid] = acc;
}

// ---------------- CSR build ----------------
__global__ __launch_bounds__(256) void k_hist(const int* __restrict__ ei, int* __restrict__ cnts)
{
  const int gid = blockIdx.x*256 + threadIdx.x;
  const int k = gid >> 13, e = gid & 8191;
  const int dst = ei[(size_t)k*2*E_ + E_ + e];
  atomicAdd(&cnts[k*1024 + dst], 1);
}

__global__ __launch_bounds__(1024) void k_scan(const int* __restrict__ cnts,
    int* __restrict__ offs, int* __restrict__ cur)
{
  const int k = blockIdx.x, tid = threadIdx.x;
  __shared__ int s[1024];
  const int v = cnts[k*1024 + tid];
  s[tid] = v; __syncthreads();
  for (int off = 1; off < 1024; off <<= 1) {
    int add = 0;
    if (tid >= off) add = s[tid - off];
    __syncthreads();
    s[tid] += add;
    __syncthreads();
  }
  const int ex = s[tid] - v;
  offs[k*1025 + tid] = ex;
  cur[k*1024 + tid] = ex;
  if (tid == 1023) offs[k*1025 + 1024] = s[1023];
}

__global__ __launch_bounds__(256) void k_scatter(const int* __restrict__ ei,
    int* __restrict__ cur, int* __restrict__ elist)
{
  const int gid = blockIdx.x*256 + threadIdx.x;
  const int k = gid >> 13, e = gid & 8191;
  const int src = ei[(size_t)k*2*E_ + e];
  const int dst = ei[(size_t)k*2*E_ + E_ + e];
  const int p = atomicAdd(&cur[k*1024 + dst], 1);
  elist[k*E_ + p] = src;
}

// ---------------- means: M[kl][d] = mean of X[a] rows (hi/lo bf16 out) ----------------
__global__ __launch_bounds__(256) void k_means(const float* __restrict__ X,
    const int* __restrict__ offs, const int* __restrict__ elist,
    ushort_t* __restrict__ Mhi, ushort_t* __restrict__ Mlo, int a)
{
  const int pid = blockIdx.x*4 + (threadIdx.x >> 6);
  const int kl = pid >> 10, d = pid & 1023;
  const int lane = threadIdx.x & 63;
  const int kg = a*12 + kl;
  const int o0 = offs[kg*1025 + d];
  const int o1 = offs[kg*1025 + d + 1];
  const float* xb = X + (size_t)a*1024*256;
  float4 s = {0.f, 0.f, 0.f, 0.f};
  int p = o0;
  while (p + 4 <= o1) {
    const int s0 = elist[(size_t)kg*E_ + p + 0];
    const int s1 = elist[(size_t)kg*E_ + p + 1];
    const int s2 = elist[(size_t)kg*E_ + p + 2];
    const int s3 = elist[(size_t)kg*E_ + p + 3];
    const float4 v0 = *reinterpret_cast<const float4*>(xb + (size_t)s0*256 + lane*4);
    const float4 v1 = *reinterpret_cast<const float4*>(xb + (size_t)s1*256 + lane*4);
    const float4 v2 = *reinterpret_cast<const float4*>(xb + (size_t)s2*256 + lane*4);
    const float4 v3 = *reinterpret_cast<const float4*>(xb + (size_t)s3*256 + lane*4);
    s.x += v0.x + v1.x + v2.x + v3.x;
    s.y += v0.y + v1.y + v2.y + v3.y;
    s.z += v0.z + v1.z + v2.z + v3.z;
    s.w += v0.w + v1.w + v2.w + v3.w;
    p += 4;
  }
  while (p < o1) {
    const int sp = elist[(size_t)kg*E_ + p];
    const float4 v = *reinterpret_cast<const float4*>(xb + (size_t)sp*256 + lane*4);
    s.x += v.x; s.y += v.y; s.z += v.z; s.w += v.w;
    ++p;
  }
  const float inv = 1.f / fmaxf((float)(o1 - o0), 1.f);
  const float mv[4] = {s.x*inv, s.y*inv, s.z*inv, s.w*inv};
  ushort_t hi[4], lo[4];
  #pragma unroll
  for (int e = 0; e < 4; ++e) {
    hi[e] = f2bf(mv[e]);
    lo[e] = f2bf(mv[e] - bf2f(hi[e]));
  }
  const size_t base = ((size_t)kl*1024 + d)*256 + lane*4;
  *reinterpret_cast<ushort4*>(Mhi + base) = *reinterpret_cast<const ushort4*>(hi);
  *reinterpret_cast<ushort4*>(Mlo + base) = *reinterpret_cast<const ushort4*>(lo);
}

// ---------------- W prep: transpose + hi/lo split ----------------
// grid (nmat, 8, 8), block 256
__global__ __launch_bounds__(256) void k_wprep(const float* __restrict__ Wsrc,
    ushort_t* __restrict__ Whi, ushort_t* __restrict__ Wlo)
{
  const int kl = blockIdx.x, hb = blockIdx.y, gb = blockIdx.z;
  const int tid = threadIdx.x;
  __shared__ float tile[32][33];
  const float* W = Wsrc + (size_t)kl*65536;
  const int r0 = tid >> 5, c = tid & 31;
  #pragma unroll
  for (int it = 0; it < 4; ++it) {
    const int r = it*8 + r0;
    tile[r][c] = W[(size_t)(hb*32 + r)*256 + gb*32 + c];
  }
  __syncthreads();
  #pragma unroll
  for (int it = 0; it < 4; ++it) {
    const int g = it*8 + r0, h = c;
    const float v = tile[h][g];
    const ushort_t hi = f2bf(v);
    const ushort_t lo = f2bf(v - bf2f(hi));
    const size_t off = (size_t)kl*65536 + (size_t)(gb*32 + g)*256 + hb*32 + h;
    Whi[off] = hi;
    Wlo[off] = lo;
  }
}

// ---------------- conv GEMM: Y[t] (+)= sum_c M[t*3+c] @ Wq[t*3+c] (64x64 tiles) ----------------
// grid (cb=4, rb=16, t=4), block 256 (4 waves of 16x64)
__global__ __launch_bounds__(256) void k_wxm(const ushort_t* __restrict__ Mhi,
    const ushort_t* __restrict__ Mlo, const ushort_t* __restrict__ Wqhi,
    const ushort_t* __restrict__ Wqlo, float* __restrict__ Y, int a)
{
  const int cb = blockIdx.x, rb = blockIdx.y, t = blockIdx.z;
  const int tid = threadIdx.x, wave = tid >> 6, lane = tid & 63;
  const int lrow = lane & 15, lgrp = lane >> 4;
  __shared__ __align__(16) ushort_t AswH[64*64];
  __shared__ __align__(16) ushort_t AswL[64*64];
  __shared__ __align__(16) ushort_t BswH[64*64];
  __shared__ __align__(16) ushort_t BswL[64*64];
  f32x4 acc[4];
  #pragma unroll
  for (int j = 0; j < 4; ++j) acc[j] = (f32x4){0.f,0.f,0.f,0.f};

  for (int c = 0; c < 3; ++c) {
    const int kl = t*3 + c;
    const ushort_t* Ah = Mhi + ((size_t)kl*1024 + rb*64)*256;
    const ushort_t* Al = Mlo + ((size_t)kl*1024 + rb*64)*256;
    const ushort_t* Bh = Wqhi + (size_t)kl*65536 + (size_t)cb*64*256;
    const ushort_t* Bl = Wqlo + (size_t)kl*65536 + (size_t)cb*64*256;
    for (int ks = 0; ks < 4; ++ks) {
      __syncthreads();
      #pragma unroll
      for (int it = 0; it < 2; ++it) {
        const int idx = tid + it*256;     // 0..511: 64 rows x 8 c8
        const int row = idx >> 3, c8 = idx & 7;
        const int off = row*64 + ((c8 ^ (row & 7)) << 3);
        const size_t gsrc = (size_t)row*256 + ks*64 + c8*8;
        *reinterpret_cast<bf16x8*>(&AswH[off]) = *reinterpret_cast<const bf16x8*>(Ah + gsrc);
        *reinterpret_cast<bf16x8*>(&AswL[off]) = *reinterpret_cast<const bf16x8*>(Al + gsrc);
        *reinterpret_cast<bf16x8*>(&BswH[off]) = *reinterpret_cast<const bf16x8*>(Bh + gsrc);
        *reinterpret_cast<bf16x8*>(&BswL[off]) = *reinterpret_cast<const bf16x8*>(Bl + gsrc);
      }
      __syncthreads();
      #pragma unroll
      for (int ksub = 0; ksub < 2; ++ksub) {
        const int c8 = ksub*4 + lgrp;
        const int arow = wave*16 + lrow;
        const int aoff = arow*64 + ((c8 ^ (arow & 7)) << 3);
        const bf16x8 ah = *reinterpret_cast<const bf16x8*>(&AswH[aoff]);
        const bf16x8 al = *reinterpret_cast<const bf16x8*>(&AswL[aoff]);
        #pragma unroll
        for (int nf = 0; nf < 4; ++nf) {
          const int g = nf*16 + lrow;
          const int boff = g*64 + ((c8 ^ (g & 7)) << 3);
          const bf16x8 bh = *reinterpret_cast<const bf16x8*>(&BswH[boff]);
          const bf16x8 bl = *reinterpret_cast<const bf16x8*>(&BswL[boff]);
          __builtin_amdgcn_s_setprio(1);
          acc[nf] = __builtin_amdgcn_mfma_f32_16x16x32_bf16(ah, bh, acc[nf], 0, 0, 0);
          acc[nf] = __builtin_amdgcn_mfma_f32_16x16x32_bf16(ah, bl, acc[nf], 0, 0, 0);
          acc[nf] = __builtin_amdgcn_mfma_f32_16x16x32_bf16(al, bh, acc[nf], 0, 0, 0);
          __builtin_amdgcn_s_setprio(0);
        }
      }
    }
  }
  float* Cb = Y + ((size_t)(t*1024 + rb*64))*256 + cb*64;
  #pragma unroll
  for (int nf = 0; nf < 4; ++nf)
    #pragma unroll
    for (int r = 0; r < 4; ++r) {
      const int row = wave*16 + lgrp*4 + r;
      const int col = nf*16 + lrow;
      if (a == 0) Cb[(size_t)row*256 + col] = acc[nf][r];
      else        Cb[(size_t)row*256 + col] += acc[nf][r];
    }
}

// ---------------- bias-gate + residual + LN + relu ----------------
__global__ __launch_bounds__(256) void k_ln(float* __restrict__ x,
    const float* __restrict__ y, const int* __restrict__ cnts,
    const float* __restrict__ convB, const float* __restrict__ ng,
    const float* __restrict__ nb, int l)
{
  const int r = blockIdx.x;
  const int t = r >> 10, d = r & 1023;
  const int tid = threadIdx.x;
  __shared__ float flag[12];
  __shared__ float rbuf[256];
  if (tid < 12) {
    const int a = tid / 3, c = tid - a*3;
    const int kj = a*12 + t*3 + c;
    flag[tid] = (cnts[kj*1024 + d] > 0) ? 1.f : 0.f;
  }
  __syncthreads();
  float v = y[(size_t)r*256 + tid] + x[(size_t)r*256 + tid];
  #pragma unroll
  for (int j = 0; j < 12; ++j) {
    const int a = j / 3, c = j - a*3;
    const int kj = a*12 + t*3 + c;
    v += flag[j] * convB[(size_t)(l*K_ + kj)*256 + tid];
  }
  rbuf[tid] = v; __syncthreads();
  for (int s = 128; s > 0; s >>= 1) { if (tid < s) rbuf[tid] += rbuf[tid+s]; __syncthreads(); }
  const float mean = rbuf[0] * (1.f/256.f); __syncthreads();
  const float diff = v - mean;
  rbuf[tid] = diff*diff; __syncthreads();
  for (int s = 128; s > 0; s >>= 1) { if (tid < s) rbuf[tid] += rbuf[tid+s]; __syncthreads(); }
  const float var = rbuf[0] * (1.f/256.f); __syncthreads();
  const float xn = diff * rsqrtf(var + 1e-5f) * ng[(size_t)(l*4 + t)*256 + tid]
                 + nb[(size_t)(l*4 + t)*256 + tid];
  x[(size_t)r*256 + tid] = fmaxf(xn, 0.f);
}

// ---------------- MFMA GEMM: C[i] = A @ Wt[i] + bias (A fp32, B pre-split hi/lo) ----------------
// grid (ncb, 32), block 256 (4 waves of 64x64 in 128x128 tile)
__global__ __launch_bounds__(256) void k_gemm(const float* __restrict__ A,
    const ushort_t* __restrict__ Bh, const ushort_t* __restrict__ Bl,
    const float* __restrict__ bias, float* __restrict__ C)
{
  const int cb = blockIdx.x, rb = blockIdx.y;
  const int col0 = cb*128, i = col0 >> 8, g0 = col0 & 255;
  const int tid = threadIdx.x, wave = tid >> 6, lane = tid & 63;
  const int lrow = lane & 15, lgrp = lane >> 4;
  const int wr = wave >> 1, wc = wave & 1;
  __shared__ __align__(16) ushort_t AswH[128*64];
  __shared__ __align__(16) ushort_t AswL[128*64];
  __shared__ __align__(16) ushort_t BswH[128*64];
  __shared__ __align__(16) ushort_t BswL[128*64];
  const float* Ab = A + (size_t)rb*128*256;
  const ushort_t* Bhp = Bh + (size_t)i*65536 + (size_t)g0*256;
  const ushort_t* Blp = Bl + (size_t)i*65536 + (size_t)g0*256;
  f32x4 acc[4][4];
  #pragma unroll
  for (int m = 0; m < 4; ++m)
    #pragma unroll
    for (int n = 0; n < 4; ++n) acc[m][n] = (f32x4){0.f,0.f,0.f,0.f};

  for (int ks = 0; ks < 4; ++ks) {
    __syncthreads();
    // stage A fp32 -> hi/lo swizzled
    #pragma unroll
    for (int it = 0; it < 8; ++it) {
      const int idx = tid + it*256;       // 0..2047: 128 rows x 16 c4
      const int row = idx >> 4, c4 = idx & 15;
      const float4 v = *reinterpret_cast<const float4*>(Ab + (size_t)row*256 + ks*64 + c4*4);
      const float f[4] = {v.x, v.y, v.z, v.w};
      ushort_t hi[4], lo[4];
      #pragma unroll
      for (int e = 0; e < 4; ++e) {
        hi[e] = f2bf(f[e]);
        lo[e] = f2bf(f[e] - bf2f(hi[e]));
      }
      const int c8 = c4 >> 1, sub = (c4 & 1) * 4;
      const int off = row*64 + ((c8 ^ (row & 7)) << 3) + sub;
      *reinterpret_cast<uint2*>(&AswH[off]) = *reinterpret_cast<const uint2*>(hi);
      *reinterpret_cast<uint2*>(&AswL[off]) = *reinterpret_cast<const uint2*>(lo);
    }
    // stage B (pre-split) swizzled
    #pragma unroll
    for (int it = 0; it < 4; ++it) {
      const int idx = tid + it*256;       // 0..1023: 128 g x 8 c8
      const int row = idx >> 3, c8 = idx & 7;
      const int off = row*64 + ((c8 ^ (row & 7)) << 3);
      const size_t gsrc = (size_t)row*256 + ks*64 + c8*8;
      *reinterpret_cast<bf16x8*>(&BswH[off]) = *reinterpret_cast<const bf16x8*>(Bhp + gsrc);
      *reinterpret_cast<bf16x8*>(&BswL[off]) = *reinterpret_cast<const bf16x8*>(Blp + gsrc);
    }
    __syncthreads();
    #pragma unroll
    for (int ksub = 0; ksub < 2; ++ksub) {
      bf16x8 ah[4], al[4], bh[4], bl[4];
      const int c8 = ksub*4 + lgrp;
      #pragma unroll
      for (int mf = 0; mf < 4; ++mf) {
        const int row = wr*64 + mf*16 + lrow;
        const int off = row*64 + ((c8 ^ (row & 7)) << 3);
        ah[mf] = *reinterpret_cast<const bf16x8*>(&AswH[off]);
        al[mf] = *reinterpret_cast<const bf16x8*>(&AswL[off]);
      }
      #pragma unroll
      for (int nf = 0; nf < 4; ++nf) {
        const int row = wc*64 + nf*16 + lrow;
        const int off = row*64 + ((c8 ^ (row & 7)) << 3);
        bh[nf] = *reinterpret_cast<const bf16x8*>(&BswH[off]);
        bl[nf] = *reinterpret_cast<const bf16x8*>(&BswL[off]);
      }
      __builtin_amdgcn_s_setprio(1);
      #pragma unroll
      for (int mf = 0; mf < 4; ++mf)
        #pragma unroll
        for (int nf = 0; nf < 4; ++nf) {
          acc[mf][nf] = __builtin_amdgcn_mfma_f32_16x16x32_bf16(ah[mf], bh[nf], acc[mf][nf], 0, 0, 0);
          acc[mf][nf] = __builtin_amdgcn_mfma_f32_16x16x32_bf16(ah[mf], bl[nf], acc[mf][nf], 0, 0, 0);
          acc[mf][nf] = __builtin_amdgcn_mfma_f32_16x16x32_bf16(al[mf], bh[nf], acc[mf][nf], 0, 0, 0);
        }
      __builtin_amdgcn_s_setprio(0);
    }
  }
  float* Cp = C + (size_t)i*1048576 + (size_t)rb*128*256 + g0;
  const float* bp = bias + i*256 + g0;
  #pragma unroll
  for (int mf = 0; mf < 4; ++mf)
    #pragma unroll
    for (int nf = 0; nf < 4; ++nf)
      #pragma unroll
      for (int r = 0; r < 4; ++r) {
        const int row = wr*64 + mf*16 + lgrp*4 + r;
        const int col = wc*64 + nf*16 + lrow;
        Cp[(size_t)row*256 + col] = acc[mf][nf][r] + bp[col];
      }
}

// ---------------- cast QKV fp32 -> bf16 (Q scaled, V transposed) ----------------
__global__ __launch_bounds__(256) void k_cast(const float* __restrict__ qkv,
    ushort_t* __restrict__ Qh, ushort_t* __restrict__ Kh, ushort_t* __restrict__ Vt)
{
  const int rb = blockIdx.x, h = blockIdx.y;
  const int tid = threadIdx.x;
  const int r = tid >> 2, c8 = (tid & 3) * 8;
  const int row = rb*64 + r;
  __shared__ ushort_t vt[32][72];
  {
    const float* src = qkv + (size_t)row*256 + h*32 + c8;
    ushort_t tmp[8];
    #pragma unroll
    for (int j = 0; j < 8; ++j) tmp[j] = f2bf(src[j] * 0.17677669529663687f);
    *reinterpret_cast<uint4*>(Qh + ((size_t)(h*4096 + row))*32 + c8) = *reinterpret_cast<uint4*>(tmp);
  }
  {
    const float* src = qkv + 1048576 + (size_t)row*256 + h*32 + c8;
    ushort_t tmp[8];
    #pragma unroll
    for (int j = 0; j < 8; ++j) tmp[j] = f2bf(src[j]);
    *reinterpret_cast<uint4*>(Kh + ((size_t)(h*4096 + row))*32 + c8) = *reinterpret_cast<uint4*>(tmp);
  }
  {
    const float* src = qkv + 2097152 + (size_t)row*256 + h*32 + c8;
    #pragma unroll
    for (int j = 0; j < 8; ++j) vt[c8 + j][r] = f2bf(src[j]);
  }
  __syncthreads();
  const int d2 = tid >> 3, r0 = (tid & 7) * 8;
  *reinterpret_cast<uint4*>(Vt + ((size_t)(h*32 + d2))*4096 + rb*64 + r0)
      = *reinterpret_cast<const uint4*>(&vt[d2][r0]);
}

// ---------------- MFMA flash attention, KVBLK=128, 2-way key split ----------------
// grid (64, 8, 2), block 256 (4 waves x 16 q-rows)
__global__ __launch_bounds__(256) void k_attn2(const ushort_t* __restrict__ Qh,
    const ushort_t* __restrict__ Kh, const ushort_t* __restrict__ Vt,
    float* __restrict__ pacc, float* __restrict__ pml)
{
  const int tid = threadIdx.x;
  const int wave = tid >> 6, lane = tid & 63;
  const int lrow = lane & 15, lgrp = lane >> 4;
  const int h = blockIdx.y, sp = blockIdx.z;
  const int q0 = blockIdx.x * 64 + wave * 16;
  __shared__ ushort_t P[4][16][136];

  const bf16x8 qf = *reinterpret_cast<const bf16x8*>(
      Qh + ((size_t)(h*4096 + q0 + lrow))*32 + lgrp*8);

  float m[4], l[4];
  f32x4 o0 = {0.f,0.f,0.f,0.f}, o1 = {0.f,0.f,0.f,0.f};
  #pragma unroll
  for (int r = 0; r < 4; ++r) { m[r] = -1e30f; l[r] = 0.f; }

  const ushort_t* Kbase = Kh + (size_t)(h*4096)*32;
  const ushort_t* Vbase = Vt + (size_t)(h*32)*4096;

  for (int kt = 0; kt < 16; ++kt) {
    const int kb = sp*2048 + kt*128;
    f32x4 s[8];
    __builtin_amdgcn_s_setprio(1);
    #pragma unroll
    for (int ks = 0; ks < 8; ++ks) {
      const bf16x8 kf = *reinterpret_cast<const bf16x8*>(
          Kbase + (size_t)(kb + ks*16 + lrow)*32 + lgrp*8);
      f32x4 z = {0.f,0.f,0.f,0.f};
      s[ks] = __builtin_amdgcn_mfma_f32_16x16x32_bf16(qf, kf, z, 0, 0, 0);
    }
    __builtin_amdgcn_s_setprio(0);
    #pragma unroll
    for (int r = 0; r < 4; ++r) {
      float mx = fmaxf(fmaxf(fmaxf(s[0][r], s[1][r]), fmaxf(s[2][r], s[3][r])),
                       fmaxf(fmaxf(s[4][r], s[5][r]), fmaxf(s[6][r], s[7][r])));
      mx = fmaxf(mx, __shfl_xor(mx, 1));
      mx = fmaxf(mx, __shfl_xor(mx, 2));
      mx = fmaxf(mx, __shfl_xor(mx, 4));
      mx = fmaxf(mx, __shfl_xor(mx, 8));
      const float mnew = fmaxf(m[r], mx);
      const float corr = __expf(m[r] - mnew);
      m[r] = mnew;
      float ps = 0.f;
      #pragma unroll
      for (int ks = 0; ks < 8; ++ks) {
        const float p = __expf(s[ks][r] - mnew);
        s[ks][r] = p; ps += p;
      }
      ps += __shfl_xor(ps, 1); ps += __shfl_xor(ps, 2);
      ps += __shfl_xor(ps, 4); ps += __shfl_xor(ps, 8);
      l[r] = l[r]*corr + ps;
      o0[r] *= corr; o1[r] *= corr;
    }
    #pragma unroll
    for (int ks = 0; ks < 8; ++ks)
      #pragma unroll
      for (int r = 0; r < 4; ++r)
        P[wave][lgrp*4 + r][ks*16 + lrow] = f2bf(s[ks][r]);
    __builtin_amdgcn_s_setprio(1);
    #pragma unroll
    for (int ks2 = 0; ks2 < 4; ++ks2) {
      const bf16x8 pa = *reinterpret_cast<const bf16x8*>(&P[wave][lrow][ks2*32 + lgrp*8]);
      const bf16x8 v0 = *reinterpret_cast<const bf16x8*>(
          Vbase + (size_t)lrow*4096 + kb + ks2*32 + lgrp*8);
      const bf16x8 v1 = *reinterpret_cast<const bf16x8*>(
          Vbase + (size_t)(16 + lrow)*4096 + kb + ks2*32 + lgrp*8);
      o0 = __builtin_amdgcn_mfma_f32_16x16x32_bf16(pa, v0, o0, 0, 0, 0);
      o1 = __builtin_amdgcn_mfma_f32_16x16x32_bf16(pa, v1, o1, 0, 0, 0);
    }
    __builtin_amdgcn_s_setprio(0);
  }
  #pragma unroll
  for (int r = 0; r < 4; ++r) {
    const int row = q0 + lgrp*4 + r;
    const size_t base = (size_t)sp*1048576 + ((size_t)row*8 + h)*32;
    pacc[base + lrow]      = o0[r];
    pacc[base + 16 + lrow] = o1[r];
    if (lrow == 0) {
      pml[((size_t)row*8 + h)*4 + sp*2 + 0] = m[r];
      pml[((size_t)row*8 + h)*4 + sp*2 + 1] = l[r];
    }
  }
}

__global__ __launch_bounds__(256) void k_attn_merge(const float* __restrict__ pacc,
    const float* __restrict__ pml, float* __restrict__ attno)
{
  const int gid = blockIdx.x*256 + threadIdx.x;      // 4096*8*32
  const int rh = gid >> 5, d = gid & 31;
  const int r = rh >> 3, h = rh & 7;
  const float m0 = pml[rh*4+0], l0 = pml[rh*4+1];
  const float m1 = pml[rh*4+2], l1 = pml[rh*4+3];
  const float mx = fmaxf(m0, m1);
  const float e0 = __expf(m0 - mx), e1 = __expf(m1 - mx);
  const float den = l0*e0 + l1*e1;
  const float o = (pacc[(size_t)rh*32 + d]*e0 + pacc[1048576 + (size_t)rh*32 + d]*e1) / den;
  attno[(size_t)r*256 + h*32 + d] = o;
}

// ---------------- pooling ----------------
__global__ __launch_bounds__(256) void k_pool_logits(const float* __restrict__ z,
    const float* __restrict__ pW, const float* __restrict__ pb, float* __restrict__ logits)
{
  const int tid = threadIdx.x;
  const int wave = tid >> 6, lane = tid & 63;
  const int r = blockIdx.x*4 + wave;
  const float4 zv = reinterpret_cast<const float4*>(z + (size_t)r*256)[lane];
  const float4 wv = reinterpret_cast<const float4*>(pW)[lane];
  float dv = zv.x*wv.x + zv.y*wv.y + zv.z*wv.z + zv.w*wv.w;
  for (int off = 32; off; off >>= 1) dv += __shfl_down(dv, off);
  if (lane == 0) logits[r] = dv + pb[0];
}

__global__ __launch_bounds__(256) void k_pool_stats(const float* __restrict__ logits,
    float* __restrict__ stats)
{
  const int tid = threadIdx.x;
  __shared__ float rbuf[256];
  float mx = -1e30f;
  for (int i = tid; i < 4096; i += 256) mx = fmaxf(mx, logits[i]);
  rbuf[tid] = mx; __syncthreads();
  for (int s = 128; s > 0; s >>= 1) { if (tid < s) rbuf[tid] = fmaxf(rbuf[tid], rbuf[tid+s]); __syncthreads(); }
  mx = rbuf[0]; __syncthreads();
  float se = 0.f;
  for (int i = tid; i < 4096; i += 256) se += __expf(logits[i] - mx);
  rbuf[tid] = se; __syncthreads();
  for (int s = 128; s > 0; s >>= 1) { if (tid < s) rbuf[tid] += rbuf[tid+s]; __syncthreads(); }
  if (tid == 0) { stats[0] = mx; stats[1] = rbuf[0]; }
}

__global__ __launch_bounds__(256) void k_pool_partial(const float* __restrict__ z,
    const float* __restrict__ logits, const float* __restrict__ stats,
    float* __restrict__ partial)
{
  const int pb = blockIdx.x, tid = threadIdx.x;
  const float mx = stats[0], se = stats[1];
  __shared__ float wl[64];
  if (tid < 64) wl[tid] = __expf(logits[pb*64 + tid] - mx) / se;
  __syncthreads();
  float acc = 0.f;
  for (int n = 0; n < 64; ++n) acc += wl[n] * z[(size_t)(pb*64 + n)*256 + tid];
  partial[pb*256 + tid] = acc;
}

// ---------------- heads helpers ----------------
__device__ __forceinline__ void mv256(const float* __restrict__ W,
    const float* __restrict__ sIn, float (*red)[256], int o, int hq)
{
  float a0 = 0.f, a1 = 0.f, a2 = 0.f, a3 = 0.f;
  const float* Wp = W + (size_t)(hq*64)*256 + o;
  const float* ip = sIn + hq*64;
  #pragma unroll
  for (int j = 0; j < 16; ++j) {
    a0 += ip[j*4+0] * Wp[(size_t)(j*4+0)*256];
    a1 += ip[j*4+1] * Wp[(size_t)(j*4+1)*256];
    a2 += ip[j*4+2] * Wp[(size_t)(j*4+2)*256];
    a3 += ip[j*4+3] * Wp[(size_t)(j*4+3)*256];
  }
  red[hq][o] = (a0 + a1) + (a2 + a3);
}

// ---------------- heads (single block, 1024 threads) ----------------
__global__ __launch_bounds__(1024) void k_heads(
    const float* __restrict__ partial,
    const float* __restrict__ cx, const float* __restrict__ cW, const float* __restrict__ cb,
    const float* __restrict__ taW1, const float* __restrict__ tab1,
    const float* __restrict__ tag, const float* __restrict__ tabeta,
    const float* __restrict__ taW2, const float* __restrict__ tab2,
    const float* __restrict__ shW1, const float* __restrict__ shb1,
    const float* __restrict__ shW2, const float* __restrict__ shb2,
    const float* __restrict__ fprWa, const float* __restrict__ fprba,
    const float* __restrict__ fprg, const float* __restrict__ fprbeta,
    const float* __restrict__ fprW1, const float* __restrict__ fprb1,
    const float* __restrict__ fprW2, const float* __restrict__ fprb2,
    const float* __restrict__ secW1, const float* __restrict__ secb1,
    const float* __restrict__ secW2, const float* __restrict__ secb2,
    float* __restrict__ out)
{
  const int tid = threadIdx.x;
  const int o = tid & 255, hq = tid >> 8;
  __shared__ float semb[256], esec[256], efpr[256], vbuf[256];
  __shared__ float red[4][256];
  __shared__ float rbuf[256];
  __shared__ float h1s[640];
  float* redf = &red[0][0];

  {
    float acc = 0.f;
    #pragma unroll
    for (int pb = 0; pb < 16; ++pb) acc += partial[(hq*16 + pb)*256 + o];
    #pragma unroll
    for (int i = 0; i < 8; ++i) acc += cx[hq*8 + i] * cW[(hq*8 + i)*256 + o];
    red[hq][o] = acc;
  }
  __syncthreads();
  if (tid < 256) semb[tid] = red[0][tid] + red[1][tid] + red[2][tid] + red[3][tid] + cb[tid];
  __syncthreads();

  for (int i = 0; i < 2; ++i) {
    mv256(taW1 + (size_t)i*65536, semb, red, o, hq);
    __syncthreads();
    float u = 0.f;
    if (tid < 256) u = red[0][tid] + red[1][tid] + red[2][tid] + red[3][tid] + tab1[i*256 + tid];
    if (tid < 256) rbuf[tid] = u;
    __syncthreads();
    for (int s = 128; s > 0; s >>= 1) { if (tid < s) rbuf[tid] += rbuf[tid+s]; __syncthreads(); }
    const float mean = rbuf[0] * (1.f/256.f);
    __syncthreads();
    const float diff = u - mean;
    if (tid < 256) rbuf[tid] = diff*diff;
    __syncthreads();
    for (int s = 128; s > 0; s >>= 1) { if (tid < s) rbuf[tid] += rbuf[tid+s]; __syncthreads(); }
    const float var = rbuf[0] * (1.f/256.f);
    __syncthreads();
    if (tid < 256)
      vbuf[tid] = fmaxf(diff * rsqrtf(var + 1e-5f) * tag[i*256 + tid] + tabeta[i*256 + tid], 0.f);
    __syncthreads();
    mv256(taW2 + (size_t)i*65536, vbuf, red, o, hq);
    __syncthreads();
    if (tid < 256) {
      const float s2v = red[0][tid] + red[1][tid] + red[2][tid] + red[3][tid] + tab2[i*256 + tid];
      const float att = semb[tid] * (1.f/(1.f + __expf(-s2v)));
      if (i == 0) esec[tid] = att; else efpr[tid] = att;
    }
    __syncthreads();
  }

  {
    const int oo = tid & 511, ii = oo >> 7, col = oo & 127, hh = tid >> 9;
    float a0 = 0.f, a1 = 0.f, a2 = 0.f, a3 = 0.f;
    const float* Wp = shW1 + (size_t)ii*32768 + (size_t)(hh*128)*128 + col;
    const float* ip = semb + hh*128;
    #pragma unroll
    for (int j = 0; j < 32; ++j) {
      a0 += ip[j*4+0] * Wp[(size_t)(j*4+0)*128];
      a1 += ip[j*4+1] * Wp[(size_t)(j*4+1)*128];
      a2 += ip[j*4+2] * Wp[(size_t)(j*4+2)*128];
      a3 += ip[j*4+3] * Wp[(size_t)(j*4+3)*128];
    }
    redf[hh*512 + oo] = (a0 + a1) + (a2 + a3);
  }
  __syncthreads();
  if (tid < 512) {
    const int ii = tid >> 7, col = tid & 127;
    h1s[tid] = fmaxf(redf[tid] + redf[512 + tid] + shb1[ii*128 + col], 0.f);
  }
  __syncthreads();
  if (tid < 20) {
    const int ii = tid / 5, c = tid % 5;
    const int rowm = (ii == 0) ? 0 : (ii + 1);
    float ov = shb2[ii*5 + c];
    for (int hh = 0; hh < 128; ++hh) ov += h1s[ii*128 + hh] * shW2[ii*640 + hh*5 + c];
    out[rowm*5 + c] = 1.f/(1.f + __expf(-ov));
  }

  mv256(fprWa, efpr, red, o, hq);
  __syncthreads();
  {
    float u = 0.f;
    if (tid < 256) u = red[0][tid] + red[1][tid] + red[2][tid] + red[3][tid] + fprba[tid];
    if (tid < 256) rbuf[tid] = u;
    __syncthreads();
    for (int s = 128; s > 0; s >>= 1) { if (tid < s) rbuf[tid] += rbuf[tid+s]; __syncthreads(); }
    const float mean = rbuf[0] * (1.f/256.f);
    __syncthreads();
    const float diff = u - mean;
    if (tid < 256) rbuf[tid] = diff*diff;
    __syncthreads();
    for (int s = 128; s > 0; s >>= 1) { if (tid < s) rbuf[tid] += rbuf[tid+s]; __syncthreads(); }
    const float var = rbuf[0] * (1.f/256.f);
    __syncthreads();
    if (tid < 256)
      vbuf[tid] = fmaxf(diff * rsqrtf(var + 1e-5f) * fprg[tid] + fprbeta[tid], 0.f);
    __syncthreads();
  }
  {
    const int col = tid & 127, hs = tid >> 7;
    float a0 = 0.f, a1 = 0.f;
    const float* Wp = fprW1 + (size_t)(hs*32)*128 + col;
    const float* ip = vbuf + hs*32;
    #pragma unroll
    for (int j = 0; j < 16; ++j) {
      a0 += ip[j*2+0] * Wp[(size_t)(j*2+0)*128];
      a1 += ip[j*2+1] * Wp[(size_t)(j*2+1)*128];
    }
    redf[hs*128 + col] = a0 + a1;
  }
  __syncthreads();
  if (tid < 128) {
    float hv = fprb1[tid];
    #pragma unroll
    for (int s = 0; s < 8; ++s) hv += redf[s*128 + tid];
    h1s[tid] = fmaxf(hv, 0.f);
  }
  __syncthreads();
  if (tid < 5) {
    float ov = fprb2[tid];
    for (int hh = 0; hh < 128; ++hh) ov += h1s[hh] * fprW2[hh*5 + tid];
    out[5 + tid] = 1.f/(1.f + __expf(-ov));
  }
  __syncthreads();

  if (tid < 640) {
    const int ii = tid >> 7, col = tid & 127;
    float a0 = 0.f, a1 = 0.f, a2 = 0.f, a3 = 0.f;
    const float* Wp = secW1 + (size_t)ii*32768 + col;
    #pragma unroll
    for (int j = 0; j < 64; ++j) {
      a0 += esec[j*4+0] * Wp[(size_t)(j*4+0)*128];
      a1 += esec[j*4+1] * Wp[(size_t)(j*4+1)*128];
      a2 += esec[j*4+2] * Wp[(size_t)(j*4+2)*128];
      a3 += esec[j*4+3] * Wp[(size_t)(j*4+3)*128];
    }
    h1s[tid] = fmaxf((a0 + a1) + (a2 + a3) + secb1[ii*128 + col], 0.f);
  }
  __syncthreads();
  if (tid < 5) {
    float ov = secb2[tid];
    for (int hh = 0; hh < 128; ++hh) ov += h1s[tid*128 + hh] * secW2[tid*128 + hh];
    out[tid*5 + 1] = 1.f/(1.f + __expf(-ov));
  }
}

// ---------------- launcher ----------------
extern "C" void kernel_launch(void* const* d_in, const int* in_sizes, int n_in,
                              void* d_out, int out_size, void* d_ws, size_t ws_size,
                              hipStream_t stream)
{
  const float* x_nodes    = (const float*)d_in[0];
  const float* contract_x = (const float*)d_in[1];
  const float* proj_W     = (const float*)d_in[2];
  const float* proj_b     = (const float*)d_in[3];
  const float* conv_W     = (const float*)d_in[4];
  const float* conv_b     = (const float*)d_in[5];
  const float* norm_g     = (const float*)d_in[6];
  const float* norm_b     = (const float*)d_in[7];
  const float* attn_W     = (const float*)d_in[8];
  const float* attn_b     = (const float*)d_in[9];
  const float* pool_W     = (const float*)d_in[10];
  const float* pool_b     = (const float*)d_in[11];
  const float* contract_W = (const float*)d_in[12];
  const float* contract_b = (const float*)d_in[13];
  const float* ta_W1      = (const float*)d_in[14];
  const float* ta_b1      = (const float*)d_in[15];
  const float* ta_g       = (const float*)d_in[16];
  const float* ta_beta    = (const float*)d_in[17];
  const float* ta_W2      = (const float*)d_in[18];
  const float* ta_b2      = (const float*)d_in[19];
  const float* sh_W1      = (const float*)d_in[20];
  const float* sh_b1      = (const float*)d_in[21];
  const float* sh_W2      = (const float*)d_in[22];
  const float* sh_b2      = (const float*)d_in[23];
  const float* fpr_Wa     = (const float*)d_in[24];
  const float* fpr_ba     = (const float*)d_in[25];
  const float* fpr_g      = (const float*)d_in[26];
  const float* fpr_beta   = (const float*)d_in[27];
  const float* fpr_W1     = (const float*)d_in[28];
  const float* fpr_b1     = (const float*)d_in[29];
  const float* fpr_W2     = (const float*)d_in[30];
  const float* fpr_b2     = (const float*)d_in[31];
  const float* sec_W1     = (const float*)d_in[32];
  const float* sec_b1     = (const float*)d_in[33];
  const float* sec_W2     = (const float*)d_in[34];
  const float* sec_b2     = (const float*)d_in[35];
  const int*   edge_index = (const int*)d_in[36];

  float* ws = (float*)d_ws;
  float* X     = ws + WS_X;
  float* Y     = ws + WS_Y;
  int*   ints  = (int*)(ws + WS_INT);
  int*   CNTS  = ints + WS_CNTS;
  int*   OFFS  = ints + WS_OFFS;
  int*   CUR   = ints + WS_CUR;
  int*   ELIST = ints + WS_ELIST;
  ushort_t* MHI  = (ushort_t*)(ws + WS_M);
  ushort_t* MLO  = MHI + (size_t)12*1024*256;
  ushort_t* WQHI = (ushort_t*)(ws + WS_WQ);
  ushort_t* WQLO = WQHI + (size_t)12*65536;
  float* QKV   = ws + WS_QKV;
  float* PACC  = ws + WS_QKV;                 // reuses QKV region after cast
  float* PML   = ws + WS_QKV + 2097152;
  ushort_t* QH = (ushort_t*)(ws + WS_BF);
  ushort_t* KH = (ushort_t*)(ws + WS_BF + 524288);
  ushort_t* VT = (ushort_t*)(ws + WS_BF + 1048576);
  ushort_t* AWHI = (ushort_t*)(ws + WS_AW);
  ushort_t* AWLO = AWHI + (size_t)4*65536;
  float* PART  = ws + WS_PART;
  float* LOG   = ws + WS_LOG;
  float* STATS = ws + WS_STATS;

  hipMemsetAsync(CNTS, 0, (size_t)K_*NPT_*sizeof(int), stream);

  k_proj<<<dim3(4096), 256, 0, stream>>>(x_nodes, proj_W, proj_b, X);
  k_hist<<<dim3(1536), 256, 0, stream>>>(edge_index, CNTS);
  k_scan<<<dim3(48), 1024, 0, stream>>>(CNTS, OFFS, CUR);
  k_scatter<<<dim3(1536), 256, 0, stream>>>(edge_index, CUR, ELIST);
  k_wprep<<<dim3(4, 8, 8), 256, 0, stream>>>(attn_W, AWHI, AWLO);

  for (int l = 0; l < L_; ++l) {
    for (int a = 0; a < 4; ++a) {
      k_means<<<dim3(3072), 256, 0, stream>>>(X, OFFS, ELIST, MHI, MLO, a);
      k_wprep<<<dim3(12, 8, 8), 256, 0, stream>>>(
          conv_W + ((size_t)(l*K_ + a*12))*65536, WQHI, WQLO);
      k_wxm<<<dim3(4, 16, 4), 256, 0, stream>>>(MHI, MLO, WQHI, WQLO, Y, a);
    }
    k_ln<<<dim3(4096), 256, 0, stream>>>(X, Y, CNTS, conv_b, norm_g, norm_b, l);
  }

  // qkv via MFMA GEMM, then cast to bf16 fragments
  k_gemm<<<dim3(6, 32), 256, 0, stream>>>(X, AWHI, AWLO, attn_b, QKV);
  k_cast<<<dim3(64, 8), 256, 0, stream>>>(QKV, QH, KH, VT);
  // MFMA flash attention (split-K 2) -> PACC/PML (QKV region), merge -> Y
  k_attn2<<<dim3(64, 8, 2), 256, 0, stream>>>(QH, KH, VT, PACC, PML);
  k_attn_merge<<<dim3(4096), 256, 0, stream>>>(PACC, PML, Y);
  // out projection -> z2 at QKV base
  k_gemm<<<dim3(2, 32), 256, 0, stream>>>(Y, AWHI + (size_t)3*65536,
      AWLO + (size_t)3*65536, attn_b + 768, QKV);
  // pooling
  k_pool_logits<<<dim3(1024), 256, 0, stream>>>(QKV, pool_W, pool_b, LOG);
  k_pool_stats<<<dim3(1), 256, 0, stream>>>(LOG, STATS);
  k_pool_partial<<<dim3(64), 256, 0, stream>>>(QKV, LOG, STATS, PART);
  // heads
  k_heads<<<dim3(1), 1024, 0, stream>>>(PART,
      contract_x, contract_W, contract_b,
      ta_W1, ta_b1, ta_g, ta_beta, ta_W2, ta_b2,
      sh_W1, sh_b1, sh_W2, sh_b2,
      fpr_Wa, fpr_ba, fpr_g, fpr_beta, fpr_W1, fpr_b1, fpr_W2, fpr_b2,
      sec_W1, sec_b1, sec_W2, sec_b2,
      (float*)d_out);
}

// Round 7
// 641.620 us; speedup vs baseline: 3.8114x; 1.0126x over previous
//
#include <hip/hip_runtime.h>
#include <hip/hip_bf16.h>
#include <cstddef>

typedef unsigned short ushort_t;
typedef __attribute__((ext_vector_type(8))) short bf16x8;
typedef __attribute__((ext_vector_type(4))) float f32x4;

// ---------------- constants ----------------
#define H_ 256
#define NPT_ 1024
#define E_ 8192
#define K_ 48
#define L_ 3

// ws layout in floats (~30.8 MB peak)
#define WS_X      0u          // X fp32 [4][1024][256]
#define WS_Y      1048576u    // conv GEMM accum / attn-merge out
#define WS_INT    2097152u    // int region
#define WS_CNTS   0u
#define WS_OFFS   49152u
#define WS_CUR    98352u
#define WS_ELIST  147504u
#define WS_M      2700288u    // Mhi/Mlo bf16 quarter (3145728 floats)
#define WS_QKV    2700288u    // QKV fp32 / PACC+PML during attention
#define WS_WQ     5846016u    // conv W quarter hi/lo (786432 floats)
#define WS_BF     5846016u    // bf16 Q/K/Vt post-conv (1572864 floats)
#define WS_PART   7418880u
#define WS_LOG    7435264u
#define WS_STATS  7439360u
#define WS_AW     7440000u    // attn_W hi/lo (262144 floats) -> end 7702144

__device__ __forceinline__ ushort_t f2bf(float x) {
  unsigned u = __float_as_uint(x);
  unsigned r = (u + 0x7FFFu + ((u >> 16) & 1u)) >> 16;
  return (ushort_t)r;
}
__device__ __forceinline__ float bf2f(ushort_t x) {
  return __uint_as_float(((unsigned)x) << 16);
}
__device__ __forceinline__ ushort_t f2bf_rn(float x) {
  __hip_bfloat16 h = __float2bfloat16(x);
  return *reinterpret_cast<ushort_t*>(&h);
}

// ---------------- proj ----------------
__global__ __launch_bounds__(256) void k_proj(const float* __restrict__ xn,
    const float* __restrict__ pW, const float* __restrict__ pb,
    float* __restrict__ x)
{
  const int t = blockIdx.x >> 10, n = blockIdx.x & 1023;
  const int tid = threadIdx.x;
  __shared__ float xr[32];
  if (tid < 21) xr[tid] = xn[(size_t)(t*1024 + n)*21 + tid];
  __syncthreads();
  float acc = pb[t*256 + tid];
  #pragma unroll
  for (int i = 0; i < 21; ++i) acc += xr[i] * pW[(size_t)(t*21 + i)*256 + tid];
  x[(size_t)(t*1024 + n)*256 + tid] = acc;
}

// ---------------- CSR build ----------------
__global__ __launch_bounds__(256) void k_hist(const int* __restrict__ ei, int* __restrict__ cnts)
{
  const int gid = blockIdx.x*256 + threadIdx.x;
  const int k = gid >> 13, e = gid & 8191;
  const int dst = ei[(size_t)k*2*E_ + E_ + e];
  atomicAdd(&cnts[k*1024 + dst], 1);
}

__global__ __launch_bounds__(1024) void k_scan(const int* __restrict__ cnts,
    int* __restrict__ offs, int* __restrict__ cur)
{
  const int k = blockIdx.x, tid = threadIdx.x;
  __shared__ int s[1024];
  const int v = cnts[k*1024 + tid];
  s[tid] = v; __syncthreads();
  for (int off = 1; off < 1024; off <<= 1) {
    int add = 0;
    if (tid >= off) add = s[tid - off];
    __syncthreads();
    s[tid] += add;
    __syncthreads();
  }
  const int ex = s[tid] - v;
  offs[k*1025 + tid] = ex;
  cur[k*1024 + tid] = ex;
  if (tid == 1023) offs[k*1025 + 1024] = s[1023];
}

__global__ __launch_bounds__(256) void k_scatter(const int* __restrict__ ei,
    int* __restrict__ cur, int* __restrict__ elist)
{
  const int gid = blockIdx.x*256 + threadIdx.x;
  const int k = gid >> 13, e = gid & 8191;
  const int src = ei[(size_t)k*2*E_ + e];
  const int dst = ei[(size_t)k*2*E_ + E_ + e];
  const int p = atomicAdd(&cur[k*1024 + dst], 1);
  elist[k*E_ + p] = src;
}

// ---------------- means: M[kl][d] = mean of X[a] rows (hi/lo bf16 out) ----------------
__global__ __launch_bounds__(256) void k_means(const float* __restrict__ X,
    const int* __restrict__ offs, const int* __restrict__ elist,
    ushort_t* __restrict__ Mhi, ushort_t* __restrict__ Mlo, int a)
{
  const int pid = blockIdx.x*4 + (threadIdx.x >> 6);
  const int kl = pid >> 10, d = pid & 1023;
  const int lane = threadIdx.x & 63;
  const int kg = a*12 + kl;
  const int o0 = offs[kg*1025 + d];
  const int o1 = offs[kg*1025 + d + 1];
  const float* xb = X + (size_t)a*1024*256;
  float4 s = {0.f, 0.f, 0.f, 0.f};
  int p = o0;
  while (p + 8 <= o1) {
    int srcs[8];
    #pragma unroll
    for (int q = 0; q < 8; ++q) srcs[q] = elist[(size_t)kg*E_ + p + q];
    float4 v[8];
    #pragma unroll
    for (int q = 0; q < 8; ++q)
      v[q] = *reinterpret_cast<const float4*>(xb + (size_t)srcs[q]*256 + lane*4);
    s.x += ((v[0].x+v[1].x)+(v[2].x+v[3].x)) + ((v[4].x+v[5].x)+(v[6].x+v[7].x));
    s.y += ((v[0].y+v[1].y)+(v[2].y+v[3].y)) + ((v[4].y+v[5].y)+(v[6].y+v[7].y));
    s.z += ((v[0].z+v[1].z)+(v[2].z+v[3].z)) + ((v[4].z+v[5].z)+(v[6].z+v[7].z));
    s.w += ((v[0].w+v[1].w)+(v[2].w+v[3].w)) + ((v[4].w+v[5].w)+(v[6].w+v[7].w));
    p += 8;
  }
  while (p + 4 <= o1) {
    const int s0 = elist[(size_t)kg*E_ + p + 0];
    const int s1 = elist[(size_t)kg*E_ + p + 1];
    const int s2 = elist[(size_t)kg*E_ + p + 2];
    const int s3 = elist[(size_t)kg*E_ + p + 3];
    const float4 v0 = *reinterpret_cast<const float4*>(xb + (size_t)s0*256 + lane*4);
    const float4 v1 = *reinterpret_cast<const float4*>(xb + (size_t)s1*256 + lane*4);
    const float4 v2 = *reinterpret_cast<const float4*>(xb + (size_t)s2*256 + lane*4);
    const float4 v3 = *reinterpret_cast<const float4*>(xb + (size_t)s3*256 + lane*4);
    s.x += (v0.x + v1.x) + (v2.x + v3.x);
    s.y += (v0.y + v1.y) + (v2.y + v3.y);
    s.z += (v0.z + v1.z) + (v2.z + v3.z);
    s.w += (v0.w + v1.w) + (v2.w + v3.w);
    p += 4;
  }
  while (p < o1) {
    const int sp = elist[(size_t)kg*E_ + p];
    const float4 v = *reinterpret_cast<const float4*>(xb + (size_t)sp*256 + lane*4);
    s.x += v.x; s.y += v.y; s.z += v.z; s.w += v.w;
    ++p;
  }
  const float inv = 1.f / fmaxf((float)(o1 - o0), 1.f);
  const float mv[4] = {s.x*inv, s.y*inv, s.z*inv, s.w*inv};
  ushort_t hi[4], lo[4];
  #pragma unroll
  for (int e = 0; e < 4; ++e) {
    hi[e] = f2bf(mv[e]);
    lo[e] = f2bf(mv[e] - bf2f(hi[e]));
  }
  const size_t base = ((size_t)kl*1024 + d)*256 + lane*4;
  *reinterpret_cast<ushort4*>(Mhi + base) = *reinterpret_cast<const ushort4*>(hi);
  *reinterpret_cast<ushort4*>(Mlo + base) = *reinterpret_cast<const ushort4*>(lo);
}

// ---------------- W prep: transpose + hi/lo split ----------------
// grid (nmat, 8, 8), block 256
__global__ __launch_bounds__(256) void k_wprep(const float* __restrict__ Wsrc,
    ushort_t* __restrict__ Whi, ushort_t* __restrict__ Wlo)
{
  const int kl = blockIdx.x, hb = blockIdx.y, gb = blockIdx.z;
  const int tid = threadIdx.x;
  __shared__ float tile[32][33];
  const float* W = Wsrc + (size_t)kl*65536;
  const int r0 = tid >> 5, c = tid & 31;
  #pragma unroll
  for (int it = 0; it < 4; ++it) {
    const int r = it*8 + r0;
    tile[r][c] = W[(size_t)(hb*32 + r)*256 + gb*32 + c];
  }
  __syncthreads();
  #pragma unroll
  for (int it = 0; it < 4; ++it) {
    const int g = it*8 + r0, h = c;
    const float v = tile[h][g];
    const ushort_t hi = f2bf(v);
    const ushort_t lo = f2bf(v - bf2f(hi));
    const size_t off = (size_t)kl*65536 + (size_t)(gb*32 + g)*256 + hb*32 + h;
    Whi[off] = hi;
    Wlo[off] = lo;
  }
}

// ---------------- conv GEMM: Y[t] (+)= sum_c M[t*3+c] @ Wq[t*3+c] (64x64 tiles) ----------------
// grid (cb=4, rb=16, t=4), block 256 (4 waves of 16x64)
__global__ __launch_bounds__(256) void k_wxm(const ushort_t* __restrict__ Mhi,
    const ushort_t* __restrict__ Mlo, const ushort_t* __restrict__ Wqhi,
    const ushort_t* __restrict__ Wqlo, float* __restrict__ Y, int a)
{
  const int cb = blockIdx.x, rb = blockIdx.y, t = blockIdx.z;
  const int tid = threadIdx.x, wave = tid >> 6, lane = tid & 63;
  const int lrow = lane & 15, lgrp = lane >> 4;
  __shared__ __align__(16) ushort_t AswH[64*64];
  __shared__ __align__(16) ushort_t AswL[64*64];
  __shared__ __align__(16) ushort_t BswH[64*64];
  __shared__ __align__(16) ushort_t BswL[64*64];
  f32x4 acc[4];
  #pragma unroll
  for (int j = 0; j < 4; ++j) acc[j] = (f32x4){0.f,0.f,0.f,0.f};

  for (int c = 0; c < 3; ++c) {
    const int kl = t*3 + c;
    const ushort_t* Ah = Mhi + ((size_t)kl*1024 + rb*64)*256;
    const ushort_t* Al = Mlo + ((size_t)kl*1024 + rb*64)*256;
    const ushort_t* Bh = Wqhi + (size_t)kl*65536 + (size_t)cb*64*256;
    const ushort_t* Bl = Wqlo + (size_t)kl*65536 + (size_t)cb*64*256;
    for (int ks = 0; ks < 4; ++ks) {
      __syncthreads();
      #pragma unroll
      for (int it = 0; it < 2; ++it) {
        const int idx = tid + it*256;     // 0..511: 64 rows x 8 c8
        const int row = idx >> 3, c8 = idx & 7;
        const int off = row*64 + ((c8 ^ (row & 7)) << 3);
        const size_t gsrc = (size_t)row*256 + ks*64 + c8*8;
        *reinterpret_cast<bf16x8*>(&AswH[off]) = *reinterpret_cast<const bf16x8*>(Ah + gsrc);
        *reinterpret_cast<bf16x8*>(&AswL[off]) = *reinterpret_cast<const bf16x8*>(Al + gsrc);
        *reinterpret_cast<bf16x8*>(&BswH[off]) = *reinterpret_cast<const bf16x8*>(Bh + gsrc);
        *reinterpret_cast<bf16x8*>(&BswL[off]) = *reinterpret_cast<const bf16x8*>(Bl + gsrc);
      }
      __syncthreads();
      #pragma unroll
      for (int ksub = 0; ksub < 2; ++ksub) {
        const int c8 = ksub*4 + lgrp;
        const int arow = wave*16 + lrow;
        const int aoff = arow*64 + ((c8 ^ (arow & 7)) << 3);
        const bf16x8 ah = *reinterpret_cast<const bf16x8*>(&AswH[aoff]);
        const bf16x8 al = *reinterpret_cast<const bf16x8*>(&AswL[aoff]);
        #pragma unroll
        for (int nf = 0; nf < 4; ++nf) {
          const int g = nf*16 + lrow;
          const int boff = g*64 + ((c8 ^ (g & 7)) << 3);
          const bf16x8 bh = *reinterpret_cast<const bf16x8*>(&BswH[boff]);
          const bf16x8 bl = *reinterpret_cast<const bf16x8*>(&BswL[boff]);
          __builtin_amdgcn_s_setprio(1);
          acc[nf] = __builtin_amdgcn_mfma_f32_16x16x32_bf16(ah, bh, acc[nf], 0, 0, 0);
          acc[nf] = __builtin_amdgcn_mfma_f32_16x16x32_bf16(ah, bl, acc[nf], 0, 0, 0);
          acc[nf] = __builtin_amdgcn_mfma_f32_16x16x32_bf16(al, bh, acc[nf], 0, 0, 0);
          __builtin_amdgcn_s_setprio(0);
        }
      }
    }
  }
  float* Cb = Y + ((size_t)(t*1024 + rb*64))*256 + cb*64;
  #pragma unroll
  for (int nf = 0; nf < 4; ++nf)
    #pragma unroll
    for (int r = 0; r < 4; ++r) {
      const int row = wave*16 + lgrp*4 + r;
      const int col = nf*16 + lrow;
      if (a == 0) Cb[(size_t)row*256 + col] = acc[nf][r];
      else        Cb[(size_t)row*256 + col] += acc[nf][r];
    }
}

// ---------------- bias-gate + residual + LN + relu ----------------
__global__ __launch_bounds__(256) void k_ln(float* __restrict__ x,
    const float* __restrict__ y, const int* __restrict__ cnts,
    const float* __restrict__ convB, const float* __restrict__ ng,
    const float* __restrict__ nb, int l)
{
  const int r = blockIdx.x;
  const int t = r >> 10, d = r & 1023;
  const int tid = threadIdx.x;
  __shared__ float flag[12];
  __shared__ float rbuf[256];
  if (tid < 12) {
    const int a = tid / 3, c = tid - a*3;
    const int kj = a*12 + t*3 + c;
    flag[tid] = (cnts[kj*1024 + d] > 0) ? 1.f : 0.f;
  }
  __syncthreads();
  float v = y[(size_t)r*256 + tid] + x[(size_t)r*256 + tid];
  #pragma unroll
  for (int j = 0; j < 12; ++j) {
    const int a = j / 3, c = j - a*3;
    const int kj = a*12 + t*3 + c;
    v += flag[j] * convB[(size_t)(l*K_ + kj)*256 + tid];
  }
  rbuf[tid] = v; __syncthreads();
  for (int s = 128; s > 0; s >>= 1) { if (tid < s) rbuf[tid] += rbuf[tid+s]; __syncthreads(); }
  const float mean = rbuf[0] * (1.f/256.f); __syncthreads();
  const float diff = v - mean;
  rbuf[tid] = diff*diff; __syncthreads();
  for (int s = 128; s > 0; s >>= 1) { if (tid < s) rbuf[tid] += rbuf[tid+s]; __syncthreads(); }
  const float var = rbuf[0] * (1.f/256.f); __syncthreads();
  const float xn = diff * rsqrtf(var + 1e-5f) * ng[(size_t)(l*4 + t)*256 + tid]
                 + nb[(size_t)(l*4 + t)*256 + tid];
  x[(size_t)r*256 + tid] = fmaxf(xn, 0.f);
}

// ---------------- MFMA GEMM: C[i] = A @ Wt[i] + bias (A fp32, B pre-split hi/lo) ----------------
// grid (ncb, 32), block 256 (4 waves of 64x64 in 128x128 tile)
__global__ __launch_bounds__(256) void k_gemm(const float* __restrict__ A,
    const ushort_t* __restrict__ Bh, const ushort_t* __restrict__ Bl,
    const float* __restrict__ bias, float* __restrict__ C)
{
  const int cb = blockIdx.x, rb = blockIdx.y;
  const int col0 = cb*128, i = col0 >> 8, g0 = col0 & 255;
  const int tid = threadIdx.x, wave = tid >> 6, lane = tid & 63;
  const int lrow = lane & 15, lgrp = lane >> 4;
  const int wr = wave >> 1, wc = wave & 1;
  __shared__ __align__(16) ushort_t AswH[128*64];
  __shared__ __align__(16) ushort_t AswL[128*64];
  __shared__ __align__(16) ushort_t BswH[128*64];
  __shared__ __align__(16) ushort_t BswL[128*64];
  const float* Ab = A + (size_t)rb*128*256;
  const ushort_t* Bhp = Bh + (size_t)i*65536 + (size_t)g0*256;
  const ushort_t* Blp = Bl + (size_t)i*65536 + (size_t)g0*256;
  f32x4 acc[4][4];
  #pragma unroll
  for (int m = 0; m < 4; ++m)
    #pragma unroll
    for (int n = 0; n < 4; ++n) acc[m][n] = (f32x4){0.f,0.f,0.f,0.f};

  for (int ks = 0; ks < 4; ++ks) {
    __syncthreads();
    // stage A fp32 -> hi/lo swizzled
    #pragma unroll
    for (int it = 0; it < 8; ++it) {
      const int idx = tid + it*256;       // 0..2047: 128 rows x 16 c4
      const int row = idx >> 4, c4 = idx & 15;
      const float4 v = *reinterpret_cast<const float4*>(Ab + (size_t)row*256 + ks*64 + c4*4);
      const float f[4] = {v.x, v.y, v.z, v.w};
      ushort_t hi[4], lo[4];
      #pragma unroll
      for (int e = 0; e < 4; ++e) {
        hi[e] = f2bf(f[e]);
        lo[e] = f2bf(f[e] - bf2f(hi[e]));
      }
      const int c8 = c4 >> 1, sub = (c4 & 1) * 4;
      const int off = row*64 + ((c8 ^ (row & 7)) << 3) + sub;
      *reinterpret_cast<uint2*>(&AswH[off]) = *reinterpret_cast<const uint2*>(hi);
      *reinterpret_cast<uint2*>(&AswL[off]) = *reinterpret_cast<const uint2*>(lo);
    }
    // stage B (pre-split) swizzled
    #pragma unroll
    for (int it = 0; it < 4; ++it) {
      const int idx = tid + it*256;       // 0..1023: 128 g x 8 c8
      const int row = idx >> 3, c8 = idx & 7;
      const int off = row*64 + ((c8 ^ (row & 7)) << 3);
      const size_t gsrc = (size_t)row*256 + ks*64 + c8*8;
      *reinterpret_cast<bf16x8*>(&BswH[off]) = *reinterpret_cast<const bf16x8*>(Bhp + gsrc);
      *reinterpret_cast<bf16x8*>(&BswL[off]) = *reinterpret_cast<const bf16x8*>(Blp + gsrc);
    }
    __syncthreads();
    #pragma unroll
    for (int ksub = 0; ksub < 2; ++ksub) {
      bf16x8 ah[4], al[4], bh[4], bl[4];
      const int c8 = ksub*4 + lgrp;
      #pragma unroll
      for (int mf = 0; mf < 4; ++mf) {
        const int row = wr*64 + mf*16 + lrow;
        const int off = row*64 + ((c8 ^ (row & 7)) << 3);
        ah[mf] = *reinterpret_cast<const bf16x8*>(&AswH[off]);
        al[mf] = *reinterpret_cast<const bf16x8*>(&AswL[off]);
      }
      #pragma unroll
      for (int nf = 0; nf < 4; ++nf) {
        const int row = wc*64 + nf*16 + lrow;
        const int off = row*64 + ((c8 ^ (row & 7)) << 3);
        bh[nf] = *reinterpret_cast<const bf16x8*>(&BswH[off]);
        bl[nf] = *reinterpret_cast<const bf16x8*>(&BswL[off]);
      }
      __builtin_amdgcn_s_setprio(1);
      #pragma unroll
      for (int mf = 0; mf < 4; ++mf)
        #pragma unroll
        for (int nf = 0; nf < 4; ++nf) {
          acc[mf][nf] = __builtin_amdgcn_mfma_f32_16x16x32_bf16(ah[mf], bh[nf], acc[mf][nf], 0, 0, 0);
          acc[mf][nf] = __builtin_amdgcn_mfma_f32_16x16x32_bf16(ah[mf], bl[nf], acc[mf][nf], 0, 0, 0);
          acc[mf][nf] = __builtin_amdgcn_mfma_f32_16x16x32_bf16(al[mf], bh[nf], acc[mf][nf], 0, 0, 0);
        }
      __builtin_amdgcn_s_setprio(0);
    }
  }
  float* Cp = C + (size_t)i*1048576 + (size_t)rb*128*256 + g0;
  const float* bp = bias + i*256 + g0;
  #pragma unroll
  for (int mf = 0; mf < 4; ++mf)
    #pragma unroll
    for (int nf = 0; nf < 4; ++nf)
      #pragma unroll
      for (int r = 0; r < 4; ++r) {
        const int row = wr*64 + mf*16 + lgrp*4 + r;
        const int col = wc*64 + nf*16 + lrow;
        Cp[(size_t)row*256 + col] = acc[mf][nf][r] + bp[col];
      }
}

// ---------------- cast QKV fp32 -> bf16 (Q scaled, V transposed) ----------------
__global__ __launch_bounds__(256) void k_cast(const float* __restrict__ qkv,
    ushort_t* __restrict__ Qh, ushort_t* __restrict__ Kh, ushort_t* __restrict__ Vt)
{
  const int rb = blockIdx.x, h = blockIdx.y;
  const int tid = threadIdx.x;
  const int r = tid >> 2, c8 = (tid & 3) * 8;
  const int row = rb*64 + r;
  __shared__ ushort_t vt[32][72];
  {
    const float* src = qkv + (size_t)row*256 + h*32 + c8;
    ushort_t tmp[8];
    #pragma unroll
    for (int j = 0; j < 8; ++j) tmp[j] = f2bf(src[j] * 0.17677669529663687f);
    *reinterpret_cast<uint4*>(Qh + ((size_t)(h*4096 + row))*32 + c8) = *reinterpret_cast<uint4*>(tmp);
  }
  {
    const float* src = qkv + 1048576 + (size_t)row*256 + h*32 + c8;
    ushort_t tmp[8];
    #pragma unroll
    for (int j = 0; j < 8; ++j) tmp[j] = f2bf(src[j]);
    *reinterpret_cast<uint4*>(Kh + ((size_t)(h*4096 + row))*32 + c8) = *reinterpret_cast<uint4*>(tmp);
  }
  {
    const float* src = qkv + 2097152 + (size_t)row*256 + h*32 + c8;
    #pragma unroll
    for (int j = 0; j < 8; ++j) vt[c8 + j][r] = f2bf(src[j]);
  }
  __syncthreads();
  const int d2 = tid >> 3, r0 = (tid & 7) * 8;
  *reinterpret_cast<uint4*>(Vt + ((size_t)(h*32 + d2))*4096 + rb*64 + r0)
      = *reinterpret_cast<const uint4*>(&vt[d2][r0]);
}

// ---------------- MFMA flash attention, max-free softmax, KVBLK=128, split-K 2 ----------------
// grid (64, 8, 2), block 256 (4 waves x 16 q-rows)
__global__ __launch_bounds__(256) void k_attn2(const ushort_t* __restrict__ Qh,
    const ushort_t* __restrict__ Kh, const ushort_t* __restrict__ Vt,
    float* __restrict__ pacc, float* __restrict__ pml)
{
  const int tid = threadIdx.x;
  const int wave = tid >> 6, lane = tid & 63;
  const int lrow = lane & 15, lgrp = lane >> 4;
  const int h = blockIdx.y, sp = blockIdx.z;
  const int q0 = blockIdx.x * 64 + wave * 16;
  __shared__ ushort_t P[4][16][136];

  const bf16x8 qf = *reinterpret_cast<const bf16x8*>(
      Qh + ((size_t)(h*4096 + q0 + lrow))*32 + lgrp*8);

  float lsum[4] = {0.f, 0.f, 0.f, 0.f};   // per-lane partial over this lane's key columns
  f32x4 o0 = {0.f,0.f,0.f,0.f}, o1 = {0.f,0.f,0.f,0.f};

  const ushort_t* Kbase = Kh + (size_t)(h*4096)*32;
  const ushort_t* Vbase = Vt + (size_t)(h*32)*4096;

  for (int kt = 0; kt < 16; ++kt) {
    const int kb = sp*2048 + kt*128;
    f32x4 s[8];
    __builtin_amdgcn_s_setprio(1);
    #pragma unroll
    for (int ks = 0; ks < 8; ++ks) {
      const bf16x8 kf = *reinterpret_cast<const bf16x8*>(
          Kbase + (size_t)(kb + ks*16 + lrow)*32 + lgrp*8);
      f32x4 z = {0.f,0.f,0.f,0.f};
      s[ks] = __builtin_amdgcn_mfma_f32_16x16x32_bf16(qf, kf, z, 0, 0, 0);
    }
    __builtin_amdgcn_s_setprio(0);
    // max-free softmax: P = exp(s); lane-local partial row-sums, no cross-lane ops
    #pragma unroll
    for (int ks = 0; ks < 8; ++ks) {
      #pragma unroll
      for (int r = 0; r < 4; ++r) {
        const float p = __expf(s[ks][r]);
        lsum[r] += p;
        P[wave][lgrp*4 + r][ks*16 + lrow] = f2bf_rn(p);
      }
    }
    __builtin_amdgcn_s_setprio(1);
    #pragma unroll
    for (int ks2 = 0; ks2 < 4; ++ks2) {
      const bf16x8 pa = *reinterpret_cast<const bf16x8*>(&P[wave][lrow][ks2*32 + lgrp*8]);
      const bf16x8 v0 = *reinterpret_cast<const bf16x8*>(
          Vbase + (size_t)lrow*4096 + kb + ks2*32 + lgrp*8);
      const bf16x8 v1 = *reinterpret_cast<const bf16x8*>(
          Vbase + (size_t)(16 + lrow)*4096 + kb + ks2*32 + lgrp*8);
      o0 = __builtin_amdgcn_mfma_f32_16x16x32_bf16(pa, v0, o0, 0, 0, 0);
      o1 = __builtin_amdgcn_mfma_f32_16x16x32_bf16(pa, v1, o1, 0, 0, 0);
    }
    __builtin_amdgcn_s_setprio(0);
  }
  #pragma unroll
  for (int r = 0; r < 4; ++r) {
    float l = lsum[r];
    l += __shfl_xor(l, 1); l += __shfl_xor(l, 2);
    l += __shfl_xor(l, 4); l += __shfl_xor(l, 8);
    const int row = q0 + lgrp*4 + r;
    const size_t base = (size_t)sp*1048576 + ((size_t)row*8 + h)*32;
    pacc[base + lrow]      = o0[r];
    pacc[base + 16 + lrow] = o1[r];
    if (lrow == 0) {
      pml[((size_t)row*8 + h)*4 + sp*2 + 0] = 0.f;   // m == 0 (max-free)
      pml[((size_t)row*8 + h)*4 + sp*2 + 1] = l;
    }
  }
}

__global__ __launch_bounds__(256) void k_attn_merge(const float* __restrict__ pacc,
    const float* __restrict__ pml, float* __restrict__ attno)
{
  const int gid = blockIdx.x*256 + threadIdx.x;      // 4096*8*32
  const int rh = gid >> 5, d = gid & 31;
  const int r = rh >> 3, h = rh & 7;
  const float m0 = pml[rh*4+0], l0 = pml[rh*4+1];
  const float m1 = pml[rh*4+2], l1 = pml[rh*4+3];
  const float mx = fmaxf(m0, m1);
  const float e0 = __expf(m0 - mx), e1 = __expf(m1 - mx);
  const float den = l0*e0 + l1*e1;
  const float o = (pacc[(size_t)rh*32 + d]*e0 + pacc[1048576 + (size_t)rh*32 + d]*e1) / den;
  attno[(size_t)r*256 + h*32 + d] = o;
}

// ---------------- pooling ----------------
__global__ __launch_bounds__(256) void k_pool_logits(const float* __restrict__ z,
    const float* __restrict__ pW, const float* __restrict__ pb, float* __restrict__ logits)
{
  const int tid = threadIdx.x;
  const int wave = tid >> 6, lane = tid & 63;
  const int r = blockIdx.x*4 + wave;
  const float4 zv = reinterpret_cast<const float4*>(z + (size_t)r*256)[lane];
  const float4 wv = reinterpret_cast<const float4*>(pW)[lane];
  float dv = zv.x*wv.x + zv.y*wv.y + zv.z*wv.z + zv.w*wv.w;
  for (int off = 32; off; off >>= 1) dv += __shfl_down(dv, off);
  if (lane == 0) logits[r] = dv + pb[0];
}

__global__ __launch_bounds__(256) void k_pool_stats(const float* __restrict__ logits,
    float* __restrict__ stats)
{
  const int tid = threadIdx.x;
  __shared__ float rbuf[256];
  float mx = -1e30f;
  for (int i = tid; i < 4096; i += 256) mx = fmaxf(mx, logits[i]);
  rbuf[tid] = mx; __syncthreads();
  for (int s = 128; s > 0; s >>= 1) { if (tid < s) rbuf[tid] = fmaxf(rbuf[tid], rbuf[tid+s]); __syncthreads(); }
  mx = rbuf[0]; __syncthreads();
  float se = 0.f;
  for (int i = tid; i < 4096; i += 256) se += __expf(logits[i] - mx);
  rbuf[tid] = se; __syncthreads();
  for (int s = 128; s > 0; s >>= 1) { if (tid < s) rbuf[tid] += rbuf[tid+s]; __syncthreads(); }
  if (tid == 0) { stats[0] = mx; stats[1] = rbuf[0]; }
}

__global__ __launch_bounds__(256) void k_pool_partial(const float* __restrict__ z,
    const float* __restrict__ logits, const float* __restrict__ stats,
    float* __restrict__ partial)
{
  const int pb = blockIdx.x, tid = threadIdx.x;
  const float mx = stats[0], se = stats[1];
  __shared__ float wl[64];
  if (tid < 64) wl[tid] = __expf(logits[pb*64 + tid] - mx) / se;
  __syncthreads();
  float acc = 0.f;
  for (int n = 0; n < 64; ++n) acc += wl[n] * z[(size_t)(pb*64 + n)*256 + tid];
  partial[pb*256 + tid] = acc;
}

// ---------------- heads helpers ----------------
__device__ __forceinline__ void mv256(const float* __restrict__ W,
    const float* __restrict__ sIn, float (*red)[256], int o, int hq)
{
  float a0 = 0.f, a1 = 0.f, a2 = 0.f, a3 = 0.f;
  const float* Wp = W + (size_t)(hq*64)*256 + o;
  const float* ip = sIn + hq*64;
  #pragma unroll
  for (int j = 0; j < 16; ++j) {
    a0 += ip[j*4+0] * Wp[(size_t)(j*4+0)*256];
    a1 += ip[j*4+1] * Wp[(size_t)(j*4+1)*256];
    a2 += ip[j*4+2] * Wp[(size_t)(j*4+2)*256];
    a3 += ip[j*4+3] * Wp[(size_t)(j*4+3)*256];
  }
  red[hq][o] = (a0 + a1) + (a2 + a3);
}

// ---------------- heads (single block, 1024 threads) ----------------
__global__ __launch_bounds__(1024) void k_heads(
    const float* __restrict__ partial,
    const float* __restrict__ cx, const float* __restrict__ cW, const float* __restrict__ cb,
    const float* __restrict__ taW1, const float* __restrict__ tab1,
    const float* __restrict__ tag, const float* __restrict__ tabeta,
    const float* __restrict__ taW2, const float* __restrict__ tab2,
    const float* __restrict__ shW1, const float* __restrict__ shb1,
    const float* __restrict__ shW2, const float* __restrict__ shb2,
    const float* __restrict__ fprWa, const float* __restrict__ fprba,
    const float* __restrict__ fprg, const float* __restrict__ fprbeta,
    const float* __restrict__ fprW1, const float* __restrict__ fprb1,
    const float* __restrict__ fprW2, const float* __restrict__ fprb2,
    const float* __restrict__ secW1, const float* __restrict__ secb1,
    const float* __restrict__ secW2, const float* __restrict__ secb2,
    float* __restrict__ out)
{
  const int tid = threadIdx.x;
  const int o = tid & 255, hq = tid >> 8;
  __shared__ float semb[256], esec[256], efpr[256], vbuf[256];
  __shared__ float red[4][256];
  __shared__ float rbuf[256];
  __shared__ float h1s[640];
  float* redf = &red[0][0];

  {
    float acc = 0.f;
    #pragma unroll
    for (int pb = 0; pb < 16; ++pb) acc += partial[(hq*16 + pb)*256 + o];
    #pragma unroll
    for (int i = 0; i < 8; ++i) acc += cx[hq*8 + i] * cW[(hq*8 + i)*256 + o];
    red[hq][o] = acc;
  }
  __syncthreads();
  if (tid < 256) semb[tid] = red[0][tid] + red[1][tid] + red[2][tid] + red[3][tid] + cb[tid];
  __syncthreads();

  for (int i = 0; i < 2; ++i) {
    mv256(taW1 + (size_t)i*65536, semb, red, o, hq);
    __syncthreads();
    float u = 0.f;
    if (tid < 256) u = red[0][tid] + red[1][tid] + red[2][tid] + red[3][tid] + tab1[i*256 + tid];
    if (tid < 256) rbuf[tid] = u;
    __syncthreads();
    for (int s = 128; s > 0; s >>= 1) { if (tid < s) rbuf[tid] += rbuf[tid+s]; __syncthreads(); }
    const float mean = rbuf[0] * (1.f/256.f);
    __syncthreads();
    const float diff = u - mean;
    if (tid < 256) rbuf[tid] = diff*diff;
    __syncthreads();
    for (int s = 128; s > 0; s >>= 1) { if (tid < s) rbuf[tid] += rbuf[tid+s]; __syncthreads(); }
    const float var = rbuf[0] * (1.f/256.f);
    __syncthreads();
    if (tid < 256)
      vbuf[tid] = fmaxf(diff * rsqrtf(var + 1e-5f) * tag[i*256 + tid] + tabeta[i*256 + tid], 0.f);
    __syncthreads();
    mv256(taW2 + (size_t)i*65536, vbuf, red, o, hq);
    __syncthreads();
    if (tid < 256) {
      const float s2v = red[0][tid] + red[1][tid] + red[2][tid] + red[3][tid] + tab2[i*256 + tid];
      const float att = semb[tid] * (1.f/(1.f + __expf(-s2v)));
      if (i == 0) esec[tid] = att; else efpr[tid] = att;
    }
    __syncthreads();
  }

  {
    const int oo = tid & 511, ii = oo >> 7, col = oo & 127, hh = tid >> 9;
    float a0 = 0.f, a1 = 0.f, a2 = 0.f, a3 = 0.f;
    const float* Wp = shW1 + (size_t)ii*32768 + (size_t)(hh*128)*128 + col;
    const float* ip = semb + hh*128;
    #pragma unroll
    for (int j = 0; j < 32; ++j) {
      a0 += ip[j*4+0] * Wp[(size_t)(j*4+0)*128];
      a1 += ip[j*4+1] * Wp[(size_t)(j*4+1)*128];
      a2 += ip[j*4+2] * Wp[(size_t)(j*4+2)*128];
      a3 += ip[j*4+3] * Wp[(size_t)(j*4+3)*128];
    }
    redf[hh*512 + oo] = (a0 + a1) + (a2 + a3);
  }
  __syncthreads();
  if (tid < 512) {
    const int ii = tid >> 7, col = tid & 127;
    h1s[tid] = fmaxf(redf[tid] + redf[512 + tid] + shb1[ii*128 + col], 0.f);
  }
  __syncthreads();
  if (tid < 20) {
    const int ii = tid / 5, c = tid % 5;
    const int rowm = (ii == 0) ? 0 : (ii + 1);
    float ov = shb2[ii*5 + c];
    for (int hh = 0; hh < 128; ++hh) ov += h1s[ii*128 + hh] * shW2[ii*640 + hh*5 + c];
    out[rowm*5 + c] = 1.f/(1.f + __expf(-ov));
  }

  mv256(fprWa, efpr, red, o, hq);
  __syncthreads();
  {
    float u = 0.f;
    if (tid < 256) u = red[0][tid] + red[1][tid] + red[2][tid] + red[3][tid] + fprba[tid];
    if (tid < 256) rbuf[tid] = u;
    __syncthreads();
    for (int s = 128; s > 0; s >>= 1) { if (tid < s) rbuf[tid] += rbuf[tid+s]; __syncthreads(); }
    const float mean = rbuf[0] * (1.f/256.f);
    __syncthreads();
    const float diff = u - mean;
    if (tid < 256) rbuf[tid] = diff*diff;
    __syncthreads();
    for (int s = 128; s > 0; s >>= 1) { if (tid < s) rbuf[tid] += rbuf[tid+s]; __syncthreads(); }
    const float var = rbuf[0] * (1.f/256.f);
    __syncthreads();
    if (tid < 256)
      vbuf[tid] = fmaxf(diff * rsqrtf(var + 1e-5f) * fprg[tid] + fprbeta[tid], 0.f);
    __syncthreads();
  }
  {
    const int col = tid & 127, hs = tid >> 7;
    float a0 = 0.f, a1 = 0.f;
    const float* Wp = fprW1 + (size_t)(hs*32)*128 + col;
    const float* ip = vbuf + hs*32;
    #pragma unroll
    for (int j = 0; j < 16; ++j) {
      a0 += ip[j*2+0] * Wp[(size_t)(j*2+0)*128];
      a1 += ip[j*2+1] * Wp[(size_t)(j*2+1)*128];
    }
    redf[hs*128 + col] = a0 + a1;
  }
  __syncthreads();
  if (tid < 128) {
    float hv = fprb1[tid];
    #pragma unroll
    for (int s = 0; s < 8; ++s) hv += redf[s*128 + tid];
    h1s[tid] = fmaxf(hv, 0.f);
  }
  __syncthreads();
  if (tid < 5) {
    float ov = fprb2[tid];
    for (int hh = 0; hh < 128; ++hh) ov += h1s[hh] * fprW2[hh*5 + tid];
    out[5 + tid] = 1.f/(1.f + __expf(-ov));
  }
  __syncthreads();

  if (tid < 640) {
    const int ii = tid >> 7, col = tid & 127;
    float a0 = 0.f, a1 = 0.f, a2 = 0.f, a3 = 0.f;
    const float* Wp = secW1 + (size_t)ii*32768 + col;
    #pragma unroll
    for (int j = 0; j < 64; ++j) {
      a0 += esec[j*4+0] * Wp[(size_t)(j*4+0)*128];
      a1 += esec[j*4+1] * Wp[(size_t)(j*4+1)*128];
      a2 += esec[j*4+2] * Wp[(size_t)(j*4+2)*128];
      a3 += esec[j*4+3] * Wp[(size_t)(j*4+3)*128];
    }
    h1s[tid] = fmaxf((a0 + a1) + (a2 + a3) + secb1[ii*128 + col], 0.f);
  }
  __syncthreads();
  if (tid < 5) {
    float ov = secb2[tid];
    for (int hh = 0; hh < 128; ++hh) ov += h1s[tid*128 + hh] * secW2[tid*128 + hh];
    out[tid*5 + 1] = 1.f/(1.f + __expf(-ov));
  }
}

// ---------------- launcher ----------------
extern "C" void kernel_launch(void* const* d_in, const int* in_sizes, int n_in,
                              void* d_out, int out_size, void* d_ws, size_t ws_size,
                              hipStream_t stream)
{
  const float* x_nodes    = (const float*)d_in[0];
  const float* contract_x = (const float*)d_in[1];
  const float* proj_W     = (const float*)d_in[2];
  const float* proj_b     = (const float*)d_in[3];
  const float* conv_W     = (const float*)d_in[4];
  const float* conv_b     = (const float*)d_in[5];
  const float* norm_g     = (const float*)d_in[6];
  const float* norm_b     = (const float*)d_in[7];
  const float* attn_W     = (const float*)d_in[8];
  const float* attn_b     = (const float*)d_in[9];
  const float* pool_W     = (const float*)d_in[10];
  const float* pool_b     = (const float*)d_in[11];
  const float* contract_W = (const float*)d_in[12];
  const float* contract_b = (const float*)d_in[13];
  const float* ta_W1      = (const float*)d_in[14];
  const float* ta_b1      = (const float*)d_in[15];
  const float* ta_g       = (const float*)d_in[16];
  const float* ta_beta    = (const float*)d_in[17];
  const float* ta_W2      = (const float*)d_in[18];
  const float* ta_b2      = (const float*)d_in[19];
  const float* sh_W1      = (const float*)d_in[20];
  const float* sh_b1      = (const float*)d_in[21];
  const float* sh_W2      = (const float*)d_in[22];
  const float* sh_b2      = (const float*)d_in[23];
  const float* fpr_Wa     = (const float*)d_in[24];
  const float* fpr_ba     = (const float*)d_in[25];
  const float* fpr_g      = (const float*)d_in[26];
  const float* fpr_beta   = (const float*)d_in[27];
  const float* fpr_W1     = (const float*)d_in[28];
  const float* fpr_b1     = (const float*)d_in[29];
  const float* fpr_W2     = (const float*)d_in[30];
  const float* fpr_b2     = (const float*)d_in[31];
  const float* sec_W1     = (const float*)d_in[32];
  const float* sec_b1     = (const float*)d_in[33];
  const float* sec_W2     = (const float*)d_in[34];
  const float* sec_b2     = (const float*)d_in[35];
  const int*   edge_index = (const int*)d_in[36];

  float* ws = (float*)d_ws;
  float* X     = ws + WS_X;
  float* Y     = ws + WS_Y;
  int*   ints  = (int*)(ws + WS_INT);
  int*   CNTS  = ints + WS_CNTS;
  int*   OFFS  = ints + WS_OFFS;
  int*   CUR   = ints + WS_CUR;
  int*   ELIST = ints + WS_ELIST;
  ushort_t* MHI  = (ushort_t*)(ws + WS_M);
  ushort_t* MLO  = MHI + (size_t)12*1024*256;
  ushort_t* WQHI = (ushort_t*)(ws + WS_WQ);
  ushort_t* WQLO = WQHI + (size_t)12*65536;
  float* QKV   = ws + WS_QKV;
  float* PACC  = ws + WS_QKV;                 // reuses QKV region after cast
  float* PML   = ws + WS_QKV + 2097152;
  ushort_t* QH = (ushort_t*)(ws + WS_BF);
  ushort_t* KH = (ushort_t*)(ws + WS_BF + 524288);
  ushort_t* VT = (ushort_t*)(ws + WS_BF + 1048576);
  ushort_t* AWHI = (ushort_t*)(ws + WS_AW);
  ushort_t* AWLO = AWHI + (size_t)4*65536;
  float* PART  = ws + WS_PART;
  float* LOG   = ws + WS_LOG;
  float* STATS = ws + WS_STATS;

  hipMemsetAsync(CNTS, 0, (size_t)K_*NPT_*sizeof(int), stream);

  k_proj<<<dim3(4096), 256, 0, stream>>>(x_nodes, proj_W, proj_b, X);
  k_hist<<<dim3(1536), 256, 0, stream>>>(edge_index, CNTS);
  k_scan<<<dim3(48), 1024, 0, stream>>>(CNTS, OFFS, CUR);
  k_scatter<<<dim3(1536), 256, 0, stream>>>(edge_index, CUR, ELIST);
  k_wprep<<<dim3(4, 8, 8), 256, 0, stream>>>(attn_W, AWHI, AWLO);

  for (int l = 0; l < L_; ++l) {
    for (int a = 0; a < 4; ++a) {
      k_means<<<dim3(3072), 256, 0, stream>>>(X, OFFS, ELIST, MHI, MLO, a);
      k_wprep<<<dim3(12, 8, 8), 256, 0, stream>>>(
          conv_W + ((size_t)(l*K_ + a*12))*65536, WQHI, WQLO);
      k_wxm<<<dim3(4, 16, 4), 256, 0, stream>>>(MHI, MLO, WQHI, WQLO, Y, a);
    }
    k_ln<<<dim3(4096), 256, 0, stream>>>(X, Y, CNTS, conv_b, norm_g, norm_b, l);
  }

  // qkv via MFMA GEMM, then cast to bf16 fragments
  k_gemm<<<dim3(6, 32), 256, 0, stream>>>(X, AWHI, AWLO, attn_b, QKV);
  k_cast<<<dim3(64, 8), 256, 0, stream>>>(QKV, QH, KH, VT);
  // MFMA flash attention (split-K 2) -> PACC/PML (QKV region), merge -> Y
  k_attn2<<<dim3(64, 8, 2), 256, 0, stream>>>(QH, KH, VT, PACC, PML);
  k_attn_merge<<<dim3(4096), 256, 0, stream>>>(PACC, PML, Y);
  // out projection -> z2 at QKV base
  k_gemm<<<dim3(2, 32), 256, 0, stream>>>(Y, AWHI + (size_t)3*65536,
      AWLO + (size_t)3*65536, attn_b + 768, QKV);
  // pooling
  k_pool_logits<<<dim3(1024), 256, 0, stream>>>(QKV, pool_W, pool_b, LOG);
  k_pool_stats<<<dim3(1), 256, 0, stream>>>(LOG, STATS);
  k_pool_partial<<<dim3(64), 256, 0, stream>>>(QKV, LOG, STATS, PART);
  // heads
  k_heads<<<dim3(1), 1024, 0, stream>>>(PART,
      contract_x, contract_W, contract_b,
      ta_W1, ta_b1, ta_g, ta_beta, ta_W2, ta_b2,
      sh_W1, sh_b1, sh_W2, sh_b2,
      fpr_Wa, fpr_ba, fpr_g, fpr_beta, fpr_W1, fpr_b1, fpr_W2, fpr_b2,
      sec_W1, sec_b1, sec_W2, sec_b2,
      (float*)d_out);
}

// Round 8
// 625.962 us; speedup vs baseline: 3.9067x; 1.0250x over previous
//
#include <hip/hip_runtime.h>
#include <hip/hip_bf16.h>
#include <cstddef>

typedef unsigned short ushort_t;
typedef __attribute__((ext_vector_type(8))) short bf16x8;
typedef __attribute__((ext_vector_type(4))) float f32x4;

// ---------------- constants ----------------
#define H_ 256
#define NPT_ 1024
#define E_ 8192
#define K_ 48
#define L_ 3

// ws layout in floats (~31.3 MB peak; 32.1 MB proven safe in R1)
#define WS_X      0u          // X fp32 [4][1024][256]; pacc sp3 during attn
#define WS_Y      1048576u    // conv GEMM accum / attn-merge out
#define WS_INT    2097152u    // int region
#define WS_CNTS   0u
#define WS_OFFS   49152u
#define WS_CUR    98352u
#define WS_ELIST  147504u
#define WS_M      2700288u    // Mhi/Mlo bf16 quarter (3145728 floats)
#define WS_QKV    2700288u    // QKV fp32 / pacc sp0-2 during attention
#define WS_WQ     5846016u    // conv W HALF hi/lo (1572864 floats)
#define WS_BF     5846016u    // bf16 Q/K/Vt post-conv (same region)
#define WS_PART   7418880u
#define WS_LOG    7435264u
#define WS_STATS  7439360u
#define WS_AW     7440000u    // attn_W hi/lo (262144 floats) -> 7702144
#define WS_PML    7702144u    // attn split l-sums (131072 floats) -> 7833216

__device__ __forceinline__ ushort_t f2bf(float x) {
  unsigned u = __float_as_uint(x);
  unsigned r = (u + 0x7FFFu + ((u >> 16) & 1u)) >> 16;
  return (ushort_t)r;
}
__device__ __forceinline__ float bf2f(ushort_t x) {
  return __uint_as_float(((unsigned)x) << 16);
}
__device__ __forceinline__ ushort_t f2bf_rn(float x) {
  __hip_bfloat16 h = __float2bfloat16(x);
  return *reinterpret_cast<ushort_t*>(&h);
}

// ---------------- proj ----------------
__global__ __launch_bounds__(256) void k_proj(const float* __restrict__ xn,
    const float* __restrict__ pW, const float* __restrict__ pb,
    float* __restrict__ x)
{
  const int t = blockIdx.x >> 10, n = blockIdx.x & 1023;
  const int tid = threadIdx.x;
  __shared__ float xr[32];
  if (tid < 21) xr[tid] = xn[(size_t)(t*1024 + n)*21 + tid];
  __syncthreads();
  float acc = pb[t*256 + tid];
  #pragma unroll
  for (int i = 0; i < 21; ++i) acc += xr[i] * pW[(size_t)(t*21 + i)*256 + tid];
  x[(size_t)(t*1024 + n)*256 + tid] = acc;
}

// ---------------- CSR build ----------------
__global__ __launch_bounds__(256) void k_hist(const int* __restrict__ ei, int* __restrict__ cnts)
{
  const int gid = blockIdx.x*256 + threadIdx.x;
  const int k = gid >> 13, e = gid & 8191;
  const int dst = ei[(size_t)k*2*E_ + E_ + e];
  atomicAdd(&cnts[k*1024 + dst], 1);
}

__global__ __launch_bounds__(1024) void k_scan(const int* __restrict__ cnts,
    int* __restrict__ offs, int* __restrict__ cur)
{
  const int k = blockIdx.x, tid = threadIdx.x;
  __shared__ int s[1024];
  const int v = cnts[k*1024 + tid];
  s[tid] = v; __syncthreads();
  for (int off = 1; off < 1024; off <<= 1) {
    int add = 0;
    if (tid >= off) add = s[tid - off];
    __syncthreads();
    s[tid] += add;
    __syncthreads();
  }
  const int ex = s[tid] - v;
  offs[k*1025 + tid] = ex;
  cur[k*1024 + tid] = ex;
  if (tid == 1023) offs[k*1025 + 1024] = s[1023];
}

__global__ __launch_bounds__(256) void k_scatter(const int* __restrict__ ei,
    int* __restrict__ cur, int* __restrict__ elist)
{
  const int gid = blockIdx.x*256 + threadIdx.x;
  const int k = gid >> 13, e = gid & 8191;
  const int src = ei[(size_t)k*2*E_ + e];
  const int dst = ei[(size_t)k*2*E_ + E_ + e];
  const int p = atomicAdd(&cur[k*1024 + dst], 1);
  elist[k*E_ + p] = src;
}

// ---------------- means: M[kl][d] = mean of X[a] rows (hi/lo bf16 out) ----------------
__global__ __launch_bounds__(256) void k_means(const float* __restrict__ X,
    const int* __restrict__ offs, const int* __restrict__ elist,
    ushort_t* __restrict__ Mhi, ushort_t* __restrict__ Mlo, int a)
{
  const int pid = blockIdx.x*4 + (threadIdx.x >> 6);
  const int kl = pid >> 10, d = pid & 1023;
  const int lane = threadIdx.x & 63;
  const int kg = a*12 + kl;
  const int o0 = offs[kg*1025 + d];
  const int o1 = offs[kg*1025 + d + 1];
  const float* xb = X + (size_t)a*1024*256;
  float4 s = {0.f, 0.f, 0.f, 0.f};
  int p = o0;
  while (p + 8 <= o1) {
    int srcs[8];
    #pragma unroll
    for (int q = 0; q < 8; ++q) srcs[q] = elist[(size_t)kg*E_ + p + q];
    float4 v[8];
    #pragma unroll
    for (int q = 0; q < 8; ++q)
      v[q] = *reinterpret_cast<const float4*>(xb + (size_t)srcs[q]*256 + lane*4);
    s.x += ((v[0].x+v[1].x)+(v[2].x+v[3].x)) + ((v[4].x+v[5].x)+(v[6].x+v[7].x));
    s.y += ((v[0].y+v[1].y)+(v[2].y+v[3].y)) + ((v[4].y+v[5].y)+(v[6].y+v[7].y));
    s.z += ((v[0].z+v[1].z)+(v[2].z+v[3].z)) + ((v[4].z+v[5].z)+(v[6].z+v[7].z));
    s.w += ((v[0].w+v[1].w)+(v[2].w+v[3].w)) + ((v[4].w+v[5].w)+(v[6].w+v[7].w));
    p += 8;
  }
  while (p + 4 <= o1) {
    const int s0 = elist[(size_t)kg*E_ + p + 0];
    const int s1 = elist[(size_t)kg*E_ + p + 1];
    const int s2 = elist[(size_t)kg*E_ + p + 2];
    const int s3 = elist[(size_t)kg*E_ + p + 3];
    const float4 v0 = *reinterpret_cast<const float4*>(xb + (size_t)s0*256 + lane*4);
    const float4 v1 = *reinterpret_cast<const float4*>(xb + (size_t)s1*256 + lane*4);
    const float4 v2 = *reinterpret_cast<const float4*>(xb + (size_t)s2*256 + lane*4);
    const float4 v3 = *reinterpret_cast<const float4*>(xb + (size_t)s3*256 + lane*4);
    s.x += (v0.x + v1.x) + (v2.x + v3.x);
    s.y += (v0.y + v1.y) + (v2.y + v3.y);
    s.z += (v0.z + v1.z) + (v2.z + v3.z);
    s.w += (v0.w + v1.w) + (v2.w + v3.w);
    p += 4;
  }
  while (p < o1) {
    const int sp = elist[(size_t)kg*E_ + p];
    const float4 v = *reinterpret_cast<const float4*>(xb + (size_t)sp*256 + lane*4);
    s.x += v.x; s.y += v.y; s.z += v.z; s.w += v.w;
    ++p;
  }
  const float inv = 1.f / fmaxf((float)(o1 - o0), 1.f);
  const float mv[4] = {s.x*inv, s.y*inv, s.z*inv, s.w*inv};
  ushort_t hi[4], lo[4];
  #pragma unroll
  for (int e = 0; e < 4; ++e) {
    hi[e] = f2bf(mv[e]);
    lo[e] = f2bf(mv[e] - bf2f(hi[e]));
  }
  const size_t base = ((size_t)kl*1024 + d)*256 + lane*4;
  *reinterpret_cast<ushort4*>(Mhi + base) = *reinterpret_cast<const ushort4*>(hi);
  *reinterpret_cast<ushort4*>(Mlo + base) = *reinterpret_cast<const ushort4*>(lo);
}

// ---------------- W prep: transpose + hi/lo split ----------------
// grid (nmat, 8, 8), block 256
__global__ __launch_bounds__(256) void k_wprep(const float* __restrict__ Wsrc,
    ushort_t* __restrict__ Whi, ushort_t* __restrict__ Wlo)
{
  const int kl = blockIdx.x, hb = blockIdx.y, gb = blockIdx.z;
  const int tid = threadIdx.x;
  __shared__ float tile[32][33];
  const float* W = Wsrc + (size_t)kl*65536;
  const int r0 = tid >> 5, c = tid & 31;
  #pragma unroll
  for (int it = 0; it < 4; ++it) {
    const int r = it*8 + r0;
    tile[r][c] = W[(size_t)(hb*32 + r)*256 + gb*32 + c];
  }
  __syncthreads();
  #pragma unroll
  for (int it = 0; it < 4; ++it) {
    const int g = it*8 + r0, h = c;
    const float v = tile[h][g];
    const ushort_t hi = f2bf(v);
    const ushort_t lo = f2bf(v - bf2f(hi));
    const size_t off = (size_t)kl*65536 + (size_t)(gb*32 + g)*256 + hb*32 + h;
    Whi[off] = hi;
    Wlo[off] = lo;
  }
}

// ---------------- conv GEMM: Y[t] (+)= sum_c M[t*3+c] @ Wq[t*3+c] (64x64 tiles) ----------------
// grid (cb=4, rb=16, t=4), block 256 (4 waves of 16x64)
__global__ __launch_bounds__(256) void k_wxm(const ushort_t* __restrict__ Mhi,
    const ushort_t* __restrict__ Mlo, const ushort_t* __restrict__ Wqhi,
    const ushort_t* __restrict__ Wqlo, float* __restrict__ Y, int a)
{
  const int cb = blockIdx.x, rb = blockIdx.y, t = blockIdx.z;
  const int tid = threadIdx.x, wave = tid >> 6, lane = tid & 63;
  const int lrow = lane & 15, lgrp = lane >> 4;
  __shared__ __align__(16) ushort_t AswH[64*64];
  __shared__ __align__(16) ushort_t AswL[64*64];
  __shared__ __align__(16) ushort_t BswH[64*64];
  __shared__ __align__(16) ushort_t BswL[64*64];
  f32x4 acc[4];
  #pragma unroll
  for (int j = 0; j < 4; ++j) acc[j] = (f32x4){0.f,0.f,0.f,0.f};

  for (int c = 0; c < 3; ++c) {
    const int kl = t*3 + c;
    const ushort_t* Ah = Mhi + ((size_t)kl*1024 + rb*64)*256;
    const ushort_t* Al = Mlo + ((size_t)kl*1024 + rb*64)*256;
    const ushort_t* Bh = Wqhi + (size_t)kl*65536 + (size_t)cb*64*256;
    const ushort_t* Bl = Wqlo + (size_t)kl*65536 + (size_t)cb*64*256;
    for (int ks = 0; ks < 4; ++ks) {
      __syncthreads();
      #pragma unroll
      for (int it = 0; it < 2; ++it) {
        const int idx = tid + it*256;     // 0..511: 64 rows x 8 c8
        const int row = idx >> 3, c8 = idx & 7;
        const int off = row*64 + ((c8 ^ (row & 7)) << 3);
        const size_t gsrc = (size_t)row*256 + ks*64 + c8*8;
        *reinterpret_cast<bf16x8*>(&AswH[off]) = *reinterpret_cast<const bf16x8*>(Ah + gsrc);
        *reinterpret_cast<bf16x8*>(&AswL[off]) = *reinterpret_cast<const bf16x8*>(Al + gsrc);
        *reinterpret_cast<bf16x8*>(&BswH[off]) = *reinterpret_cast<const bf16x8*>(Bh + gsrc);
        *reinterpret_cast<bf16x8*>(&BswL[off]) = *reinterpret_cast<const bf16x8*>(Bl + gsrc);
      }
      __syncthreads();
      #pragma unroll
      for (int ksub = 0; ksub < 2; ++ksub) {
        const int c8 = ksub*4 + lgrp;
        const int arow = wave*16 + lrow;
        const int aoff = arow*64 + ((c8 ^ (arow & 7)) << 3);
        const bf16x8 ah = *reinterpret_cast<const bf16x8*>(&AswH[aoff]);
        const bf16x8 al = *reinterpret_cast<const bf16x8*>(&AswL[aoff]);
        #pragma unroll
        for (int nf = 0; nf < 4; ++nf) {
          const int g = nf*16 + lrow;
          const int boff = g*64 + ((c8 ^ (g & 7)) << 3);
          const bf16x8 bh = *reinterpret_cast<const bf16x8*>(&BswH[boff]);
          const bf16x8 bl = *reinterpret_cast<const bf16x8*>(&BswL[boff]);
          __builtin_amdgcn_s_setprio(1);
          acc[nf] = __builtin_amdgcn_mfma_f32_16x16x32_bf16(ah, bh, acc[nf], 0, 0, 0);
          acc[nf] = __builtin_amdgcn_mfma_f32_16x16x32_bf16(ah, bl, acc[nf], 0, 0, 0);
          acc[nf] = __builtin_amdgcn_mfma_f32_16x16x32_bf16(al, bh, acc[nf], 0, 0, 0);
          __builtin_amdgcn_s_setprio(0);
        }
      }
    }
  }
  float* Cb = Y + ((size_t)(t*1024 + rb*64))*256 + cb*64;
  #pragma unroll
  for (int nf = 0; nf < 4; ++nf)
    #pragma unroll
    for (int r = 0; r < 4; ++r) {
      const int row = wave*16 + lgrp*4 + r;
      const int col = nf*16 + lrow;
      if (a == 0) Cb[(size_t)row*256 + col] = acc[nf][r];
      else        Cb[(size_t)row*256 + col] += acc[nf][r];
    }
}

// ---------------- bias-gate + residual + LN + relu ----------------
__global__ __launch_bounds__(256) void k_ln(float* __restrict__ x,
    const float* __restrict__ y, const int* __restrict__ cnts,
    const float* __restrict__ convB, const float* __restrict__ ng,
    const float* __restrict__ nb, int l)
{
  const int r = blockIdx.x;
  const int t = r >> 10, d = r & 1023;
  const int tid = threadIdx.x;
  __shared__ float flag[12];
  __shared__ float rbuf[256];
  if (tid < 12) {
    const int a = tid / 3, c = tid - a*3;
    const int kj = a*12 + t*3 + c;
    flag[tid] = (cnts[kj*1024 + d] > 0) ? 1.f : 0.f;
  }
  __syncthreads();
  float v = y[(size_t)r*256 + tid] + x[(size_t)r*256 + tid];
  #pragma unroll
  for (int j = 0; j < 12; ++j) {
    const int a = j / 3, c = j - a*3;
    const int kj = a*12 + t*3 + c;
    v += flag[j] * convB[(size_t)(l*K_ + kj)*256 + tid];
  }
  rbuf[tid] = v; __syncthreads();
  for (int s = 128; s > 0; s >>= 1) { if (tid < s) rbuf[tid] += rbuf[tid+s]; __syncthreads(); }
  const float mean = rbuf[0] * (1.f/256.f); __syncthreads();
  const float diff = v - mean;
  rbuf[tid] = diff*diff; __syncthreads();
  for (int s = 128; s > 0; s >>= 1) { if (tid < s) rbuf[tid] += rbuf[tid+s]; __syncthreads(); }
  const float var = rbuf[0] * (1.f/256.f); __syncthreads();
  const float xn = diff * rsqrtf(var + 1e-5f) * ng[(size_t)(l*4 + t)*256 + tid]
                 + nb[(size_t)(l*4 + t)*256 + tid];
  x[(size_t)r*256 + tid] = fmaxf(xn, 0.f);
}

// ---------------- MFMA GEMM: C[i] = A @ Wt[i] + bias (A fp32, B pre-split hi/lo) ----------------
// grid (ncb, 32), block 256 (4 waves of 64x64 in 128x128 tile)
__global__ __launch_bounds__(256) void k_gemm(const float* __restrict__ A,
    const ushort_t* __restrict__ Bh, const ushort_t* __restrict__ Bl,
    const float* __restrict__ bias, float* __restrict__ C)
{
  const int cb = blockIdx.x, rb = blockIdx.y;
  const int col0 = cb*128, i = col0 >> 8, g0 = col0 & 255;
  const int tid = threadIdx.x, wave = tid >> 6, lane = tid & 63;
  const int lrow = lane & 15, lgrp = lane >> 4;
  const int wr = wave >> 1, wc = wave & 1;
  __shared__ __align__(16) ushort_t AswH[128*64];
  __shared__ __align__(16) ushort_t AswL[128*64];
  __shared__ __align__(16) ushort_t BswH[128*64];
  __shared__ __align__(16) ushort_t BswL[128*64];
  const float* Ab = A + (size_t)rb*128*256;
  const ushort_t* Bhp = Bh + (size_t)i*65536 + (size_t)g0*256;
  const ushort_t* Blp = Bl + (size_t)i*65536 + (size_t)g0*256;
  f32x4 acc[4][4];
  #pragma unroll
  for (int m = 0; m < 4; ++m)
    #pragma unroll
    for (int n = 0; n < 4; ++n) acc[m][n] = (f32x4){0.f,0.f,0.f,0.f};

  for (int ks = 0; ks < 4; ++ks) {
    __syncthreads();
    #pragma unroll
    for (int it = 0; it < 8; ++it) {
      const int idx = tid + it*256;       // 0..2047: 128 rows x 16 c4
      const int row = idx >> 4, c4 = idx & 15;
      const float4 v = *reinterpret_cast<const float4*>(Ab + (size_t)row*256 + ks*64 + c4*4);
      const float f[4] = {v.x, v.y, v.z, v.w};
      ushort_t hi[4], lo[4];
      #pragma unroll
      for (int e = 0; e < 4; ++e) {
        hi[e] = f2bf(f[e]);
        lo[e] = f2bf(f[e] - bf2f(hi[e]));
      }
      const int c8 = c4 >> 1, sub = (c4 & 1) * 4;
      const int off = row*64 + ((c8 ^ (row & 7)) << 3) + sub;
      *reinterpret_cast<uint2*>(&AswH[off]) = *reinterpret_cast<const uint2*>(hi);
      *reinterpret_cast<uint2*>(&AswL[off]) = *reinterpret_cast<const uint2*>(lo);
    }
    #pragma unroll
    for (int it = 0; it < 4; ++it) {
      const int idx = tid + it*256;       // 0..1023: 128 g x 8 c8
      const int row = idx >> 3, c8 = idx & 7;
      const int off = row*64 + ((c8 ^ (row & 7)) << 3);
      const size_t gsrc = (size_t)row*256 + ks*64 + c8*8;
      *reinterpret_cast<bf16x8*>(&BswH[off]) = *reinterpret_cast<const bf16x8*>(Bhp + gsrc);
      *reinterpret_cast<bf16x8*>(&BswL[off]) = *reinterpret_cast<const bf16x8*>(Blp + gsrc);
    }
    __syncthreads();
    #pragma unroll
    for (int ksub = 0; ksub < 2; ++ksub) {
      bf16x8 ah[4], al[4], bh[4], bl[4];
      const int c8 = ksub*4 + lgrp;
      #pragma unroll
      for (int mf = 0; mf < 4; ++mf) {
        const int row = wr*64 + mf*16 + lrow;
        const int off = row*64 + ((c8 ^ (row & 7)) << 3);
        ah[mf] = *reinterpret_cast<const bf16x8*>(&AswH[off]);
        al[mf] = *reinterpret_cast<const bf16x8*>(&AswL[off]);
      }
      #pragma unroll
      for (int nf = 0; nf < 4; ++nf) {
        const int row = wc*64 + nf*16 + lrow;
        const int off = row*64 + ((c8 ^ (row & 7)) << 3);
        bh[nf] = *reinterpret_cast<const bf16x8*>(&BswH[off]);
        bl[nf] = *reinterpret_cast<const bf16x8*>(&BswL[off]);
      }
      __builtin_amdgcn_s_setprio(1);
      #pragma unroll
      for (int mf = 0; mf < 4; ++mf)
        #pragma unroll
        for (int nf = 0; nf < 4; ++nf) {
          acc[mf][nf] = __builtin_amdgcn_mfma_f32_16x16x32_bf16(ah[mf], bh[nf], acc[mf][nf], 0, 0, 0);
          acc[mf][nf] = __builtin_amdgcn_mfma_f32_16x16x32_bf16(ah[mf], bl[nf], acc[mf][nf], 0, 0, 0);
          acc[mf][nf] = __builtin_amdgcn_mfma_f32_16x16x32_bf16(al[mf], bh[nf], acc[mf][nf], 0, 0, 0);
        }
      __builtin_amdgcn_s_setprio(0);
    }
  }
  float* Cp = C + (size_t)i*1048576 + (size_t)rb*128*256 + g0;
  const float* bp = bias + i*256 + g0;
  #pragma unroll
  for (int mf = 0; mf < 4; ++mf)
    #pragma unroll
    for (int nf = 0; nf < 4; ++nf)
      #pragma unroll
      for (int r = 0; r < 4; ++r) {
        const int row = wr*64 + mf*16 + lgrp*4 + r;
        const int col = wc*64 + nf*16 + lrow;
        Cp[(size_t)row*256 + col] = acc[mf][nf][r] + bp[col];
      }
}

// ---------------- cast QKV fp32 -> bf16 (Q scaled, V transposed) ----------------
__global__ __launch_bounds__(256) void k_cast(const float* __restrict__ qkv,
    ushort_t* __restrict__ Qh, ushort_t* __restrict__ Kh, ushort_t* __restrict__ Vt)
{
  const int rb = blockIdx.x, h = blockIdx.y;
  const int tid = threadIdx.x;
  const int r = tid >> 2, c8 = (tid & 3) * 8;
  const int row = rb*64 + r;
  __shared__ ushort_t vt[32][72];
  {
    const float* src = qkv + (size_t)row*256 + h*32 + c8;
    ushort_t tmp[8];
    #pragma unroll
    for (int j = 0; j < 8; ++j) tmp[j] = f2bf(src[j] * 0.17677669529663687f);
    *reinterpret_cast<uint4*>(Qh + ((size_t)(h*4096 + row))*32 + c8) = *reinterpret_cast<uint4*>(tmp);
  }
  {
    const float* src = qkv + 1048576 + (size_t)row*256 + h*32 + c8;
    ushort_t tmp[8];
    #pragma unroll
    for (int j = 0; j < 8; ++j) tmp[j] = f2bf(src[j]);
    *reinterpret_cast<uint4*>(Kh + ((size_t)(h*4096 + row))*32 + c8) = *reinterpret_cast<uint4*>(tmp);
  }
  {
    const float* src = qkv + 2097152 + (size_t)row*256 + h*32 + c8;
    #pragma unroll
    for (int j = 0; j < 8; ++j) vt[c8 + j][r] = f2bf(src[j]);
  }
  __syncthreads();
  const int d2 = tid >> 3, r0 = (tid & 7) * 8;
  *reinterpret_cast<uint4*>(Vt + ((size_t)(h*32 + d2))*4096 + rb*64 + r0)
      = *reinterpret_cast<const uint4*>(&vt[d2][r0]);
}

// ---------------- MFMA flash attention, max-free softmax, KVBLK=128, split-K 4 ----------------
// grid (64, 8, 4), block 256 (4 waves x 16 q-rows)
__global__ __launch_bounds__(256) void k_attn2(const ushort_t* __restrict__ Qh,
    const ushort_t* __restrict__ Kh, const ushort_t* __restrict__ Vt,
    float* __restrict__ pacc, float* __restrict__ pacc3, float* __restrict__ pml)
{
  const int tid = threadIdx.x;
  const int wave = tid >> 6, lane = tid & 63;
  const int lrow = lane & 15, lgrp = lane >> 4;
  const int h = blockIdx.y, sp = blockIdx.z;
  const int q0 = blockIdx.x * 64 + wave * 16;
  __shared__ ushort_t P[4][16][136];

  const bf16x8 qf = *reinterpret_cast<const bf16x8*>(
      Qh + ((size_t)(h*4096 + q0 + lrow))*32 + lgrp*8);

  float lsum[4] = {0.f, 0.f, 0.f, 0.f};
  f32x4 o0 = {0.f,0.f,0.f,0.f}, o1 = {0.f,0.f,0.f,0.f};

  const ushort_t* Kbase = Kh + (size_t)(h*4096)*32;
  const ushort_t* Vbase = Vt + (size_t)(h*32)*4096;

  for (int kt = 0; kt < 8; ++kt) {
    const int kb = sp*1024 + kt*128;
    f32x4 s[8];
    __builtin_amdgcn_s_setprio(1);
    #pragma unroll
    for (int ks = 0; ks < 8; ++ks) {
      const bf16x8 kf = *reinterpret_cast<const bf16x8*>(
          Kbase + (size_t)(kb + ks*16 + lrow)*32 + lgrp*8);
      f32x4 z = {0.f,0.f,0.f,0.f};
      s[ks] = __builtin_amdgcn_mfma_f32_16x16x32_bf16(qf, kf, z, 0, 0, 0);
    }
    __builtin_amdgcn_s_setprio(0);
    #pragma unroll
    for (int ks = 0; ks < 8; ++ks) {
      #pragma unroll
      for (int r = 0; r < 4; ++r) {
        const float p = __expf(s[ks][r]);
        lsum[r] += p;
        P[wave][lgrp*4 + r][ks*16 + lrow] = f2bf_rn(p);
      }
    }
    __builtin_amdgcn_s_setprio(1);
    #pragma unroll
    for (int ks2 = 0; ks2 < 4; ++ks2) {
      const bf16x8 pa = *reinterpret_cast<const bf16x8*>(&P[wave][lrow][ks2*32 + lgrp*8]);
      const bf16x8 v0 = *reinterpret_cast<const bf16x8*>(
          Vbase + (size_t)lrow*4096 + kb + ks2*32 + lgrp*8);
      const bf16x8 v1 = *reinterpret_cast<const bf16x8*>(
          Vbase + (size_t)(16 + lrow)*4096 + kb + ks2*32 + lgrp*8);
      o0 = __builtin_amdgcn_mfma_f32_16x16x32_bf16(pa, v0, o0, 0, 0, 0);
      o1 = __builtin_amdgcn_mfma_f32_16x16x32_bf16(pa, v1, o1, 0, 0, 0);
    }
    __builtin_amdgcn_s_setprio(0);
  }
  float* po = (sp == 3) ? pacc3 : (pacc + (size_t)sp*1048576);
  #pragma unroll
  for (int r = 0; r < 4; ++r) {
    float l = lsum[r];
    l += __shfl_xor(l, 1); l += __shfl_xor(l, 2);
    l += __shfl_xor(l, 4); l += __shfl_xor(l, 8);
    const int row = q0 + lgrp*4 + r;
    const size_t base = ((size_t)row*8 + h)*32;
    po[base + lrow]      = o0[r];
    po[base + 16 + lrow] = o1[r];
    if (lrow == 0) pml[((size_t)row*8 + h)*4 + sp] = l;
  }
}

__global__ __launch_bounds__(256) void k_attn_merge(const float* __restrict__ pacc,
    const float* __restrict__ pacc3, const float* __restrict__ pml,
    float* __restrict__ attno)
{
  const int gid = blockIdx.x*256 + threadIdx.x;      // 4096*8*32
  const int rh = gid >> 5, d = gid & 31;
  const int r = rh >> 3, h = rh & 7;
  const float den = pml[rh*4+0] + pml[rh*4+1] + pml[rh*4+2] + pml[rh*4+3];
  const size_t idx = (size_t)rh*32 + d;
  const float sum = pacc[idx] + pacc[1048576 + idx] + pacc[2097152 + idx] + pacc3[idx];
  attno[(size_t)r*256 + h*32 + d] = sum / den;
}

// ---------------- pooling ----------------
__global__ __launch_bounds__(256) void k_pool_logits(const float* __restrict__ z,
    const float* __restrict__ pW, const float* __restrict__ pb, float* __restrict__ logits)
{
  const int tid = threadIdx.x;
  const int wave = tid >> 6, lane = tid & 63;
  const int r = blockIdx.x*4 + wave;
  const float4 zv = reinterpret_cast<const float4*>(z + (size_t)r*256)[lane];
  const float4 wv = reinterpret_cast<const float4*>(pW)[lane];
  float dv = zv.x*wv.x + zv.y*wv.y + zv.z*wv.z + zv.w*wv.w;
  for (int off = 32; off; off >>= 1) dv += __shfl_down(dv, off);
  if (lane == 0) logits[r] = dv + pb[0];
}

__global__ __launch_bounds__(256) void k_pool_stats(const float* __restrict__ logits,
    float* __restrict__ stats)
{
  const int tid = threadIdx.x;
  __shared__ float rbuf[256];
  float mx = -1e30f;
  for (int i = tid; i < 4096; i += 256) mx = fmaxf(mx, logits[i]);
  rbuf[tid] = mx; __syncthreads();
  for (int s = 128; s > 0; s >>= 1) { if (tid < s) rbuf[tid] = fmaxf(rbuf[tid], rbuf[tid+s]); __syncthreads(); }
  mx = rbuf[0]; __syncthreads();
  float se = 0.f;
  for (int i = tid; i < 4096; i += 256) se += __expf(logits[i] - mx);
  rbuf[tid] = se; __syncthreads();
  for (int s = 128; s > 0; s >>= 1) { if (tid < s) rbuf[tid] += rbuf[tid+s]; __syncthreads(); }
  if (tid == 0) { stats[0] = mx; stats[1] = rbuf[0]; }
}

__global__ __launch_bounds__(256) void k_pool_partial(const float* __restrict__ z,
    const float* __restrict__ logits, const float* __restrict__ stats,
    float* __restrict__ partial)
{
  const int pb = blockIdx.x, tid = threadIdx.x;
  const float mx = stats[0], se = stats[1];
  __shared__ float wl[64];
  if (tid < 64) wl[tid] = __expf(logits[pb*64 + tid] - mx) / se;
  __syncthreads();
  float acc = 0.f;
  for (int n = 0; n < 64; ++n) acc += wl[n] * z[(size_t)(pb*64 + n)*256 + tid];
  partial[pb*256 + tid] = acc;
}

// ---------------- heads helpers ----------------
__device__ __forceinline__ void mv256(const float* __restrict__ W,
    const float* __restrict__ sIn, float (*red)[256], int o, int hq)
{
  float a0 = 0.f, a1 = 0.f, a2 = 0.f, a3 = 0.f;
  const float* Wp = W + (size_t)(hq*64)*256 + o;
  const float* ip = sIn + hq*64;
  #pragma unroll
  for (int j = 0; j < 16; ++j) {
    a0 += ip[j*4+0] * Wp[(size_t)(j*4+0)*256];
    a1 += ip[j*4+1] * Wp[(size_t)(j*4+1)*256];
    a2 += ip[j*4+2] * Wp[(size_t)(j*4+2)*256];
    a3 += ip[j*4+3] * Wp[(size_t)(j*4+3)*256];
  }
  red[hq][o] = (a0 + a1) + (a2 + a3);
}

// ---------------- heads (single block, 1024 threads) ----------------
__global__ __launch_bounds__(1024) void k_heads(
    const float* __restrict__ partial,
    const float* __restrict__ cx, const float* __restrict__ cW, const float* __restrict__ cb,
    const float* __restrict__ taW1, const float* __restrict__ tab1,
    const float* __restrict__ tag, const float* __restrict__ tabeta,
    const float* __restrict__ taW2, const float* __restrict__ tab2,
    const float* __restrict__ shW1, const float* __restrict__ shb1,
    const float* __restrict__ shW2, const float* __restrict__ shb2,
    const float* __restrict__ fprWa, const float* __restrict__ fprba,
    const float* __restrict__ fprg, const float* __restrict__ fprbeta,
    const float* __restrict__ fprW1, const float* __restrict__ fprb1,
    const float* __restrict__ fprW2, const float* __restrict__ fprb2,
    const float* __restrict__ secW1, const float* __restrict__ secb1,
    const float* __restrict__ secW2, const float* __restrict__ secb2,
    float* __restrict__ out)
{
  const int tid = threadIdx.x;
  const int o = tid & 255, hq = tid >> 8;
  __shared__ float semb[256], esec[256], efpr[256], vbuf[256];
  __shared__ float red[4][256];
  __shared__ float rbuf[256];
  __shared__ float h1s[640];
  float* redf = &red[0][0];

  {
    float acc = 0.f;
    #pragma unroll
    for (int pb = 0; pb < 16; ++pb) acc += partial[(hq*16 + pb)*256 + o];
    #pragma unroll
    for (int i = 0; i < 8; ++i) acc += cx[hq*8 + i] * cW[(hq*8 + i)*256 + o];
    red[hq][o] = acc;
  }
  __syncthreads();
  if (tid < 256) semb[tid] = red[0][tid] + red[1][tid] + red[2][tid] + red[3][tid] + cb[tid];
  __syncthreads();

  for (int i = 0; i < 2; ++i) {
    mv256(taW1 + (size_t)i*65536, semb, red, o, hq);
    __syncthreads();
    float u = 0.f;
    if (tid < 256) u = red[0][tid] + red[1][tid] + red[2][tid] + red[3][tid] + tab1[i*256 + tid];
    if (tid < 256) rbuf[tid] = u;
    __syncthreads();
    for (int s = 128; s > 0; s >>= 1) { if (tid < s) rbuf[tid] += rbuf[tid+s]; __syncthreads(); }
    const float mean = rbuf[0] * (1.f/256.f);
    __syncthreads();
    const float diff = u - mean;
    if (tid < 256) rbuf[tid] = diff*diff;
    __syncthreads();
    for (int s = 128; s > 0; s >>= 1) { if (tid < s) rbuf[tid] += rbuf[tid+s]; __syncthreads(); }
    const float var = rbuf[0] * (1.f/256.f);
    __syncthreads();
    if (tid < 256)
      vbuf[tid] = fmaxf(diff * rsqrtf(var + 1e-5f) * tag[i*256 + tid] + tabeta[i*256 + tid], 0.f);
    __syncthreads();
    mv256(taW2 + (size_t)i*65536, vbuf, red, o, hq);
    __syncthreads();
    if (tid < 256) {
      const float s2v = red[0][tid] + red[1][tid] + red[2][tid] + red[3][tid] + tab2[i*256 + tid];
      const float att = semb[tid] * (1.f/(1.f + __expf(-s2v)));
      if (i == 0) esec[tid] = att; else efpr[tid] = att;
    }
    __syncthreads();
  }

  {
    const int oo = tid & 511, ii = oo >> 7, col = oo & 127, hh = tid >> 9;
    float a0 = 0.f, a1 = 0.f, a2 = 0.f, a3 = 0.f;
    const float* Wp = shW1 + (size_t)ii*32768 + (size_t)(hh*128)*128 + col;
    const float* ip = semb + hh*128;
    #pragma unroll
    for (int j = 0; j < 32; ++j) {
      a0 += ip[j*4+0] * Wp[(size_t)(j*4+0)*128];
      a1 += ip[j*4+1] * Wp[(size_t)(j*4+1)*128];
      a2 += ip[j*4+2] * Wp[(size_t)(j*4+2)*128];
      a3 += ip[j*4+3] * Wp[(size_t)(j*4+3)*128];
    }
    redf[hh*512 + oo] = (a0 + a1) + (a2 + a3);
  }
  __syncthreads();
  if (tid < 512) {
    const int ii = tid >> 7, col = tid & 127;
    h1s[tid] = fmaxf(redf[tid] + redf[512 + tid] + shb1[ii*128 + col], 0.f);
  }
  __syncthreads();
  if (tid < 20) {
    const int ii = tid / 5, c = tid % 5;
    const int rowm = (ii == 0) ? 0 : (ii + 1);
    float ov = shb2[ii*5 + c];
    for (int hh = 0; hh < 128; ++hh) ov += h1s[ii*128 + hh] * shW2[ii*640 + hh*5 + c];
    out[rowm*5 + c] = 1.f/(1.f + __expf(-ov));
  }

  mv256(fprWa, efpr, red, o, hq);
  __syncthreads();
  {
    float u = 0.f;
    if (tid < 256) u = red[0][tid] + red[1][tid] + red[2][tid] + red[3][tid] + fprba[tid];
    if (tid < 256) rbuf[tid] = u;
    __syncthreads();
    for (int s = 128; s > 0; s >>= 1) { if (tid < s) rbuf[tid] += rbuf[tid+s]; __syncthreads(); }
    const float mean = rbuf[0] * (1.f/256.f);
    __syncthreads();
    const float diff = u - mean;
    if (tid < 256) rbuf[tid] = diff*diff;
    __syncthreads();
    for (int s = 128; s > 0; s >>= 1) { if (tid < s) rbuf[tid] += rbuf[tid+s]; __syncthreads(); }
    const float var = rbuf[0] * (1.f/256.f);
    __syncthreads();
    if (tid < 256)
      vbuf[tid] = fmaxf(diff * rsqrtf(var + 1e-5f) * fprg[tid] + fprbeta[tid], 0.f);
    __syncthreads();
  }
  {
    const int col = tid & 127, hs = tid >> 7;
    float a0 = 0.f, a1 = 0.f;
    const float* Wp = fprW1 + (size_t)(hs*32)*128 + col;
    const float* ip = vbuf + hs*32;
    #pragma unroll
    for (int j = 0; j < 16; ++j) {
      a0 += ip[j*2+0] * Wp[(size_t)(j*2+0)*128];
      a1 += ip[j*2+1] * Wp[(size_t)(j*2+1)*128];
    }
    redf[hs*128 + col] = a0 + a1;
  }
  __syncthreads();
  if (tid < 128) {
    float hv = fprb1[tid];
    #pragma unroll
    for (int s = 0; s < 8; ++s) hv += redf[s*128 + tid];
    h1s[tid] = fmaxf(hv, 0.f);
  }
  __syncthreads();
  if (tid < 5) {
    float ov = fprb2[tid];
    for (int hh = 0; hh < 128; ++hh) ov += h1s[hh] * fprW2[hh*5 + tid];
    out[5 + tid] = 1.f/(1.f + __expf(-ov));
  }
  __syncthreads();

  if (tid < 640) {
    const int ii = tid >> 7, col = tid & 127;
    float a0 = 0.f, a1 = 0.f, a2 = 0.f, a3 = 0.f;
    const float* Wp = secW1 + (size_t)ii*32768 + col;
    #pragma unroll
    for (int j = 0; j < 64; ++j) {
      a0 += esec[j*4+0] * Wp[(size_t)(j*4+0)*128];
      a1 += esec[j*4+1] * Wp[(size_t)(j*4+1)*128];
      a2 += esec[j*4+2] * Wp[(size_t)(j*4+2)*128];
      a3 += esec[j*4+3] * Wp[(size_t)(j*4+3)*128];
    }
    h1s[tid] = fmaxf((a0 + a1) + (a2 + a3) + secb1[ii*128 + col], 0.f);
  }
  __syncthreads();
  if (tid < 5) {
    float ov = secb2[tid];
    for (int hh = 0; hh < 128; ++hh) ov += h1s[tid*128 + hh] * secW2[tid*128 + hh];
    out[tid*5 + 1] = 1.f/(1.f + __expf(-ov));
  }
}

// ---------------- launcher ----------------
extern "C" void kernel_launch(void* const* d_in, const int* in_sizes, int n_in,
                              void* d_out, int out_size, void* d_ws, size_t ws_size,
                              hipStream_t stream)
{
  const float* x_nodes    = (const float*)d_in[0];
  const float* contract_x = (const float*)d_in[1];
  const float* proj_W     = (const float*)d_in[2];
  const float* proj_b     = (const float*)d_in[3];
  const float* conv_W     = (const float*)d_in[4];
  const float* conv_b     = (const float*)d_in[5];
  const float* norm_g     = (const float*)d_in[6];
  const float* norm_b     = (const float*)d_in[7];
  const float* attn_W     = (const float*)d_in[8];
  const float* attn_b     = (const float*)d_in[9];
  const float* pool_W     = (const float*)d_in[10];
  const float* pool_b     = (const float*)d_in[11];
  const float* contract_W = (const float*)d_in[12];
  const float* contract_b = (const float*)d_in[13];
  const float* ta_W1      = (const float*)d_in[14];
  const float* ta_b1      = (const float*)d_in[15];
  const float* ta_g       = (const float*)d_in[16];
  const float* ta_beta    = (const float*)d_in[17];
  const float* ta_W2      = (const float*)d_in[18];
  const float* ta_b2      = (const float*)d_in[19];
  const float* sh_W1      = (const float*)d_in[20];
  const float* sh_b1      = (const float*)d_in[21];
  const float* sh_W2      = (const float*)d_in[22];
  const float* sh_b2      = (const float*)d_in[23];
  const float* fpr_Wa     = (const float*)d_in[24];
  const float* fpr_ba     = (const float*)d_in[25];
  const float* fpr_g      = (const float*)d_in[26];
  const float* fpr_beta   = (const float*)d_in[27];
  const float* fpr_W1     = (const float*)d_in[28];
  const float* fpr_b1     = (const float*)d_in[29];
  const float* fpr_W2     = (const float*)d_in[30];
  const float* fpr_b2     = (const float*)d_in[31];
  const float* sec_W1     = (const float*)d_in[32];
  const float* sec_b1     = (const float*)d_in[33];
  const float* sec_W2     = (const float*)d_in[34];
  const float* sec_b2     = (const float*)d_in[35];
  const int*   edge_index = (const int*)d_in[36];

  float* ws = (float*)d_ws;
  float* X     = ws + WS_X;
  float* Y     = ws + WS_Y;
  int*   ints  = (int*)(ws + WS_INT);
  int*   CNTS  = ints + WS_CNTS;
  int*   OFFS  = ints + WS_OFFS;
  int*   CUR   = ints + WS_CUR;
  int*   ELIST = ints + WS_ELIST;
  ushort_t* MHI  = (ushort_t*)(ws + WS_M);
  ushort_t* MLO  = MHI + (size_t)12*1024*256;
  ushort_t* WQHI = (ushort_t*)(ws + WS_WQ);     // 24-matrix half
  ushort_t* WQLO = WQHI + (size_t)24*65536;
  float* QKV   = ws + WS_QKV;
  float* PACC  = ws + WS_QKV;                   // sp0..2 (3 x 1M floats)
  float* PACC3 = ws + WS_X;                     // sp3 reuses X region
  float* PML   = ws + WS_PML;
  ushort_t* QH = (ushort_t*)(ws + WS_BF);
  ushort_t* KH = (ushort_t*)(ws + WS_BF + 524288);
  ushort_t* VT = (ushort_t*)(ws + WS_BF + 1048576);
  ushort_t* AWHI = (ushort_t*)(ws + WS_AW);
  ushort_t* AWLO = AWHI + (size_t)4*65536;
  float* PART  = ws + WS_PART;
  float* LOG   = ws + WS_LOG;
  float* STATS = ws + WS_STATS;

  hipMemsetAsync(CNTS, 0, (size_t)K_*NPT_*sizeof(int), stream);

  k_proj<<<dim3(4096), 256, 0, stream>>>(x_nodes, proj_W, proj_b, X);
  k_hist<<<dim3(1536), 256, 0, stream>>>(edge_index, CNTS);
  k_scan<<<dim3(48), 1024, 0, stream>>>(CNTS, OFFS, CUR);
  k_scatter<<<dim3(1536), 256, 0, stream>>>(edge_index, CUR, ELIST);
  k_wprep<<<dim3(4, 8, 8), 256, 0, stream>>>(attn_W, AWHI, AWLO);

  for (int l = 0; l < L_; ++l) {
    for (int half = 0; half < 2; ++half) {
      k_wprep<<<dim3(24, 8, 8), 256, 0, stream>>>(
          conv_W + ((size_t)(l*K_ + half*24))*65536, WQHI, WQLO);
      for (int aa = 0; aa < 2; ++aa) {
        const int a = half*2 + aa;
        k_means<<<dim3(3072), 256, 0, stream>>>(X, OFFS, ELIST, MHI, MLO, a);
        k_wxm<<<dim3(4, 16, 4), 256, 0, stream>>>(MHI, MLO,
            WQHI + (size_t)aa*12*65536, WQLO + (size_t)aa*12*65536, Y, a);
      }
    }
    k_ln<<<dim3(4096), 256, 0, stream>>>(X, Y, CNTS, conv_b, norm_g, norm_b, l);
  }

  // qkv via MFMA GEMM, then cast to bf16 fragments
  k_gemm<<<dim3(6, 32), 256, 0, stream>>>(X, AWHI, AWLO, attn_b, QKV);
  k_cast<<<dim3(64, 8), 256, 0, stream>>>(QKV, QH, KH, VT);
  // MFMA flash attention (split-K 4) -> PACC sp0-2 (QKV region) + sp3 (X region)
  k_attn2<<<dim3(64, 8, 4), 256, 0, stream>>>(QH, KH, VT, PACC, PACC3, PML);
  k_attn_merge<<<dim3(4096), 256, 0, stream>>>(PACC, PACC3, PML, Y);
  // out projection -> z2 at QKV base
  k_gemm<<<dim3(2, 32), 256, 0, stream>>>(Y, AWHI + (size_t)3*65536,
      AWLO + (size_t)3*65536, attn_b + 768, QKV);
  // pooling
  k_pool_logits<<<dim3(1024), 256, 0, stream>>>(QKV, pool_W, pool_b, LOG);
  k_pool_stats<<<dim3(1), 256, 0, stream>>>(LOG, STATS);
  k_pool_partial<<<dim3(64), 256, 0, stream>>>(QKV, LOG, STATS, PART);
  // heads
  k_heads<<<dim3(1), 1024, 0, stream>>>(PART,
      contract_x, contract_W, contract_b,
      ta_W1, ta_b1, ta_g, ta_beta, ta_W2, ta_b2,
      sh_W1, sh_b1, sh_W2, sh_b2,
      fpr_Wa, fpr_ba, fpr_g, fpr_beta, fpr_W1, fpr_b1, fpr_W2, fpr_b2,
      sec_W1, sec_b1, sec_W2, sec_b2,
      (float*)d_out);
}

// Round 9
// 625.767 us; speedup vs baseline: 3.9079x; 1.0003x over previous
//
#include <hip/hip_runtime.h>
#include <hip/hip_bf16.h>
#include <cstddef>
#include <cstdint>

typedef unsigned short ushort_t;
typedef __attribute__((ext_vector_type(8))) short bf16x8;
typedef __attribute__((ext_vector_type(4))) float f32x4;
typedef __attribute__((ext_vector_type(2))) unsigned int u32x2;

// ---------------- constants ----------------
#define H_ 256
#define NPT_ 1024
#define E_ 8192
#define K_ 48
#define L_ 3

// ws layout in floats (~31.3 MB peak)
#define WS_X      0u          // X fp32 [4][1024][256]; pacc sp3 during attn
#define WS_Y      1048576u    // conv GEMM accum / z2 after out-proj
#define WS_INT    2097152u    // int region
#define WS_CNTS   0u
#define WS_OFFS   49152u
#define WS_CUR    98352u
#define WS_ELIST  147504u
#define WS_M      2700288u    // Mhi/Mlo bf16 quarter (3145728 floats)
#define WS_QKV    2700288u    // pacc sp0-2 during attention
#define WS_WQ     5846016u    // conv W HALF hi/lo (1572864 floats)
#define WS_BF     5846016u    // bf16 Q/K/Vt post-conv (same region)
#define WS_PART   7418880u
#define WS_LOG    7435264u
#define WS_STATS  7439360u
#define WS_AW     7440000u    // attn_W hi/lo (262144 floats) -> 7702144
#define WS_PML    7702144u    // attn split l-sums -> 7833216

__device__ __forceinline__ ushort_t f2bf(float x) {
  unsigned u = __float_as_uint(x);
  unsigned r = (u + 0x7FFFu + ((u >> 16) & 1u)) >> 16;
  return (ushort_t)r;
}
__device__ __forceinline__ float bf2f(ushort_t x) {
  return __uint_as_float(((unsigned)x) << 16);
}
__device__ __forceinline__ ushort_t f2bf_rn(float x) {
  __hip_bfloat16 h = __float2bfloat16(x);
  return *reinterpret_cast<ushort_t*>(&h);
}

// ---------------- proj ----------------
__global__ __launch_bounds__(256) void k_proj(const float* __restrict__ xn,
    const float* __restrict__ pW, const float* __restrict__ pb,
    float* __restrict__ x)
{
  const int t = blockIdx.x >> 10, n = blockIdx.x & 1023;
  const int tid = threadIdx.x;
  __shared__ float xr[32];
  if (tid < 21) xr[tid] = xn[(size_t)(t*1024 + n)*21 + tid];
  __syncthreads();
  float acc = pb[t*256 + tid];
  #pragma unroll
  for (int i = 0; i < 21; ++i) acc += xr[i] * pW[(size_t)(t*21 + i)*256 + tid];
  x[(size_t)(t*1024 + n)*256 + tid] = acc;
}

// ---------------- CSR build ----------------
__global__ __launch_bounds__(256) void k_hist(const int* __restrict__ ei, int* __restrict__ cnts)
{
  const int gid = blockIdx.x*256 + threadIdx.x;
  const int k = gid >> 13, e = gid & 8191;
  const int dst = ei[(size_t)k*2*E_ + E_ + e];
  atomicAdd(&cnts[k*1024 + dst], 1);
}

__global__ __launch_bounds__(1024) void k_scan(const int* __restrict__ cnts,
    int* __restrict__ offs, int* __restrict__ cur)
{
  const int k = blockIdx.x, tid = threadIdx.x;
  __shared__ int s[1024];
  const int v = cnts[k*1024 + tid];
  s[tid] = v; __syncthreads();
  for (int off = 1; off < 1024; off <<= 1) {
    int add = 0;
    if (tid >= off) add = s[tid - off];
    __syncthreads();
    s[tid] += add;
    __syncthreads();
  }
  const int ex = s[tid] - v;
  offs[k*1025 + tid] = ex;
  cur[k*1024 + tid] = ex;
  if (tid == 1023) offs[k*1025 + 1024] = s[1023];
}

__global__ __launch_bounds__(256) void k_scatter(const int* __restrict__ ei,
    int* __restrict__ cur, int* __restrict__ elist)
{
  const int gid = blockIdx.x*256 + threadIdx.x;
  const int k = gid >> 13, e = gid & 8191;
  const int src = ei[(size_t)k*2*E_ + e];
  const int dst = ei[(size_t)k*2*E_ + E_ + e];
  const int p = atomicAdd(&cur[k*1024 + dst], 1);
  elist[k*E_ + p] = src;
}

// ---------------- means ----------------
__global__ __launch_bounds__(256) void k_means(const float* __restrict__ X,
    const int* __restrict__ offs, const int* __restrict__ elist,
    ushort_t* __restrict__ Mhi, ushort_t* __restrict__ Mlo, int a)
{
  const int pid = blockIdx.x*4 + (threadIdx.x >> 6);
  const int kl = pid >> 10, d = pid & 1023;
  const int lane = threadIdx.x & 63;
  const int kg = a*12 + kl;
  const int o0 = offs[kg*1025 + d];
  const int o1 = offs[kg*1025 + d + 1];
  const float* xb = X + (size_t)a*1024*256;
  float4 s = {0.f, 0.f, 0.f, 0.f};
  int p = o0;
  while (p + 8 <= o1) {
    int srcs[8];
    #pragma unroll
    for (int q = 0; q < 8; ++q) srcs[q] = elist[(size_t)kg*E_ + p + q];
    float4 v[8];
    #pragma unroll
    for (int q = 0; q < 8; ++q)
      v[q] = *reinterpret_cast<const float4*>(xb + (size_t)srcs[q]*256 + lane*4);
    s.x += ((v[0].x+v[1].x)+(v[2].x+v[3].x)) + ((v[4].x+v[5].x)+(v[6].x+v[7].x));
    s.y += ((v[0].y+v[1].y)+(v[2].y+v[3].y)) + ((v[4].y+v[5].y)+(v[6].y+v[7].y));
    s.z += ((v[0].z+v[1].z)+(v[2].z+v[3].z)) + ((v[4].z+v[5].z)+(v[6].z+v[7].z));
    s.w += ((v[0].w+v[1].w)+(v[2].w+v[3].w)) + ((v[4].w+v[5].w)+(v[6].w+v[7].w));
    p += 8;
  }
  while (p + 4 <= o1) {
    const int s0 = elist[(size_t)kg*E_ + p + 0];
    const int s1 = elist[(size_t)kg*E_ + p + 1];
    const int s2 = elist[(size_t)kg*E_ + p + 2];
    const int s3 = elist[(size_t)kg*E_ + p + 3];
    const float4 v0 = *reinterpret_cast<const float4*>(xb + (size_t)s0*256 + lane*4);
    const float4 v1 = *reinterpret_cast<const float4*>(xb + (size_t)s1*256 + lane*4);
    const float4 v2 = *reinterpret_cast<const float4*>(xb + (size_t)s2*256 + lane*4);
    const float4 v3 = *reinterpret_cast<const float4*>(xb + (size_t)s3*256 + lane*4);
    s.x += (v0.x + v1.x) + (v2.x + v3.x);
    s.y += (v0.y + v1.y) + (v2.y + v3.y);
    s.z += (v0.z + v1.z) + (v2.z + v3.z);
    s.w += (v0.w + v1.w) + (v2.w + v3.w);
    p += 4;
  }
  while (p < o1) {
    const int sp = elist[(size_t)kg*E_ + p];
    const float4 v = *reinterpret_cast<const float4*>(xb + (size_t)sp*256 + lane*4);
    s.x += v.x; s.y += v.y; s.z += v.z; s.w += v.w;
    ++p;
  }
  const float inv = 1.f / fmaxf((float)(o1 - o0), 1.f);
  const float mv[4] = {s.x*inv, s.y*inv, s.z*inv, s.w*inv};
  ushort_t hi[4], lo[4];
  #pragma unroll
  for (int e = 0; e < 4; ++e) {
    hi[e] = f2bf(mv[e]);
    lo[e] = f2bf(mv[e] - bf2f(hi[e]));
  }
  const size_t base = ((size_t)kl*1024 + d)*256 + lane*4;
  *reinterpret_cast<ushort4*>(Mhi + base) = *reinterpret_cast<const ushort4*>(hi);
  *reinterpret_cast<ushort4*>(Mlo + base) = *reinterpret_cast<const ushort4*>(lo);
}

// ---------------- W prep: transpose + hi/lo split ----------------
__global__ __launch_bounds__(256) void k_wprep(const float* __restrict__ Wsrc,
    ushort_t* __restrict__ Whi, ushort_t* __restrict__ Wlo)
{
  const int kl = blockIdx.x, hb = blockIdx.y, gb = blockIdx.z;
  const int tid = threadIdx.x;
  __shared__ float tile[32][33];
  const float* W = Wsrc + (size_t)kl*65536;
  const int r0 = tid >> 5, c = tid & 31;
  #pragma unroll
  for (int it = 0; it < 4; ++it) {
    const int r = it*8 + r0;
    tile[r][c] = W[(size_t)(hb*32 + r)*256 + gb*32 + c];
  }
  __syncthreads();
  #pragma unroll
  for (int it = 0; it < 4; ++it) {
    const int g = it*8 + r0, h = c;
    const float v = tile[h][g];
    const ushort_t hi = f2bf(v);
    const ushort_t lo = f2bf(v - bf2f(hi));
    const size_t off = (size_t)kl*65536 + (size_t)(gb*32 + g)*256 + hb*32 + h;
    Whi[off] = hi;
    Wlo[off] = lo;
  }
}

// ---------------- conv GEMM ----------------
__global__ __launch_bounds__(256) void k_wxm(const ushort_t* __restrict__ Mhi,
    const ushort_t* __restrict__ Mlo, const ushort_t* __restrict__ Wqhi,
    const ushort_t* __restrict__ Wqlo, float* __restrict__ Y, int a)
{
  const int cb = blockIdx.x, rb = blockIdx.y, t = blockIdx.z;
  const int tid = threadIdx.x, wave = tid >> 6, lane = tid & 63;
  const int lrow = lane & 15, lgrp = lane >> 4;
  __shared__ __align__(16) ushort_t AswH[64*64];
  __shared__ __align__(16) ushort_t AswL[64*64];
  __shared__ __align__(16) ushort_t BswH[64*64];
  __shared__ __align__(16) ushort_t BswL[64*64];
  f32x4 acc[4];
  #pragma unroll
  for (int j = 0; j < 4; ++j) acc[j] = (f32x4){0.f,0.f,0.f,0.f};

  for (int c = 0; c < 3; ++c) {
    const int kl = t*3 + c;
    const ushort_t* Ah = Mhi + ((size_t)kl*1024 + rb*64)*256;
    const ushort_t* Al = Mlo + ((size_t)kl*1024 + rb*64)*256;
    const ushort_t* Bh = Wqhi + (size_t)kl*65536 + (size_t)cb*64*256;
    const ushort_t* Bl = Wqlo + (size_t)kl*65536 + (size_t)cb*64*256;
    for (int ks = 0; ks < 4; ++ks) {
      __syncthreads();
      #pragma unroll
      for (int it = 0; it < 2; ++it) {
        const int idx = tid + it*256;
        const int row = idx >> 3, c8 = idx & 7;
        const int off = row*64 + ((c8 ^ (row & 7)) << 3);
        const size_t gsrc = (size_t)row*256 + ks*64 + c8*8;
        *reinterpret_cast<bf16x8*>(&AswH[off]) = *reinterpret_cast<const bf16x8*>(Ah + gsrc);
        *reinterpret_cast<bf16x8*>(&AswL[off]) = *reinterpret_cast<const bf16x8*>(Al + gsrc);
        *reinterpret_cast<bf16x8*>(&BswH[off]) = *reinterpret_cast<const bf16x8*>(Bh + gsrc);
        *reinterpret_cast<bf16x8*>(&BswL[off]) = *reinterpret_cast<const bf16x8*>(Bl + gsrc);
      }
      __syncthreads();
      #pragma unroll
      for (int ksub = 0; ksub < 2; ++ksub) {
        const int c8 = ksub*4 + lgrp;
        const int arow = wave*16 + lrow;
        const int aoff = arow*64 + ((c8 ^ (arow & 7)) << 3);
        const bf16x8 ah = *reinterpret_cast<const bf16x8*>(&AswH[aoff]);
        const bf16x8 al = *reinterpret_cast<const bf16x8*>(&AswL[aoff]);
        #pragma unroll
        for (int nf = 0; nf < 4; ++nf) {
          const int g = nf*16 + lrow;
          const int boff = g*64 + ((c8 ^ (g & 7)) << 3);
          const bf16x8 bh = *reinterpret_cast<const bf16x8*>(&BswH[boff]);
          const bf16x8 bl = *reinterpret_cast<const bf16x8*>(&BswL[boff]);
          __builtin_amdgcn_s_setprio(1);
          acc[nf] = __builtin_amdgcn_mfma_f32_16x16x32_bf16(ah, bh, acc[nf], 0, 0, 0);
          acc[nf] = __builtin_amdgcn_mfma_f32_16x16x32_bf16(ah, bl, acc[nf], 0, 0, 0);
          acc[nf] = __builtin_amdgcn_mfma_f32_16x16x32_bf16(al, bh, acc[nf], 0, 0, 0);
          __builtin_amdgcn_s_setprio(0);
        }
      }
    }
  }
  float* Cb = Y + ((size_t)(t*1024 + rb*64))*256 + cb*64;
  #pragma unroll
  for (int nf = 0; nf < 4; ++nf)
    #pragma unroll
    for (int r = 0; r < 4; ++r) {
      const int row = wave*16 + lgrp*4 + r;
      const int col = nf*16 + lrow;
      if (a == 0) Cb[(size_t)row*256 + col] = acc[nf][r];
      else        Cb[(size_t)row*256 + col] += acc[nf][r];
    }
}

// ---------------- bias-gate + residual + LN + relu ----------------
__global__ __launch_bounds__(256) void k_ln(float* __restrict__ x,
    const float* __restrict__ y, const int* __restrict__ cnts,
    const float* __restrict__ convB, const float* __restrict__ ng,
    const float* __restrict__ nb, int l)
{
  const int r = blockIdx.x;
  const int t = r >> 10, d = r & 1023;
  const int tid = threadIdx.x;
  __shared__ float flag[12];
  __shared__ float rbuf[256];
  if (tid < 12) {
    const int a = tid / 3, c = tid - a*3;
    const int kj = a*12 + t*3 + c;
    flag[tid] = (cnts[kj*1024 + d] > 0) ? 1.f : 0.f;
  }
  __syncthreads();
  float v = y[(size_t)r*256 + tid] + x[(size_t)r*256 + tid];
  #pragma unroll
  for (int j = 0; j < 12; ++j) {
    const int a = j / 3, c = j - a*3;
    const int kj = a*12 + t*3 + c;
    v += flag[j] * convB[(size_t)(l*K_ + kj)*256 + tid];
  }
  rbuf[tid] = v; __syncthreads();
  for (int s = 128; s > 0; s >>= 1) { if (tid < s) rbuf[tid] += rbuf[tid+s]; __syncthreads(); }
  const float mean = rbuf[0] * (1.f/256.f); __syncthreads();
  const float diff = v - mean;
  rbuf[tid] = diff*diff; __syncthreads();
  for (int s = 128; s > 0; s >>= 1) { if (tid < s) rbuf[tid] += rbuf[tid+s]; __syncthreads(); }
  const float var = rbuf[0] * (1.f/256.f); __syncthreads();
  const float xn = diff * rsqrtf(var + 1e-5f) * ng[(size_t)(l*4 + t)*256 + tid]
                 + nb[(size_t)(l*4 + t)*256 + tid];
  x[(size_t)r*256 + tid] = fmaxf(xn, 0.f);
}

// ---------------- QKV GEMM with fused bf16 cast (Q scaled, V transposed) ----------------
// grid (6, 32), block 256
__global__ __launch_bounds__(256) void k_gemmq(const float* __restrict__ A,
    const ushort_t* __restrict__ Bh, const ushort_t* __restrict__ Bl,
    const float* __restrict__ bias,
    ushort_t* __restrict__ Qh, ushort_t* __restrict__ Kh, ushort_t* __restrict__ Vt)
{
  const int cb = blockIdx.x, rb = blockIdx.y;
  const int col0 = cb*128, i = col0 >> 8, g0 = col0 & 255;
  const int tid = threadIdx.x, wave = tid >> 6, lane = tid & 63;
  const int lrow = lane & 15, lgrp = lane >> 4;
  const int wr = wave >> 1, wc = wave & 1;
  __shared__ __align__(16) ushort_t AswH[128*64];
  __shared__ __align__(16) ushort_t AswL[128*64];
  __shared__ __align__(16) ushort_t BswH[128*64];
  __shared__ __align__(16) ushort_t BswL[128*64];
  const float* Ab = A + (size_t)rb*128*256;
  const ushort_t* Bhp = Bh + (size_t)i*65536 + (size_t)g0*256;
  const ushort_t* Blp = Bl + (size_t)i*65536 + (size_t)g0*256;
  f32x4 acc[4][4];
  #pragma unroll
  for (int m = 0; m < 4; ++m)
    #pragma unroll
    for (int n = 0; n < 4; ++n) acc[m][n] = (f32x4){0.f,0.f,0.f,0.f};

  for (int ks = 0; ks < 4; ++ks) {
    __syncthreads();
    #pragma unroll
    for (int it = 0; it < 8; ++it) {
      const int idx = tid + it*256;
      const int row = idx >> 4, c4 = idx & 15;
      const float4 v = *reinterpret_cast<const float4*>(Ab + (size_t)row*256 + ks*64 + c4*4);
      const float f[4] = {v.x, v.y, v.z, v.w};
      ushort_t hi[4], lo[4];
      #pragma unroll
      for (int e = 0; e < 4; ++e) {
        hi[e] = f2bf(f[e]);
        lo[e] = f2bf(f[e] - bf2f(hi[e]));
      }
      const int c8 = c4 >> 1, sub = (c4 & 1) * 4;
      const int off = row*64 + ((c8 ^ (row & 7)) << 3) + sub;
      *reinterpret_cast<uint2*>(&AswH[off]) = *reinterpret_cast<const uint2*>(hi);
      *reinterpret_cast<uint2*>(&AswL[off]) = *reinterpret_cast<const uint2*>(lo);
    }
    #pragma unroll
    for (int it = 0; it < 4; ++it) {
      const int idx = tid + it*256;
      const int row = idx >> 3, c8 = idx & 7;
      const int off = row*64 + ((c8 ^ (row & 7)) << 3);
      const size_t gsrc = (size_t)row*256 + ks*64 + c8*8;
      *reinterpret_cast<bf16x8*>(&BswH[off]) = *reinterpret_cast<const bf16x8*>(Bhp + gsrc);
      *reinterpret_cast<bf16x8*>(&BswL[off]) = *reinterpret_cast<const bf16x8*>(Blp + gsrc);
    }
    __syncthreads();
    #pragma unroll
    for (int ksub = 0; ksub < 2; ++ksub) {
      bf16x8 ah[4], al[4], bh[4], bl[4];
      const int c8 = ksub*4 + lgrp;
      #pragma unroll
      for (int mf = 0; mf < 4; ++mf) {
        const int row = wr*64 + mf*16 + lrow;
        const int off = row*64 + ((c8 ^ (row & 7)) << 3);
        ah[mf] = *reinterpret_cast<const bf16x8*>(&AswH[off]);
        al[mf] = *reinterpret_cast<const bf16x8*>(&AswL[off]);
      }
      #pragma unroll
      for (int nf = 0; nf < 4; ++nf) {
        const int row = wc*64 + nf*16 + lrow;
        const int off = row*64 + ((c8 ^ (row & 7)) << 3);
        bh[nf] = *reinterpret_cast<const bf16x8*>(&BswH[off]);
        bl[nf] = *reinterpret_cast<const bf16x8*>(&BswL[off]);
      }
      __builtin_amdgcn_s_setprio(1);
      #pragma unroll
      for (int mf = 0; mf < 4; ++mf)
        #pragma unroll
        for (int nf = 0; nf < 4; ++nf) {
          acc[mf][nf] = __builtin_amdgcn_mfma_f32_16x16x32_bf16(ah[mf], bh[nf], acc[mf][nf], 0, 0, 0);
          acc[mf][nf] = __builtin_amdgcn_mfma_f32_16x16x32_bf16(ah[mf], bl[nf], acc[mf][nf], 0, 0, 0);
          acc[mf][nf] = __builtin_amdgcn_mfma_f32_16x16x32_bf16(al[mf], bh[nf], acc[mf][nf], 0, 0, 0);
        }
      __builtin_amdgcn_s_setprio(0);
    }
  }
  const float* bp = bias + i*256;
  const float qs = (i == 0) ? 0.17677669529663687f : 1.f;
  #pragma unroll
  for (int mf = 0; mf < 4; ++mf)
    #pragma unroll
    for (int nf = 0; nf < 4; ++nf) {
      const int colg = g0 + wc*64 + nf*16 + lrow;
      const int h = colg >> 5, d = colg & 31;
      const float b = bp[colg];
      const int rowbase = rb*128 + wr*64 + mf*16 + lgrp*4;
      if (i < 2) {
        ushort_t* dst = (i == 0) ? Qh : Kh;
        #pragma unroll
        for (int r = 0; r < 4; ++r)
          dst[((size_t)(h*4096 + rowbase + r))*32 + d] = f2bf_rn((acc[mf][nf][r] + b) * qs);
      } else {
        ushort4 w;
        w.x = f2bf_rn(acc[mf][nf][0] + b);
        w.y = f2bf_rn(acc[mf][nf][1] + b);
        w.z = f2bf_rn(acc[mf][nf][2] + b);
        w.w = f2bf_rn(acc[mf][nf][3] + b);
        *reinterpret_cast<ushort4*>(Vt + (size_t)(h*32 + d)*4096 + rowbase) = w;
      }
    }
}

// ---------------- out-proj GEMM with fused split-K merge ----------------
// grid (2, 32), block 256. A = merged attention output from pacc/pml.
__global__ __launch_bounds__(256) void k_gemmo(const float* __restrict__ p0,
    const float* __restrict__ p3, const float* __restrict__ pml,
    const ushort_t* __restrict__ Bh, const ushort_t* __restrict__ Bl,
    const float* __restrict__ bias, float* __restrict__ C)
{
  const int cb = blockIdx.x, rb = blockIdx.y;
  const int g0 = cb*128;
  const int tid = threadIdx.x, wave = tid >> 6, lane = tid & 63;
  const int lrow = lane & 15, lgrp = lane >> 4;
  const int wr = wave >> 1, wc = wave & 1;
  __shared__ __align__(16) ushort_t AswH[128*64];
  __shared__ __align__(16) ushort_t AswL[128*64];
  __shared__ __align__(16) ushort_t BswH[128*64];
  __shared__ __align__(16) ushort_t BswL[128*64];
  const ushort_t* Bhp = Bh + (size_t)g0*256;
  const ushort_t* Blp = Bl + (size_t)g0*256;
  f32x4 acc[4][4];
  #pragma unroll
  for (int m = 0; m < 4; ++m)
    #pragma unroll
    for (int n = 0; n < 4; ++n) acc[m][n] = (f32x4){0.f,0.f,0.f,0.f};

  for (int ks = 0; ks < 4; ++ks) {
    __syncthreads();
    #pragma unroll
    for (int it = 0; it < 8; ++it) {
      const int idx = tid + it*256;
      const int row = rb*128 + (idx >> 4), c4 = idx & 15;
      const int c = ks*64 + c4*4;
      const int h = c >> 5;
      const float den = pml[(size_t)(row*8 + h)*4 + 0] + pml[(size_t)(row*8 + h)*4 + 1]
                      + pml[(size_t)(row*8 + h)*4 + 2] + pml[(size_t)(row*8 + h)*4 + 3];
      const float inv = 1.f / den;
      const size_t bidx = (size_t)row*256 + c;
      float f[4];
      #pragma unroll
      for (int e = 0; e < 4; ++e)
        f[e] = (p0[bidx + e] + p0[1048576 + bidx + e] + p0[2097152 + bidx + e]
              + p3[bidx + e]) * inv;
      ushort_t hi[4], lo[4];
      #pragma unroll
      for (int e = 0; e < 4; ++e) {
        hi[e] = f2bf(f[e]);
        lo[e] = f2bf(f[e] - bf2f(hi[e]));
      }
      const int rloc = idx >> 4;
      const int c8 = c4 >> 1, sub = (c4 & 1) * 4;
      const int off = rloc*64 + ((c8 ^ (rloc & 7)) << 3) + sub;
      *reinterpret_cast<uint2*>(&AswH[off]) = *reinterpret_cast<const uint2*>(hi);
      *reinterpret_cast<uint2*>(&AswL[off]) = *reinterpret_cast<const uint2*>(lo);
    }
    #pragma unroll
    for (int it = 0; it < 4; ++it) {
      const int idx = tid + it*256;
      const int row = idx >> 3, c8 = idx & 7;
      const int off = row*64 + ((c8 ^ (row & 7)) << 3);
      const size_t gsrc = (size_t)row*256 + ks*64 + c8*8;
      *reinterpret_cast<bf16x8*>(&BswH[off]) = *reinterpret_cast<const bf16x8*>(Bhp + gsrc);
      *reinterpret_cast<bf16x8*>(&BswL[off]) = *reinterpret_cast<const bf16x8*>(Blp + gsrc);
    }
    __syncthreads();
    #pragma unroll
    for (int ksub = 0; ksub < 2; ++ksub) {
      bf16x8 ah[4], al[4], bh[4], bl[4];
      const int c8 = ksub*4 + lgrp;
      #pragma unroll
      for (int mf = 0; mf < 4; ++mf) {
        const int row = wr*64 + mf*16 + lrow;
        const int off = row*64 + ((c8 ^ (row & 7)) << 3);
        ah[mf] = *reinterpret_cast<const bf16x8*>(&AswH[off]);
        al[mf] = *reinterpret_cast<const bf16x8*>(&AswL[off]);
      }
      #pragma unroll
      for (int nf = 0; nf < 4; ++nf) {
        const int row = wc*64 + nf*16 + lrow;
        const int off = row*64 + ((c8 ^ (row & 7)) << 3);
        bh[nf] = *reinterpret_cast<const bf16x8*>(&BswH[off]);
        bl[nf] = *reinterpret_cast<const bf16x8*>(&BswL[off]);
      }
      __builtin_amdgcn_s_setprio(1);
      #pragma unroll
      for (int mf = 0; mf < 4; ++mf)
        #pragma unroll
        for (int nf = 0; nf < 4; ++nf) {
          acc[mf][nf] = __builtin_amdgcn_mfma_f32_16x16x32_bf16(ah[mf], bh[nf], acc[mf][nf], 0, 0, 0);
          acc[mf][nf] = __builtin_amdgcn_mfma_f32_16x16x32_bf16(ah[mf], bl[nf], acc[mf][nf], 0, 0, 0);
          acc[mf][nf] = __builtin_amdgcn_mfma_f32_16x16x32_bf16(al[mf], bh[nf], acc[mf][nf], 0, 0, 0);
        }
      __builtin_amdgcn_s_setprio(0);
    }
  }
  float* Cp = C + (size_t)rb*128*256 + g0;
  #pragma unroll
  for (int mf = 0; mf < 4; ++mf)
    #pragma unroll
    for (int nf = 0; nf < 4; ++nf)
      #pragma unroll
      for (int r = 0; r < 4; ++r) {
        const int row = wr*64 + mf*16 + lgrp*4 + r;
        const int col = wc*64 + nf*16 + lrow;
        Cp[(size_t)row*256 + col] = acc[mf][nf][r] + bias[g0 + col];
      }
}

// ---------------- MFMA flash attention: transposed-P + tr_b16 reads, split-K 4 ----------------
// grid (64, 8, 4), block 256 (4 waves x 16 q-rows)
__global__ __launch_bounds__(256) void k_attn2(const ushort_t* __restrict__ Qh,
    const ushort_t* __restrict__ Kh, const ushort_t* __restrict__ Vt,
    float* __restrict__ pacc, float* __restrict__ pacc3, float* __restrict__ pml)
{
  const int tid = threadIdx.x;
  const int wave = tid >> 6, lane = tid & 63;
  const int lrow = lane & 15, lgrp = lane >> 4;
  const int h = blockIdx.y, sp = blockIdx.z;
  const int q0 = blockIdx.x * 64 + wave * 16;
  // P^T layout: [key 0..127][q 0..15], row stride 16 ushorts (32B)
  __shared__ __align__(16) ushort_t Pt[4][2048];
  const unsigned ptbase = (unsigned)(uintptr_t)&Pt[wave][0];

  const bf16x8 qf = *reinterpret_cast<const bf16x8*>(
      Qh + ((size_t)(h*4096 + q0 + lrow))*32 + lgrp*8);

  float lsum[4] = {0.f, 0.f, 0.f, 0.f};
  f32x4 o0 = {0.f,0.f,0.f,0.f}, o1 = {0.f,0.f,0.f,0.f};

  const ushort_t* Kbase = Kh + (size_t)(h*4096)*32;
  const ushort_t* Vbase = Vt + (size_t)(h*32)*4096;

  for (int kt = 0; kt < 8; ++kt) {
    const int kb = sp*1024 + kt*128;
    f32x4 s[8];
    __builtin_amdgcn_s_setprio(1);
    #pragma unroll
    for (int ks = 0; ks < 8; ++ks) {
      const bf16x8 kf = *reinterpret_cast<const bf16x8*>(
          Kbase + (size_t)(kb + ks*16 + lrow)*32 + lgrp*8);
      f32x4 z = {0.f,0.f,0.f,0.f};
      s[ks] = __builtin_amdgcn_mfma_f32_16x16x32_bf16(qf, kf, z, 0, 0, 0);
    }
    __builtin_amdgcn_s_setprio(0);
    // max-free softmax: P = exp(s); store transposed: 4 q's per lane contiguous -> b64 write
    #pragma unroll
    for (int ks = 0; ks < 8; ++ks) {
      float e0 = __expf(s[ks][0]), e1 = __expf(s[ks][1]);
      float e2 = __expf(s[ks][2]), e3 = __expf(s[ks][3]);
      lsum[0] += e0; lsum[1] += e1; lsum[2] += e2; lsum[3] += e3;
      ushort4 w;
      w.x = f2bf_rn(e0); w.y = f2bf_rn(e1); w.z = f2bf_rn(e2); w.w = f2bf_rn(e3);
      *reinterpret_cast<ushort4*>(&Pt[wave][(ks*16 + lrow)*16 + lgrp*4]) = w;
    }
    asm volatile("s_waitcnt lgkmcnt(0)" ::: "memory");
    __builtin_amdgcn_sched_barrier(0);
    __builtin_amdgcn_s_setprio(1);
    #pragma unroll
    for (int ks2 = 0; ks2 < 4; ++ks2) {
      // A-frag: P[q=lrow][k = ks2*32 + lgrp*8 + j], j=0..7 via 2x ds_read_b64_tr_b16
      const unsigned base = ptbase + (unsigned)(ks2*1024 + lgrp*128);
      u32x2 t0, t1;
      asm volatile("ds_read_b64_tr_b16 %0, %2\n\t"
                   "ds_read_b64_tr_b16 %1, %2 offset:128\n\t"
                   "s_waitcnt lgkmcnt(0)"
                   : "=v"(t0), "=v"(t1) : "v"(base) : "memory");
      __builtin_amdgcn_sched_barrier(0);
      union { unsigned u[4]; bf16x8 v; } pk;
      pk.u[0] = t0.x; pk.u[1] = t0.y; pk.u[2] = t1.x; pk.u[3] = t1.y;
      const bf16x8 v0 = *reinterpret_cast<const bf16x8*>(
          Vbase + (size_t)lrow*4096 + kb + ks2*32 + lgrp*8);
      const bf16x8 v1 = *reinterpret_cast<const bf16x8*>(
          Vbase + (size_t)(16 + lrow)*4096 + kb + ks2*32 + lgrp*8);
      o0 = __builtin_amdgcn_mfma_f32_16x16x32_bf16(pk.v, v0, o0, 0, 0, 0);
      o1 = __builtin_amdgcn_mfma_f32_16x16x32_bf16(pk.v, v1, o1, 0, 0, 0);
    }
    __builtin_amdgcn_s_setprio(0);
  }
  float* po = (sp == 3) ? pacc3 : (pacc + (size_t)sp*1048576);
  #pragma unroll
  for (int r = 0; r < 4; ++r) {
    float l = lsum[r];
    l += __shfl_xor(l, 1); l += __shfl_xor(l, 2);
    l += __shfl_xor(l, 4); l += __shfl_xor(l, 8);
    const int row = q0 + lgrp*4 + r;
    const size_t base = ((size_t)row*8 + h)*32;
    po[base + lrow]      = o0[r];
    po[base + 16 + lrow] = o1[r];
    if (lrow == 0) pml[((size_t)row*8 + h)*4 + sp] = l;
  }
}

// ---------------- pooling ----------------
__global__ __launch_bounds__(256) void k_pool_logits(const float* __restrict__ z,
    const float* __restrict__ pW, const float* __restrict__ pb, float* __restrict__ logits)
{
  const int tid = threadIdx.x;
  const int wave = tid >> 6, lane = tid & 63;
  const int r = blockIdx.x*4 + wave;
  const float4 zv = reinterpret_cast<const float4*>(z + (size_t)r*256)[lane];
  const float4 wv = reinterpret_cast<const float4*>(pW)[lane];
  float dv = zv.x*wv.x + zv.y*wv.y + zv.z*wv.z + zv.w*wv.w;
  for (int off = 32; off; off >>= 1) dv += __shfl_down(dv, off);
  if (lane == 0) logits[r] = dv + pb[0];
}

__global__ __launch_bounds__(256) void k_pool_stats(const float* __restrict__ logits,
    float* __restrict__ stats)
{
  const int tid = threadIdx.x;
  __shared__ float rbuf[256];
  float mx = -1e30f;
  for (int i = tid; i < 4096; i += 256) mx = fmaxf(mx, logits[i]);
  rbuf[tid] = mx; __syncthreads();
  for (int s = 128; s > 0; s >>= 1) { if (tid < s) rbuf[tid] = fmaxf(rbuf[tid], rbuf[tid+s]); __syncthreads(); }
  mx = rbuf[0]; __syncthreads();
  float se = 0.f;
  for (int i = tid; i < 4096; i += 256) se += __expf(logits[i] - mx);
  rbuf[tid] = se; __syncthreads();
  for (int s = 128; s > 0; s >>= 1) { if (tid < s) rbuf[tid] += rbuf[tid+s]; __syncthreads(); }
  if (tid == 0) { stats[0] = mx; stats[1] = rbuf[0]; }
}

__global__ __launch_bounds__(256) void k_pool_partial(const float* __restrict__ z,
    const float* __restrict__ logits, const float* __restrict__ stats,
    float* __restrict__ partial)
{
  const int pb = blockIdx.x, tid = threadIdx.x;
  const float mx = stats[0], se = stats[1];
  __shared__ float wl[64];
  if (tid < 64) wl[tid] = __expf(logits[pb*64 + tid] - mx) / se;
  __syncthreads();
  float acc = 0.f;
  for (int n = 0; n < 64; ++n) acc += wl[n] * z[(size_t)(pb*64 + n)*256 + tid];
  partial[pb*256 + tid] = acc;
}

// ---------------- heads helpers ----------------
__device__ __forceinline__ void mv256(const float* __restrict__ W,
    const float* __restrict__ sIn, float (*red)[256], int o, int hq)
{
  float a0 = 0.f, a1 = 0.f, a2 = 0.f, a3 = 0.f;
  const float* Wp = W + (size_t)(hq*64)*256 + o;
  const float* ip = sIn + hq*64;
  #pragma unroll
  for (int j = 0; j < 16; ++j) {
    a0 += ip[j*4+0] * Wp[(size_t)(j*4+0)*256];
    a1 += ip[j*4+1] * Wp[(size_t)(j*4+1)*256];
    a2 += ip[j*4+2] * Wp[(size_t)(j*4+2)*256];
    a3 += ip[j*4+3] * Wp[(size_t)(j*4+3)*256];
  }
  red[hq][o] = (a0 + a1) + (a2 + a3);
}

// ---------------- heads (single block, 1024 threads) ----------------
__global__ __launch_bounds__(1024) void k_heads(
    const float* __restrict__ partial,
    const float* __restrict__ cx, const float* __restrict__ cW, const float* __restrict__ cb,
    const float* __restrict__ taW1, const float* __restrict__ tab1,
    const float* __restrict__ tag, const float* __restrict__ tabeta,
    const float* __restrict__ taW2, const float* __restrict__ tab2,
    const float* __restrict__ shW1, const float* __restrict__ shb1,
    const float* __restrict__ shW2, const float* __restrict__ shb2,
    const float* __restrict__ fprWa, const float* __restrict__ fprba,
    const float* __restrict__ fprg, const float* __restrict__ fprbeta,
    const float* __restrict__ fprW1, const float* __restrict__ fprb1,
    const float* __restrict__ fprW2, const float* __restrict__ fprb2,
    const float* __restrict__ secW1, const float* __restrict__ secb1,
    const float* __restrict__ secW2, const float* __restrict__ secb2,
    float* __restrict__ out)
{
  const int tid = threadIdx.x;
  const int o = tid & 255, hq = tid >> 8;
  __shared__ float semb[256], esec[256], efpr[256], vbuf[256];
  __shared__ float red[4][256];
  __shared__ float rbuf[256];
  __shared__ float h1s[640];
  float* redf = &red[0][0];

  {
    float acc = 0.f;
    #pragma unroll
    for (int pb = 0; pb < 16; ++pb) acc += partial[(hq*16 + pb)*256 + o];
    #pragma unroll
    for (int i = 0; i < 8; ++i) acc += cx[hq*8 + i] * cW[(hq*8 + i)*256 + o];
    red[hq][o] = acc;
  }
  __syncthreads();
  if (tid < 256) semb[tid] = red[0][tid] + red[1][tid] + red[2][tid] + red[3][tid] + cb[tid];
  __syncthreads();

  for (int i = 0; i < 2; ++i) {
    mv256(taW1 + (size_t)i*65536, semb, red, o, hq);
    __syncthreads();
    float u = 0.f;
    if (tid < 256) u = red[0][tid] + red[1][tid] + red[2][tid] + red[3][tid] + tab1[i*256 + tid];
    if (tid < 256) rbuf[tid] = u;
    __syncthreads();
    for (int s = 128; s > 0; s >>= 1) { if (tid < s) rbuf[tid] += rbuf[tid+s]; __syncthreads(); }
    const float mean = rbuf[0] * (1.f/256.f);
    __syncthreads();
    const float diff = u - mean;
    if (tid < 256) rbuf[tid] = diff*diff;
    __syncthreads();
    for (int s = 128; s > 0; s >>= 1) { if (tid < s) rbuf[tid] += rbuf[tid+s]; __syncthreads(); }
    const float var = rbuf[0] * (1.f/256.f);
    __syncthreads();
    if (tid < 256)
      vbuf[tid] = fmaxf(diff * rsqrtf(var + 1e-5f) * tag[i*256 + tid] + tabeta[i*256 + tid], 0.f);
    __syncthreads();
    mv256(taW2 + (size_t)i*65536, vbuf, red, o, hq);
    __syncthreads();
    if (tid < 256) {
      const float s2v = red[0][tid] + red[1][tid] + red[2][tid] + red[3][tid] + tab2[i*256 + tid];
      const float att = semb[tid] * (1.f/(1.f + __expf(-s2v)));
      if (i == 0) esec[tid] = att; else efpr[tid] = att;
    }
    __syncthreads();
  }

  {
    const int oo = tid & 511, ii = oo >> 7, col = oo & 127, hh = tid >> 9;
    float a0 = 0.f, a1 = 0.f, a2 = 0.f, a3 = 0.f;
    const float* Wp = shW1 + (size_t)ii*32768 + (size_t)(hh*128)*128 + col;
    const float* ip = semb + hh*128;
    #pragma unroll
    for (int j = 0; j < 32; ++j) {
      a0 += ip[j*4+0] * Wp[(size_t)(j*4+0)*128];
      a1 += ip[j*4+1] * Wp[(size_t)(j*4+1)*128];
      a2 += ip[j*4+2] * Wp[(size_t)(j*4+2)*128];
      a3 += ip[j*4+3] * Wp[(size_t)(j*4+3)*128];
    }
    redf[hh*512 + oo] = (a0 + a1) + (a2 + a3);
  }
  __syncthreads();
  if (tid < 512) {
    const int ii = tid >> 7, col = tid & 127;
    h1s[tid] = fmaxf(redf[tid] + redf[512 + tid] + shb1[ii*128 + col], 0.f);
  }
  __syncthreads();
  if (tid < 20) {
    const int ii = tid / 5, c = tid % 5;
    const int rowm = (ii == 0) ? 0 : (ii + 1);
    float ov = shb2[ii*5 + c];
    for (int hh = 0; hh < 128; ++hh) ov += h1s[ii*128 + hh] * shW2[ii*640 + hh*5 + c];
    out[rowm*5 + c] = 1.f/(1.f + __expf(-ov));
  }

  mv256(fprWa, efpr, red, o, hq);
  __syncthreads();
  {
    float u = 0.f;
    if (tid < 256) u = red[0][tid] + red[1][tid] + red[2][tid] + red[3][tid] + fprba[tid];
    if (tid < 256) rbuf[tid] = u;
    __syncthreads();
    for (int s = 128; s > 0; s >>= 1) { if (tid < s) rbuf[tid] += rbuf[tid+s]; __syncthreads(); }
    const float mean = rbuf[0] * (1.f/256.f);
    __syncthreads();
    const float diff = u - mean;
    if (tid < 256) rbuf[tid] = diff*diff;
    __syncthreads();
    for (int s = 128; s > 0; s >>= 1) { if (tid < s) rbuf[tid] += rbuf[tid+s]; __syncthreads(); }
    const float var = rbuf[0] * (1.f/256.f);
    __syncthreads();
    if (tid < 256)
      vbuf[tid] = fmaxf(diff * rsqrtf(var + 1e-5f) * fprg[tid] + fprbeta[tid], 0.f);
    __syncthreads();
  }
  {
    const int col = tid & 127, hs = tid >> 7;
    float a0 = 0.f, a1 = 0.f;
    const float* Wp = fprW1 + (size_t)(hs*32)*128 + col;
    const float* ip = vbuf + hs*32;
    #pragma unroll
    for (int j = 0; j < 16; ++j) {
      a0 += ip[j*2+0] * Wp[(size_t)(j*2+0)*128];
      a1 += ip[j*2+1] * Wp[(size_t)(j*2+1)*128];
    }
    redf[hs*128 + col] = a0 + a1;
  }
  __syncthreads();
  if (tid < 128) {
    float hv = fprb1[tid];
    #pragma unroll
    for (int s = 0; s < 8; ++s) hv += redf[s*128 + tid];
    h1s[tid] = fmaxf(hv, 0.f);
  }
  __syncthreads();
  if (tid < 5) {
    float ov = fprb2[tid];
    for (int hh = 0; hh < 128; ++hh) ov += h1s[hh] * fprW2[hh*5 + tid];
    out[5 + tid] = 1.f/(1.f + __expf(-ov));
  }
  __syncthreads();

  if (tid < 640) {
    const int ii = tid >> 7, col = tid & 127;
    float a0 = 0.f, a1 = 0.f, a2 = 0.f, a3 = 0.f;
    const float* Wp = secW1 + (size_t)ii*32768 + col;
    #pragma unroll
    for (int j = 0; j < 64; ++j) {
      a0 += esec[j*4+0] * Wp[(size_t)(j*4+0)*128];
      a1 += esec[j*4+1] * Wp[(size_t)(j*4+1)*128];
      a2 += esec[j*4+2] * Wp[(size_t)(j*4+2)*128];
      a3 += esec[j*4+3] * Wp[(size_t)(j*4+3)*128];
    }
    h1s[tid] = fmaxf((a0 + a1) + (a2 + a3) + secb1[ii*128 + col], 0.f);
  }
  __syncthreads();
  if (tid < 5) {
    float ov = secb2[tid];
    for (int hh = 0; hh < 128; ++hh) ov += h1s[tid*128 + hh] * secW2[tid*128 + hh];
    out[tid*5 + 1] = 1.f/(1.f + __expf(-ov));
  }
}

// ---------------- launcher ----------------
extern "C" void kernel_launch(void* const* d_in, const int* in_sizes, int n_in,
                              void* d_out, int out_size, void* d_ws, size_t ws_size,
                              hipStream_t stream)
{
  const float* x_nodes    = (const float*)d_in[0];
  const float* contract_x = (const float*)d_in[1];
  const float* proj_W     = (const float*)d_in[2];
  const float* proj_b     = (const float*)d_in[3];
  const float* conv_W     = (const float*)d_in[4];
  const float* conv_b     = (const float*)d_in[5];
  const float* norm_g     = (const float*)d_in[6];
  const float* norm_b     = (const float*)d_in[7];
  const float* attn_W     = (const float*)d_in[8];
  const float* attn_b     = (const float*)d_in[9];
  const float* pool_W     = (const float*)d_in[10];
  const float* pool_b     = (const float*)d_in[11];
  const float* contract_W = (const float*)d_in[12];
  const float* contract_b = (const float*)d_in[13];
  const float* ta_W1      = (const float*)d_in[14];
  const float* ta_b1      = (const float*)d_in[15];
  const float* ta_g       = (const float*)d_in[16];
  const float* ta_beta    = (const float*)d_in[17];
  const float* ta_W2      = (const float*)d_in[18];
  const float* ta_b2      = (const float*)d_in[19];
  const float* sh_W1      = (const float*)d_in[20];
  const float* sh_b1      = (const float*)d_in[21];
  const float* sh_W2      = (const float*)d_in[22];
  const float* sh_b2      = (const float*)d_in[23];
  const float* fpr_Wa     = (const float*)d_in[24];
  const float* fpr_ba     = (const float*)d_in[25];
  const float* fpr_g      = (const float*)d_in[26];
  const float* fpr_beta   = (const float*)d_in[27];
  const float* fpr_W1     = (const float*)d_in[28];
  const float* fpr_b1     = (const float*)d_in[29];
  const float* fpr_W2     = (const float*)d_in[30];
  const float* fpr_b2     = (const float*)d_in[31];
  const float* sec_W1     = (const float*)d_in[32];
  const float* sec_b1     = (const float*)d_in[33];
  const float* sec_W2     = (const float*)d_in[34];
  const float* sec_b2     = (const float*)d_in[35];
  const int*   edge_index = (const int*)d_in[36];

  float* ws = (float*)d_ws;
  float* X     = ws + WS_X;
  float* Y     = ws + WS_Y;
  int*   ints  = (int*)(ws + WS_INT);
  int*   CNTS  = ints + WS_CNTS;
  int*   OFFS  = ints + WS_OFFS;
  int*   CUR   = ints + WS_CUR;
  int*   ELIST = ints + WS_ELIST;
  ushort_t* MHI  = (ushort_t*)(ws + WS_M);
  ushort_t* MLO  = MHI + (size_t)12*1024*256;
  ushort_t* WQHI = (ushort_t*)(ws + WS_WQ);     // 24-matrix half
  ushort_t* WQLO = WQHI + (size_t)24*65536;
  float* PACC  = ws + WS_QKV;                   // sp0..2 (3 x 1M floats)
  float* PACC3 = ws + WS_X;                     // sp3 reuses X region
  float* PML   = ws + WS_PML;
  ushort_t* QH = (ushort_t*)(ws + WS_BF);
  ushort_t* KH = (ushort_t*)(ws + WS_BF + 524288);
  ushort_t* VT = (ushort_t*)(ws + WS_BF + 1048576);
  ushort_t* AWHI = (ushort_t*)(ws + WS_AW);
  ushort_t* AWLO = AWHI + (size_t)4*65536;
  float* PART  = ws + WS_PART;
  float* LOG   = ws + WS_LOG;
  float* STATS = ws + WS_STATS;

  hipMemsetAsync(CNTS, 0, (size_t)K_*NPT_*sizeof(int), stream);

  k_proj<<<dim3(4096), 256, 0, stream>>>(x_nodes, proj_W, proj_b, X);
  k_hist<<<dim3(1536), 256, 0, stream>>>(edge_index, CNTS);
  k_scan<<<dim3(48), 1024, 0, stream>>>(CNTS, OFFS, CUR);
  k_scatter<<<dim3(1536), 256, 0, stream>>>(edge_index, CUR, ELIST);
  k_wprep<<<dim3(4, 8, 8), 256, 0, stream>>>(attn_W, AWHI, AWLO);

  for (int l = 0; l < L_; ++l) {
    for (int half = 0; half < 2; ++half) {
      k_wprep<<<dim3(24, 8, 8), 256, 0, stream>>>(
          conv_W + ((size_t)(l*K_ + half*24))*65536, WQHI, WQLO);
      for (int aa = 0; aa < 2; ++aa) {
        const int a = half*2 + aa;
        k_means<<<dim3(3072), 256, 0, stream>>>(X, OFFS, ELIST, MHI, MLO, a);
        k_wxm<<<dim3(4, 16, 4), 256, 0, stream>>>(MHI, MLO,
            WQHI + (size_t)aa*12*65536, WQLO + (size_t)aa*12*65536, Y, a);
      }
    }
    k_ln<<<dim3(4096), 256, 0, stream>>>(X, Y, CNTS, conv_b, norm_g, norm_b, l);
  }

  // QKV GEMM with fused bf16 cast (writes QH/KH/VT directly)
  k_gemmq<<<dim3(6, 32), 256, 0, stream>>>(X, AWHI, AWLO, attn_b, QH, KH, VT);
  // MFMA flash attention (split-K 4) -> PACC sp0-2 + sp3 (X region, X now dead)
  k_attn2<<<dim3(64, 8, 4), 256, 0, stream>>>(QH, KH, VT, PACC, PACC3, PML);
  // out projection with fused merge -> z2 in Y
  k_gemmo<<<dim3(2, 32), 256, 0, stream>>>(PACC, PACC3, PML,
      AWHI + (size_t)3*65536, AWLO + (size_t)3*65536, attn_b + 768, Y);
  // pooling (z2 = Y)
  k_pool_logits<<<dim3(1024), 256, 0, stream>>>(Y, pool_W, pool_b, LOG);
  k_pool_stats<<<dim3(1), 256, 0, stream>>>(LOG, STATS);
  k_pool_partial<<<dim3(64), 256, 0, stream>>>(Y, LOG, STATS, PART);
  // heads
  k_heads<<<dim3(1), 1024, 0, stream>>>(PART,
      contract_x, contract_W, contract_b,
      ta_W1, ta_b1, ta_g, ta_beta, ta_W2, ta_b2,
      sh_W1, sh_b1, sh_W2, sh_b2,
      fpr_Wa, fpr_ba, fpr_g, fpr_beta, fpr_W1, fpr_b1, fpr_W2, fpr_b2,
      sec_W1, sec_b1, sec_W2, sec_b2,
      (float*)d_out);
}